// Round 3
// baseline (745.197 us; speedup 1.0000x reference)
//
#include <hip/hip_runtime.h>
#include <hip/hip_bf16.h>

// Sizes
#define NB 256
#define NS 30
#define NW 10
#define SYM 128
#define HID 512
#define ENT 64
#define ROLE 32

// Workspace offsets (floats)
static const size_t OF_SENT = 0;          // 7680*128
static const size_t OF_QEMB = 983040;     // 256*128
static const size_t OF_H    = 1015808;    // scratch (dummy qe2 etc.)
static const size_t OF_E1   = 4947968;    // 7680*64
static const size_t OF_E2   = 5439488;
static const size_t OF_R1   = 5931008;    // 7680*32
static const size_t OF_R2   = 6176768;
static const size_t OF_R3   = 6422528;
static const size_t OF_QE1  = 6668288;    // 256*64
static const size_t OF_QR1  = 6684672;    // 256*32
static const size_t OF_QR2  = 6692864;
static const size_t OF_QR3  = 6701056;
static const size_t OF_PP   = 6709248;    // 3 heads * 4 g * 7680 * 64
static const size_t OF_M    = 12607488;   // 256 * 9 * 900
static const size_t OF_FN2  = 14681088;   // 1

__device__ __forceinline__ void fma4(float4& d, float a, const float4& v) {
  d.x += a * v.x; d.y += a * v.y; d.z += a * v.z; d.w += a * v.w;
}
__device__ __forceinline__ float wreduce64(float v) {
  #pragma unroll
  for (int o = 32; o > 0; o >>= 1) v += __shfl_xor(v, o);
  return v;
}

// ---------------- embedding ----------------
__global__ __launch_bounds__(128) void embed_k(const int* __restrict__ story, const int* __restrict__ query,
    const float* __restrict__ WE, const float* __restrict__ PE,
    float* __restrict__ sent, float* __restrict__ qemb) {
  int bs = blockIdx.x; int e = threadIdx.x;
  const int* idx; float* dst;
  if (bs < 7680) { idx = story + (size_t)bs * NW; dst = sent + (size_t)bs * SYM; }
  else           { idx = query + (size_t)(bs - 7680) * NW; dst = qemb + (size_t)(bs - 7680) * SYM; }
  float acc = 0.f;
  #pragma unroll
  for (int w = 0; w < NW; ++w) {
    int t = idx[w];
    acc += WE[t * SYM + e] * PE[w * SYM + e];
  }
  dst[e] = acc;
}

// ---------------- fused 5-head MLP (2 ENT heads + 3 ROLE heads) per 16-row tile ----------------
// Also reused for query heads (grid=16): eW* = ie params, rW* = ir params.
__global__ __launch_bounds__(256) void fused_mlp_k(const float* __restrict__ X,
    const float* __restrict__ eW1, const float* __restrict__ eb1,
    const float* __restrict__ eW2, const float* __restrict__ eb2,
    const float* __restrict__ rW1, const float* __restrict__ rb1,
    const float* __restrict__ rW2, const float* __restrict__ rb2,
    float* __restrict__ E1, float* __restrict__ E2,
    float* __restrict__ R1, float* __restrict__ R2, float* __restrict__ R3) {
  __shared__ float xt[16 * 128];
  __shared__ float ht[16 * 516];
  int r0 = blockIdx.x * 16, tid = threadIdx.x;
  #pragma unroll
  for (int i = 0; i < 8; ++i) { int idx = tid + i * 256; xt[idx] = X[(size_t)r0 * 128 + idx]; }
  __syncthreads();

  auto stage1 = [&](const float* W1, const float* b1) {
    for (int ch = 0; ch < 2; ++ch) {
      int c = ch * 256 + tid;
      float acc[16];
      #pragma unroll
      for (int i = 0; i < 16; ++i) acc[i] = 0.f;
      for (int k = 0; k < 128; ++k) {
        float w = W1[(size_t)k * 512 + c];
        #pragma unroll
        for (int i = 0; i < 16; ++i) acc[i] += xt[i * 128 + k] * w;
      }
      float bb = b1[c];
      #pragma unroll
      for (int i = 0; i < 16; ++i) ht[i * 516 + c] = tanhf(acc[i] + bb);
    }
  };
  auto stage2_64 = [&](const float* W2, const float* b2, float* Out) {
    int c = tid & 63, grp = tid >> 6;           // 4 groups x 4 rows
    float acc[4] = {0.f, 0.f, 0.f, 0.f};
    for (int k = 0; k < 512; ++k) {
      float w = W2[(size_t)k * 64 + c];
      #pragma unroll
      for (int i = 0; i < 4; ++i) acc[i] += ht[(grp * 4 + i) * 516 + k] * w;
    }
    float bb = b2[c];
    #pragma unroll
    for (int i = 0; i < 4; ++i) Out[(size_t)(r0 + grp * 4 + i) * 64 + c] = tanhf(acc[i] + bb);
  };
  auto stage2_32 = [&](const float* W2, const float* b2, float* Out) {
    int c = tid & 31, grp = tid >> 5;           // 8 groups x 2 rows
    float acc[2] = {0.f, 0.f};
    for (int k = 0; k < 512; ++k) {
      float w = W2[(size_t)k * 32 + c];
      #pragma unroll
      for (int i = 0; i < 2; ++i) acc[i] += ht[(grp * 2 + i) * 516 + k] * w;
    }
    float bb = b2[c];
    #pragma unroll
    for (int i = 0; i < 2; ++i) Out[(size_t)(r0 + grp * 2 + i) * 32 + c] = tanhf(acc[i] + bb);
  };

  stage1(eW1, eb1);                    __syncthreads();
  stage2_64(eW2, eb2, E1);             __syncthreads();
  stage1(eW1 + 65536, eb1 + 512);      __syncthreads();
  stage2_64(eW2 + 32768, eb2 + 64, E2); __syncthreads();
  stage1(rW1, rb1);                    __syncthreads();
  stage2_32(rW2, rb2, R1);             __syncthreads();
  stage1(rW1 + 65536, rb1 + 512);      __syncthreads();
  stage2_32(rW2 + 16384, rb2 + 32, R2); __syncthreads();
  stage1(rW1 + 131072, rb1 + 1024);    __syncthreads();
  stage2_32(rW2 + 32768, rb2 + 64, R3);
}

// ---------------- ||fwm||^2 ----------------
__global__ __launch_bounds__(256) void fnorm_k(const float* __restrict__ fwm, float* __restrict__ o) {
  __shared__ float red[4];
  int tid = threadIdx.x;
  const float4* f4 = reinterpret_cast<const float4*>(fwm);
  float a = 0.f;
  for (int i = tid; i < 32768; i += 256) {
    float4 v = f4[i];
    a += v.x*v.x + v.y*v.y + v.z*v.z + v.w*v.w;
  }
  #pragma unroll
  for (int off = 32; off > 0; off >>= 1) a += __shfl_down(a, off);
  if ((tid & 63) == 0) red[tid >> 6] = a;
  __syncthreads();
  if (tid == 0) o[0] = red[0] + red[1] + red[2] + red[3];
}

// ---------------- P-stage ----------------
__global__ __launch_bounds__(256) void pstage_k(const float* __restrict__ fwm,
    const float* __restrict__ e1g, const float* __restrict__ e2g,
    const float* __restrict__ r1g, const float* __restrict__ r2g, const float* __restrict__ r3g,
    float* __restrict__ Pp) {
  __shared__ float fwmT[64 * 128];
  __shared__ float e1t[16 * 65], e2t[16 * 65];
  __shared__ float r1t[128], r2t[128], r3t[128];
  int rb = blockIdx.x, g = blockIdx.y, tid = threadIdx.x;
  int row = tid >> 4, fo = tid & 15;
  for (int i = tid; i < 1024; i += 256) {
    int rr = i >> 6, e = i & 63;
    e1t[rr * 65 + e] = e1g[((size_t)rb * 16 + rr) * 64 + e];
    e2t[rr * 65 + e] = e2g[((size_t)rb * 16 + rr) * 64 + e];
  }
  if (tid < 128) {
    int rr = tid >> 3, k = tid & 7;
    r1t[tid] = r1g[((size_t)rb * 16 + rr) * 32 + g * 8 + k];
    r2t[tid] = r2g[((size_t)rb * 16 + rr) * 32 + g * 8 + k];
    r3t[tid] = r3g[((size_t)rb * 16 + rr) * 32 + g * 8 + k];
  }
  float4 P11a = {0,0,0,0}, P21a = {0,0,0,0}, P32a = {0,0,0,0};
  const float4* fwm4 = reinterpret_cast<const float4*>(fwm);
  float4* fT4 = reinterpret_cast<float4*>(fwmT);
  for (int sub = 0; sub < 4; ++sub) {
    __syncthreads();
    for (int i = tid; i < 2048; i += 256) {
      int e = i >> 5, c4 = i & 31;
      fT4[i] = fwm4[(size_t)e * 512 + g * 128 + sub * 32 + c4];
    }
    __syncthreads();
    float4 t10 = {0,0,0,0}, t11 = {0,0,0,0}, t20 = {0,0,0,0}, t21 = {0,0,0,0};
    #pragma unroll 8
    for (int e = 0; e < 64; ++e) {
      float w1 = e1t[row * 65 + e], w2 = e2t[row * 65 + e];
      float4 va = fT4[e * 32 + fo], vb = fT4[e * 32 + 16 + fo];
      fma4(t10, w1, va); fma4(t11, w1, vb);
      fma4(t20, w2, va); fma4(t21, w2, vb);
    }
    int rl = sub * 2;
    float a0 = r1t[row * 8 + rl], a1 = r1t[row * 8 + rl + 1];
    float b0 = r2t[row * 8 + rl], b1 = r2t[row * 8 + rl + 1];
    float c0 = r3t[row * 8 + rl], c1 = r3t[row * 8 + rl + 1];
    fma4(P11a, a0, t10); fma4(P11a, a1, t11);
    fma4(P21a, b0, t10); fma4(P21a, b1, t11);
    fma4(P32a, c0, t20); fma4(P32a, c1, t21);
  }
  float4* Pp4 = reinterpret_cast<float4*>(Pp);
  size_t base = (size_t)g * 122880 + ((size_t)rb * 16 + row) * 16 + fo;
  Pp4[base] = P11a;
  Pp4[491520 + base] = P21a;
  Pp4[2 * 491520 + base] = P32a;
}

// ---------------- Gram/M kernel ----------------
__global__ __launch_bounds__(512) void gram_k(const float* __restrict__ e1g, const float* __restrict__ e2g,
    const float* __restrict__ r1g, const float* __restrict__ r2g, const float* __restrict__ r3g,
    float* __restrict__ Mg) {
  __shared__ float e1L[1920], e2L[1920], r1L[960], r2L[960], r3L[960];
  int b = blockIdx.x, tid = threadIdx.x;
  for (int i = tid; i < 1920; i += 512) { e1L[i] = e1g[(size_t)b * 1920 + i]; e2L[i] = e2g[(size_t)b * 1920 + i]; }
  for (int i = tid; i < 960; i += 512) {
    r1L[i] = r1g[(size_t)b * 960 + i]; r2L[i] = r2g[(size_t)b * 960 + i]; r3L[i] = r3g[(size_t)b * 960 + i];
  }
  __syncthreads();
  for (int p = tid; p < 900; p += 512) {
    int si = p / 30, sj = p % 30;
    float g11 = 0, g12 = 0, g21 = 0, g22 = 0;
    for (int e = 0; e < 64; ++e) {
      float a1 = e1L[si * 64 + e], a2 = e2L[si * 64 + e];
      float c1 = e1L[sj * 64 + e], c2 = e2L[sj * 64 + e];
      g11 += a1 * c1; g12 += a1 * c2; g21 += a2 * c1; g22 += a2 * c2;
    }
    float R11=0,R12=0,R13=0,R21=0,R22=0,R23=0,R31=0,R32=0,R33=0;
    for (int r = 0; r < 32; ++r) {
      float x1 = r1L[si * 32 + r], x2 = r2L[si * 32 + r], x3 = r3L[si * 32 + r];
      float y1 = r1L[sj * 32 + r], y2 = r2L[sj * 32 + r], y3 = r3L[sj * 32 + r];
      R11 += x1*y1; R12 += x1*y2; R13 += x1*y3;
      R21 += x2*y1; R22 += x2*y2; R23 += x2*y3;
      R31 += x3*y1; R32 += x3*y2; R33 += x3*y3;
    }
    size_t o = (size_t)b * 8100 + p;
    Mg[o         ] = g11 * R11;
    Mg[o + 900   ] = g11 * R12;
    Mg[o + 1800  ] = g12 * R13;
    Mg[o + 2700  ] = g11 * R21;
    Mg[o + 3600  ] = g11 * R22;
    Mg[o + 4500  ] = g12 * R23;
    Mg[o + 5400  ] = g21 * R31;
    Mg[o + 6300  ] = g21 * R32;
    Mg[o + 7200  ] = g22 * R33;
  }
}

// ---------------- scan + inference (512 threads: s=tid>>4, fo=tid&15, 4 f each) ----------------
__global__ __launch_bounds__(512, 2) void scan_k(
    const float* __restrict__ Mg, const float* __restrict__ Pp,
    const float* __restrict__ e1g, const float* __restrict__ e2g,
    const float* __restrict__ r1g, const float* __restrict__ r2g, const float* __restrict__ r3g,
    const float* __restrict__ qe1g, const float* __restrict__ qr1g, const float* __restrict__ qr2g,
    const float* __restrict__ qr3g, const float* __restrict__ fn2p, const float* __restrict__ fwm,
    const float* __restrict__ lng, const float* __restrict__ lnb, const float* __restrict__ Zg,
    float* __restrict__ out) {
  __shared__ float ML[8100];
  __shared__ float e1L[1920], e2L[1920];
  __shared__ float v1L[1920], v2L[1920], v3L[1920];
  __shared__ float zL[32 * 68];
  __shared__ float uv[64], qv[32], alf[96], siL[64];
  __shared__ float redL[8], scal[2];
  int b = blockIdx.x, tid = threadIdx.x;
  int s = tid >> 4, fo = tid & 15;
  bool act = s < 30;
  int off = s * 64 + fo * 4;
  for (int i = tid; i < 8100; i += 512) ML[i] = Mg[(size_t)b * 8100 + i];
  for (int i = tid; i < 1920; i += 512) {
    e1L[i] = e1g[(size_t)b * 1920 + i];
    e2L[i] = e2g[(size_t)b * 1920 + i];
  }
  float H1[4], H2[4], H3[4], a1[4], a2[4], a3[4];
  #pragma unroll
  for (int j = 0; j < 4; ++j) { H1[j]=0; H2[j]=0; H3[j]=0; a1[j]=0; a2[j]=0; a3[j]=0; }
  float n2 = fn2p[0], c0v = 1.f;
  if (act) {
    size_t base = ((size_t)b * 30 + s) * 64 + fo * 4;
    #pragma unroll
    for (int g = 0; g < 4; ++g) {
      size_t o = (size_t)g * 491520 + base;
      #pragma unroll
      for (int j = 0; j < 4; ++j) {
        H1[j] += Pp[o + j];
        H2[j] += Pp[1966080 + o + j];
        H3[j] += Pp[3932160 + o + j];
      }
    }
  }
  __syncthreads();

  for (int layer = 0; layer < 3; ++layer) {
    float w[4], H2s[4], H3s[4], v1r[4], v2r[4], v3r[4];
    if (act) {
      #pragma unroll
      for (int j = 0; j < 4; ++j) {
        w[j] = H1[j]; H2s[j] = H2[j]; H3s[j] = H3[j];
        v1r[j] = e2L[off + j] - H1[j];
        v1L[off + j] = v1r[j];
      }
    }
    __syncthreads();
    if (act) {
      const float* MLs = ML + s * 30;
      for (int sp = 0; sp < 30; ++sp) {
        float m1 = MLs[sp], m2 = MLs[2700 + sp], m3 = MLs[5400 + sp];
        const float* vv = &v1L[sp * 64 + fo * 4];
        #pragma unroll
        for (int j = 0; j < 4; ++j) { float x = vv[j]; H1[j] += m1 * x; H2[j] += m2 * x; H3[j] += m3 * x; }
      }
      #pragma unroll
      for (int j = 0; j < 4; ++j) { v2r[j] = w[j] - H2[j]; v2L[off + j] = v2r[j]; }
    }
    __syncthreads();
    if (act) {
      const float* MLs = ML + s * 30;
      for (int sp = 0; sp < 30; ++sp) {
        float m1 = MLs[900 + sp], m2 = MLs[3600 + sp], m3 = MLs[6300 + sp];
        const float* vv = &v2L[sp * 64 + fo * 4];
        #pragma unroll
        for (int j = 0; j < 4; ++j) { float x = vv[j]; H1[j] += m1 * x; H2[j] += m2 * x; H3[j] += m3 * x; }
      }
      #pragma unroll
      for (int j = 0; j < 4; ++j) { v3r[j] = e1L[off + j] - H3[j]; v3L[off + j] = v3r[j]; }
    }
    __syncthreads();
    float local = 0.f;
    if (act) {
      const float* MLs = ML + s * 30;
      for (int sp = 0; sp < 30; ++sp) {
        float m1 = MLs[1800 + sp], m2 = MLs[4500 + sp], m3 = MLs[7200 + sp];
        const float* vv = &v3L[sp * 64 + fo * 4];
        #pragma unroll
        for (int j = 0; j < 4; ++j) { float x = vv[j]; H1[j] += m1 * x; H2[j] += m2 * x; H3[j] += m3 * x; }
      }
      #pragma unroll
      for (int j = 0; j < 4; ++j) { a1[j] += v1r[j]; a2[j] += v2r[j]; a3[j] += v3r[j]; }
      float cr = 0.f;
      #pragma unroll
      for (int j = 0; j < 4; ++j) cr += w[j] * v1r[j] + H2s[j] * v2r[j] + H3s[j] * v3r[j];
      float dt2 = 0.f;
      for (int sp = 0; sp < 30; ++sp) {
        const float* p1 = &v1L[sp * 64 + fo * 4];
        const float* p2 = &v2L[sp * 64 + fo * 4];
        const float* p3 = &v3L[sp * 64 + fo * 4];
        float d11=0,d22=0,d33=0,d12=0,d13=0,d23=0;
        #pragma unroll
        for (int j = 0; j < 4; ++j) {
          float x1 = v1r[j], x2 = v2r[j], x3 = v3r[j];
          float y1 = p1[j], y2 = p2[j], y3 = p3[j];
          d11 += x1*y1; d22 += x2*y2; d33 += x3*y3;
          d12 += x1*y2; d13 += x1*y3; d23 += x2*y3;
        }
        int o = s * 30 + sp;
        dt2 += ML[o]*d11 + ML[3600 + o]*d22 + ML[7200 + o]*d33
             + 2.f*(ML[900 + o]*d12 + ML[1800 + o]*d13 + ML[4500 + o]*d23);
      }
      local = 2.f * cr + dt2;
    }
    local = wreduce64(local);
    if ((tid & 63) == 0) redL[tid >> 6] = local;
    __syncthreads();
    if (tid == 0) {
      float tot = n2;
      #pragma unroll
      for (int i = 0; i < 8; ++i) tot += redL[i];
      float fn = fmaxf(sqrtf(tot), 1.f);
      scal[0] = 1.f / fn; scal[1] = tot;
    }
    __syncthreads();
    float inv = scal[0]; n2 = scal[1] * inv * inv; c0v *= inv;
    if (act) {
      #pragma unroll
      for (int j = 0; j < 4; ++j) { H1[j]*=inv; H2[j]*=inv; H3[j]*=inv; a1[j]*=inv; a2[j]*=inv; a3[j]*=inv; }
    }
    __syncthreads();
  }

  // ---- inference ----
  if (act) {
    #pragma unroll
    for (int j = 0; j < 4; ++j) {
      v1L[off + j] = a1[j];
      v2L[off + j] = a2[j];
      v3L[off + j] = a3[j];
    }
  }
  if (tid < 64) { uv[tid] = qe1g[(size_t)b * 64 + tid]; siL[tid] = 0.f; }
  __syncthreads();
  int zr = tid >> 4;
  for (int st = 0; st < 3; ++st) {
    const float* qrg = (st == 0) ? qr1g : ((st == 1) ? qr2g : qr3g);
    if (tid < 32) qv[tid] = qrg[(size_t)b * 32 + tid];
    __syncthreads();
    if (tid < 240) {
      int ss = tid >> 3, k = tid & 7;
      float eu1 = 0.f, eu2 = 0.f;
      for (int e = k; e < 64; e += 8) { float u = uv[e]; eu1 += e1L[ss * 64 + e] * u; eu2 += e2L[ss * 64 + e] * u; }
      float rq1 = 0.f, rq2 = 0.f, rq3 = 0.f;
      size_t rbase = ((size_t)b * 30 + ss) * 32;
      for (int rr = k; rr < 32; rr += 8) {
        float q = qv[rr];
        rq1 += r1g[rbase + rr] * q; rq2 += r2g[rbase + rr] * q; rq3 += r3g[rbase + rr] * q;
      }
      #pragma unroll
      for (int d = 4; d > 0; d >>= 1) {
        eu1 += __shfl_down(eu1, d, 8); eu2 += __shfl_down(eu2, d, 8);
        rq1 += __shfl_down(rq1, d, 8); rq2 += __shfl_down(rq2, d, 8); rq3 += __shfl_down(rq3, d, 8);
      }
      if (k == 0) { alf[ss] = eu1 * rq1; alf[32 + ss] = eu1 * rq2; alf[64 + ss] = eu2 * rq3; }
    }
    float z[4] = {0.f, 0.f, 0.f, 0.f};
    {
      const float* fb = fwm + zr * 64 + fo * 4;
      for (int e = 0; e < 64; ++e) {
        float u = uv[e];
        const float* fr = fb + (size_t)e * 2048;
        #pragma unroll
        for (int j = 0; j < 4; ++j) z[j] += u * fr[j];
      }
    }
    {
      float q = qv[zr];
      #pragma unroll
      for (int j = 0; j < 4; ++j) zL[zr * 68 + fo * 4 + j] = q * z[j];
    }
    __syncthreads();
    if (tid < 64) {
      float F = 0.f;
      for (int rr = 0; rr < 32; ++rr) F += zL[rr * 68 + tid];
      float raw = c0v * F;
      for (int sp = 0; sp < 30; ++sp)
        raw += alf[sp] * v1L[sp * 64 + tid] + alf[32 + sp] * v2L[sp * 64 + tid] + alf[64 + sp] * v3L[sp * 64 + tid];
      float mean = wreduce64(raw) * (1.f / 64.f);
      float d = raw - mean;
      float var = wreduce64(d * d) * (1.f / 63.f);
      float y = lng[st * 64 + tid] * d / (sqrtf(var) + 1e-6f) + lnb[st * 64 + tid];
      siL[tid] += y;
      uv[tid] = y;
    }
    __syncthreads();
  }
  if (tid < 9) {
    float o = 0.f;
    for (int ff = 0; ff < 64; ++ff) o += siL[ff] * Zg[ff * 9 + tid];
    out[(size_t)b * 9 + tid] = o;
  }
}

extern "C" void kernel_launch(void* const* d_in, const int* in_sizes, int n_in,
                              void* d_out, int out_size, void* d_ws, size_t ws_size,
                              hipStream_t stream) {
  const int*   story = (const int*)d_in[0];
  const int*   query = (const int*)d_in[1];
  const float* WE    = (const float*)d_in[2];
  const float* PE    = (const float*)d_in[3];
  const float* ueW1  = (const float*)d_in[4];
  const float* ueb1  = (const float*)d_in[5];
  const float* ueW2  = (const float*)d_in[6];
  const float* ueb2  = (const float*)d_in[7];
  const float* urW1  = (const float*)d_in[8];
  const float* urb1  = (const float*)d_in[9];
  const float* urW2  = (const float*)d_in[10];
  const float* urb2  = (const float*)d_in[11];
  const float* fwm   = (const float*)d_in[12];
  const float* ieW1  = (const float*)d_in[13];
  const float* ieb1  = (const float*)d_in[14];
  const float* ieW2  = (const float*)d_in[15];
  const float* ieb2  = (const float*)d_in[16];
  const float* irW1  = (const float*)d_in[17];
  const float* irb1  = (const float*)d_in[18];
  const float* irW2  = (const float*)d_in[19];
  const float* irb2  = (const float*)d_in[20];
  const float* lng   = (const float*)d_in[21];
  const float* lnb   = (const float*)d_in[22];
  const float* Z     = (const float*)d_in[23];
  float* W = (float*)d_ws;
  float* out = (float*)d_out;

  embed_k<<<7936, 128, 0, stream>>>(story, query, WE, PE, W + OF_SENT, W + OF_QEMB);

  // all 5 story heads in one dispatch (no H round-trip)
  fused_mlp_k<<<480, 256, 0, stream>>>(W + OF_SENT,
      ueW1, ueb1, ueW2, ueb2, urW1, urb1, urW2, urb2,
      W + OF_E1, W + OF_E2, W + OF_R1, W + OF_R2, W + OF_R3);
  // 4 query heads in one dispatch (qe2 computed into scratch, unused)
  fused_mlp_k<<<16, 256, 0, stream>>>(W + OF_QEMB,
      ieW1, ieb1, ieW2, ieb2, irW1, irb1, irW2, irb2,
      W + OF_QE1, W + OF_H, W + OF_QR1, W + OF_QR2, W + OF_QR3);

  fnorm_k<<<1, 256, 0, stream>>>(fwm, W + OF_FN2);
  pstage_k<<<dim3(480, 4), 256, 0, stream>>>(fwm, W + OF_E1, W + OF_E2, W + OF_R1, W + OF_R2, W + OF_R3, W + OF_PP);
  gram_k<<<NB, 512, 0, stream>>>(W + OF_E1, W + OF_E2, W + OF_R1, W + OF_R2, W + OF_R3, W + OF_M);
  scan_k<<<NB, 512, 0, stream>>>(W + OF_M, W + OF_PP, W + OF_E1, W + OF_E2, W + OF_R1, W + OF_R2, W + OF_R3,
      W + OF_QE1, W + OF_QR1, W + OF_QR2, W + OF_QR3, W + OF_FN2, fwm, lng, lnb, Z, out);
}

// Round 4
// 559.269 us; speedup vs baseline: 1.3324x; 1.3324x over previous
//
#include <hip/hip_runtime.h>
#include <hip/hip_bf16.h>

// Sizes
#define NB 256
#define NS 30
#define NW 10
#define SYM 128
#define HID 512
#define ENT 64
#define ROLE 32

// Workspace offsets (floats)
static const size_t OF_SENT = 0;          // 7680*128
static const size_t OF_QEMB = 983040;     // 256*128
static const size_t OF_H    = 1015808;    // 5 * 7680*512 = 19,660,800
static const size_t OF_QH   = 20676608;   // 4 * 256*512 = 524,288
static const size_t OF_E1   = 21200896;   // 7680*64
static const size_t OF_E2   = 21692416;
static const size_t OF_R1   = 22183936;   // 7680*32
static const size_t OF_R2   = 22429696;
static const size_t OF_R3   = 22675456;
static const size_t OF_QE1  = 22921216;   // 256*64
static const size_t OF_QR1  = 22937600;   // 256*32
static const size_t OF_QR2  = 22945792;
static const size_t OF_QR3  = 22953984;
static const size_t OF_PP   = 22962176;   // 3 * 4 * 7680*64 = 5,898,240
static const size_t OF_M    = 28860416;   // 256 * 9 * 900 = 2,073,600
static const size_t OF_FN2  = 30934016;   // 1

static const size_t H_STRIDE  = 3932160;  // 7680*512
static const size_t QH_STRIDE = 131072;   // 256*512

__device__ __forceinline__ void fma4(float4& d, float a, const float4& v) {
  d.x += a * v.x; d.y += a * v.y; d.z += a * v.z; d.w += a * v.w;
}
__device__ __forceinline__ float wreduce64(float v) {
  #pragma unroll
  for (int o = 32; o > 0; o >>= 1) v += __shfl_xor(v, o);
  return v;
}

// ---------------- embedding ----------------
__global__ __launch_bounds__(128) void embed_k(const int* __restrict__ story, const int* __restrict__ query,
    const float* __restrict__ WE, const float* __restrict__ PE,
    float* __restrict__ sent, float* __restrict__ qemb) {
  int bs = blockIdx.x; int e = threadIdx.x;
  const int* idx; float* dst;
  if (bs < 7680) { idx = story + (size_t)bs * NW; dst = sent + (size_t)bs * SYM; }
  else           { idx = query + (size_t)(bs - 7680) * NW; dst = qemb + (size_t)(bs - 7680) * SYM; }
  float acc = 0.f;
  #pragma unroll
  for (int w = 0; w < NW; ++w) {
    int t = idx[w];
    acc += WE[t * SYM + e] * PE[w * SYM + e];
  }
  dst[e] = acc;
}

// ---------------- MLP stage 1: H[h] = tanh(X[32,128] @ W1[h] + b1[h]) ----------------
// 32 rows/block; thread = (cg 0..63 -> 8 cols, rg 0..3 -> 8 rows). 32:1 FMA:LDS ratio.
__global__ __launch_bounds__(256) void mlp1_k(const float* __restrict__ X,
    const float* __restrict__ W1, size_t wstride, const float* __restrict__ b1, int bstride,
    float* __restrict__ H, size_t hstride) {
  __shared__ float xt[32 * 128];
  int r0 = blockIdx.x * 32, h = blockIdx.y, tid = threadIdx.x;
  const float* Wp = W1 + (size_t)h * wstride;
  const float* bp = b1 + (size_t)h * bstride;
  float* Ho = H + (size_t)h * hstride;

  const float4* X4 = reinterpret_cast<const float4*>(X + (size_t)r0 * 128);
  float4* xt4 = reinterpret_cast<float4*>(xt);
  #pragma unroll
  for (int i = 0; i < 4; ++i) xt4[tid + i * 256] = X4[tid + i * 256];
  __syncthreads();

  int cg = tid & 63, rg = tid >> 6;
  int c0 = cg * 8;
  float acc[8][8];
  #pragma unroll
  for (int r = 0; r < 8; ++r)
    #pragma unroll
    for (int j = 0; j < 8; ++j) acc[r][j] = 0.f;

  for (int k = 0; k < 128; k += 4) {
    float4 xr[8];
    #pragma unroll
    for (int r = 0; r < 8; ++r) xr[r] = *reinterpret_cast<const float4*>(&xt[(rg * 8 + r) * 128 + k]);
    const float* Wk = Wp + (size_t)k * 512 + c0;
    #pragma unroll
    for (int kk = 0; kk < 4; ++kk) {
      float4 wa = *reinterpret_cast<const float4*>(Wk + kk * 512);
      float4 wb = *reinterpret_cast<const float4*>(Wk + kk * 512 + 4);
      #pragma unroll
      for (int r = 0; r < 8; ++r) {
        float xv = reinterpret_cast<const float*>(&xr[r])[kk];
        acc[r][0] += xv * wa.x; acc[r][1] += xv * wa.y; acc[r][2] += xv * wa.z; acc[r][3] += xv * wa.w;
        acc[r][4] += xv * wb.x; acc[r][5] += xv * wb.y; acc[r][6] += xv * wb.z; acc[r][7] += xv * wb.w;
      }
    }
  }
  float4 ba = *reinterpret_cast<const float4*>(bp + c0);
  float4 bb = *reinterpret_cast<const float4*>(bp + c0 + 4);
  #pragma unroll
  for (int r = 0; r < 8; ++r) {
    float4 oa, ob;
    oa.x = tanhf(acc[r][0] + ba.x); oa.y = tanhf(acc[r][1] + ba.y);
    oa.z = tanhf(acc[r][2] + ba.z); oa.w = tanhf(acc[r][3] + ba.w);
    ob.x = tanhf(acc[r][4] + bb.x); ob.y = tanhf(acc[r][5] + bb.y);
    ob.z = tanhf(acc[r][6] + bb.z); ob.w = tanhf(acc[r][7] + bb.w);
    float* dst = Ho + (size_t)(r0 + rg * 8 + r) * 512 + c0;
    *reinterpret_cast<float4*>(dst) = oa;
    *reinterpret_cast<float4*>(dst + 4) = ob;
  }
}

// ---------------- MLP stage 2: Out[h] = tanh(H[h][16,512] @ W2[h] + b2[h]) ----------------
// 16 rows/block; thread = (cg 0..15 -> C cols, rg 0..15 -> 1 row); ht stride 516 (pad).
template <int O>
__global__ __launch_bounds__(256) void mlp2_k(const float* __restrict__ H, size_t hstride,
    const float* __restrict__ W2, size_t wstride, const float* __restrict__ b2, int bstride,
    float* __restrict__ Out, size_t ostride) {
  constexpr int C = O / 16;
  __shared__ float ht[16 * 516];
  int r0 = blockIdx.x * 16, h = blockIdx.y, tid = threadIdx.x;
  const float* Wp = W2 + (size_t)h * wstride;
  const float* bp = b2 + (size_t)h * bstride;
  float* Op = Out + (size_t)h * ostride;

  const float4* H4 = reinterpret_cast<const float4*>(H + (size_t)h * hstride + (size_t)r0 * 512);
  for (int i = tid; i < 2048; i += 256) {
    int row = i >> 7, c4 = i & 127;
    *reinterpret_cast<float4*>(&ht[row * 516 + c4 * 4]) = H4[row * 128 + c4];
  }
  __syncthreads();

  int cg = tid & 15, rg = tid >> 4;
  int c0 = cg * C;
  float acc[C];
  #pragma unroll
  for (int j = 0; j < C; ++j) acc[j] = 0.f;

  for (int k = 0; k < 512; k += 4) {
    float4 xv = *reinterpret_cast<const float4*>(&ht[rg * 516 + k]);
    const float* Wk = Wp + (size_t)k * O + c0;
    #pragma unroll
    for (int kk = 0; kk < 4; ++kk) {
      float x = reinterpret_cast<const float*>(&xv)[kk];
      #pragma unroll
      for (int j = 0; j < C; ++j) acc[j] += x * Wk[kk * O + j];
    }
  }
  float* dst = Op + (size_t)(r0 + rg) * O + c0;
  #pragma unroll
  for (int j = 0; j < C; ++j) dst[j] = tanhf(acc[j] + bp[c0 + j]);
}

// ---------------- ||fwm||^2 ----------------
__global__ __launch_bounds__(256) void fnorm_k(const float* __restrict__ fwm, float* __restrict__ o) {
  __shared__ float red[4];
  int tid = threadIdx.x;
  const float4* f4 = reinterpret_cast<const float4*>(fwm);
  float a = 0.f;
  for (int i = tid; i < 32768; i += 256) {
    float4 v = f4[i];
    a += v.x*v.x + v.y*v.y + v.z*v.z + v.w*v.w;
  }
  #pragma unroll
  for (int off = 32; off > 0; off >>= 1) a += __shfl_down(a, off);
  if ((tid & 63) == 0) red[tid >> 6] = a;
  __syncthreads();
  if (tid == 0) o[0] = red[0] + red[1] + red[2] + red[3];
}

// ---------------- P-stage ----------------
__global__ __launch_bounds__(256) void pstage_k(const float* __restrict__ fwm,
    const float* __restrict__ e1g, const float* __restrict__ e2g,
    const float* __restrict__ r1g, const float* __restrict__ r2g, const float* __restrict__ r3g,
    float* __restrict__ Pp) {
  __shared__ float fwmT[64 * 128];
  __shared__ float e1t[16 * 65], e2t[16 * 65];
  __shared__ float r1t[128], r2t[128], r3t[128];
  int rb = blockIdx.x, g = blockIdx.y, tid = threadIdx.x;
  int row = tid >> 4, fo = tid & 15;
  for (int i = tid; i < 1024; i += 256) {
    int rr = i >> 6, e = i & 63;
    e1t[rr * 65 + e] = e1g[((size_t)rb * 16 + rr) * 64 + e];
    e2t[rr * 65 + e] = e2g[((size_t)rb * 16 + rr) * 64 + e];
  }
  if (tid < 128) {
    int rr = tid >> 3, k = tid & 7;
    r1t[tid] = r1g[((size_t)rb * 16 + rr) * 32 + g * 8 + k];
    r2t[tid] = r2g[((size_t)rb * 16 + rr) * 32 + g * 8 + k];
    r3t[tid] = r3g[((size_t)rb * 16 + rr) * 32 + g * 8 + k];
  }
  float4 P11a = {0,0,0,0}, P21a = {0,0,0,0}, P32a = {0,0,0,0};
  const float4* fwm4 = reinterpret_cast<const float4*>(fwm);
  float4* fT4 = reinterpret_cast<float4*>(fwmT);
  for (int sub = 0; sub < 4; ++sub) {
    __syncthreads();
    for (int i = tid; i < 2048; i += 256) {
      int e = i >> 5, c4 = i & 31;
      fT4[i] = fwm4[(size_t)e * 512 + g * 128 + sub * 32 + c4];
    }
    __syncthreads();
    float4 t10 = {0,0,0,0}, t11 = {0,0,0,0}, t20 = {0,0,0,0}, t21 = {0,0,0,0};
    #pragma unroll 8
    for (int e = 0; e < 64; ++e) {
      float w1 = e1t[row * 65 + e], w2 = e2t[row * 65 + e];
      float4 va = fT4[e * 32 + fo], vb = fT4[e * 32 + 16 + fo];
      fma4(t10, w1, va); fma4(t11, w1, vb);
      fma4(t20, w2, va); fma4(t21, w2, vb);
    }
    int rl = sub * 2;
    float a0 = r1t[row * 8 + rl], a1 = r1t[row * 8 + rl + 1];
    float b0 = r2t[row * 8 + rl], b1 = r2t[row * 8 + rl + 1];
    float c0 = r3t[row * 8 + rl], c1 = r3t[row * 8 + rl + 1];
    fma4(P11a, a0, t10); fma4(P11a, a1, t11);
    fma4(P21a, b0, t10); fma4(P21a, b1, t11);
    fma4(P32a, c0, t20); fma4(P32a, c1, t21);
  }
  float4* Pp4 = reinterpret_cast<float4*>(Pp);
  size_t base = (size_t)g * 122880 + ((size_t)rb * 16 + row) * 16 + fo;
  Pp4[base] = P11a;
  Pp4[491520 + base] = P21a;
  Pp4[2 * 491520 + base] = P32a;
}

// ---------------- Gram/M kernel ----------------
__global__ __launch_bounds__(512) void gram_k(const float* __restrict__ e1g, const float* __restrict__ e2g,
    const float* __restrict__ r1g, const float* __restrict__ r2g, const float* __restrict__ r3g,
    float* __restrict__ Mg) {
  __shared__ float e1L[1920], e2L[1920], r1L[960], r2L[960], r3L[960];
  int b = blockIdx.x, tid = threadIdx.x;
  for (int i = tid; i < 1920; i += 512) { e1L[i] = e1g[(size_t)b * 1920 + i]; e2L[i] = e2g[(size_t)b * 1920 + i]; }
  for (int i = tid; i < 960; i += 512) {
    r1L[i] = r1g[(size_t)b * 960 + i]; r2L[i] = r2g[(size_t)b * 960 + i]; r3L[i] = r3g[(size_t)b * 960 + i];
  }
  __syncthreads();
  for (int p = tid; p < 900; p += 512) {
    int si = p / 30, sj = p % 30;
    float g11 = 0, g12 = 0, g21 = 0, g22 = 0;
    for (int e = 0; e < 64; ++e) {
      float a1 = e1L[si * 64 + e], a2 = e2L[si * 64 + e];
      float c1 = e1L[sj * 64 + e], c2 = e2L[sj * 64 + e];
      g11 += a1 * c1; g12 += a1 * c2; g21 += a2 * c1; g22 += a2 * c2;
    }
    float R11=0,R12=0,R13=0,R21=0,R22=0,R23=0,R31=0,R32=0,R33=0;
    for (int r = 0; r < 32; ++r) {
      float x1 = r1L[si * 32 + r], x2 = r2L[si * 32 + r], x3 = r3L[si * 32 + r];
      float y1 = r1L[sj * 32 + r], y2 = r2L[sj * 32 + r], y3 = r3L[sj * 32 + r];
      R11 += x1*y1; R12 += x1*y2; R13 += x1*y3;
      R21 += x2*y1; R22 += x2*y2; R23 += x2*y3;
      R31 += x3*y1; R32 += x3*y2; R33 += x3*y3;
    }
    size_t o = (size_t)b * 8100 + p;
    Mg[o         ] = g11 * R11;
    Mg[o + 900   ] = g11 * R12;
    Mg[o + 1800  ] = g12 * R13;
    Mg[o + 2700  ] = g11 * R21;
    Mg[o + 3600  ] = g11 * R22;
    Mg[o + 4500  ] = g12 * R23;
    Mg[o + 5400  ] = g21 * R31;
    Mg[o + 6300  ] = g21 * R32;
    Mg[o + 7200  ] = g22 * R33;
  }
}

// ---------------- scan + inference (512 threads) ----------------
__global__ __launch_bounds__(512, 2) void scan_k(
    const float* __restrict__ Mg, const float* __restrict__ Pp,
    const float* __restrict__ e1g, const float* __restrict__ e2g,
    const float* __restrict__ r1g, const float* __restrict__ r2g, const float* __restrict__ r3g,
    const float* __restrict__ qe1g, const float* __restrict__ qr1g, const float* __restrict__ qr2g,
    const float* __restrict__ qr3g, const float* __restrict__ fn2p, const float* __restrict__ fwm,
    const float* __restrict__ lng, const float* __restrict__ lnb, const float* __restrict__ Zg,
    float* __restrict__ out) {
  __shared__ float ML[8100];
  __shared__ float e1L[1920], e2L[1920];
  __shared__ float v1L[1920], v2L[1920], v3L[1920];
  __shared__ float zL[32 * 68];
  __shared__ float uv[64], qv[32], alf[96], siL[64];
  __shared__ float redL[8], scal[2];
  int b = blockIdx.x, tid = threadIdx.x;
  int s = tid >> 4, fo = tid & 15;
  bool act = s < 30;
  int off = s * 64 + fo * 4;
  for (int i = tid; i < 8100; i += 512) ML[i] = Mg[(size_t)b * 8100 + i];
  for (int i = tid; i < 1920; i += 512) {
    e1L[i] = e1g[(size_t)b * 1920 + i];
    e2L[i] = e2g[(size_t)b * 1920 + i];
  }
  float H1[4], H2[4], H3[4], a1[4], a2[4], a3[4];
  #pragma unroll
  for (int j = 0; j < 4; ++j) { H1[j]=0; H2[j]=0; H3[j]=0; a1[j]=0; a2[j]=0; a3[j]=0; }
  float n2 = fn2p[0], c0v = 1.f;
  if (act) {
    size_t base = ((size_t)b * 30 + s) * 64 + fo * 4;
    #pragma unroll
    for (int g = 0; g < 4; ++g) {
      size_t o = (size_t)g * 491520 + base;
      #pragma unroll
      for (int j = 0; j < 4; ++j) {
        H1[j] += Pp[o + j];
        H2[j] += Pp[1966080 + o + j];
        H3[j] += Pp[3932160 + o + j];
      }
    }
  }
  __syncthreads();

  for (int layer = 0; layer < 3; ++layer) {
    float w[4], H2s[4], H3s[4], v1r[4], v2r[4], v3r[4];
    if (act) {
      #pragma unroll
      for (int j = 0; j < 4; ++j) {
        w[j] = H1[j]; H2s[j] = H2[j]; H3s[j] = H3[j];
        v1r[j] = e2L[off + j] - H1[j];
        v1L[off + j] = v1r[j];
      }
    }
    __syncthreads();
    if (act) {
      const float* MLs = ML + s * 30;
      for (int sp = 0; sp < 30; ++sp) {
        float m1 = MLs[sp], m2 = MLs[2700 + sp], m3 = MLs[5400 + sp];
        const float* vv = &v1L[sp * 64 + fo * 4];
        #pragma unroll
        for (int j = 0; j < 4; ++j) { float x = vv[j]; H1[j] += m1 * x; H2[j] += m2 * x; H3[j] += m3 * x; }
      }
      #pragma unroll
      for (int j = 0; j < 4; ++j) { v2r[j] = w[j] - H2[j]; v2L[off + j] = v2r[j]; }
    }
    __syncthreads();
    if (act) {
      const float* MLs = ML + s * 30;
      for (int sp = 0; sp < 30; ++sp) {
        float m1 = MLs[900 + sp], m2 = MLs[3600 + sp], m3 = MLs[6300 + sp];
        const float* vv = &v2L[sp * 64 + fo * 4];
        #pragma unroll
        for (int j = 0; j < 4; ++j) { float x = vv[j]; H1[j] += m1 * x; H2[j] += m2 * x; H3[j] += m3 * x; }
      }
      #pragma unroll
      for (int j = 0; j < 4; ++j) { v3r[j] = e1L[off + j] - H3[j]; v3L[off + j] = v3r[j]; }
    }
    __syncthreads();
    float local = 0.f;
    if (act) {
      const float* MLs = ML + s * 30;
      for (int sp = 0; sp < 30; ++sp) {
        float m1 = MLs[1800 + sp], m2 = MLs[4500 + sp], m3 = MLs[7200 + sp];
        const float* vv = &v3L[sp * 64 + fo * 4];
        #pragma unroll
        for (int j = 0; j < 4; ++j) { float x = vv[j]; H1[j] += m1 * x; H2[j] += m2 * x; H3[j] += m3 * x; }
      }
      #pragma unroll
      for (int j = 0; j < 4; ++j) { a1[j] += v1r[j]; a2[j] += v2r[j]; a3[j] += v3r[j]; }
      float cr = 0.f;
      #pragma unroll
      for (int j = 0; j < 4; ++j) cr += w[j] * v1r[j] + H2s[j] * v2r[j] + H3s[j] * v3r[j];
      float dt2 = 0.f;
      for (int sp = 0; sp < 30; ++sp) {
        const float* p1 = &v1L[sp * 64 + fo * 4];
        const float* p2 = &v2L[sp * 64 + fo * 4];
        const float* p3 = &v3L[sp * 64 + fo * 4];
        float d11=0,d22=0,d33=0,d12=0,d13=0,d23=0;
        #pragma unroll
        for (int j = 0; j < 4; ++j) {
          float x1 = v1r[j], x2 = v2r[j], x3 = v3r[j];
          float y1 = p1[j], y2 = p2[j], y3 = p3[j];
          d11 += x1*y1; d22 += x2*y2; d33 += x3*y3;
          d12 += x1*y2; d13 += x1*y3; d23 += x2*y3;
        }
        int o = s * 30 + sp;
        dt2 += ML[o]*d11 + ML[3600 + o]*d22 + ML[7200 + o]*d33
             + 2.f*(ML[900 + o]*d12 + ML[1800 + o]*d13 + ML[4500 + o]*d23);
      }
      local = 2.f * cr + dt2;
    }
    local = wreduce64(local);
    if ((tid & 63) == 0) redL[tid >> 6] = local;
    __syncthreads();
    if (tid == 0) {
      float tot = n2;
      #pragma unroll
      for (int i = 0; i < 8; ++i) tot += redL[i];
      float fn = fmaxf(sqrtf(tot), 1.f);
      scal[0] = 1.f / fn; scal[1] = tot;
    }
    __syncthreads();
    float inv = scal[0]; n2 = scal[1] * inv * inv; c0v *= inv;
    if (act) {
      #pragma unroll
      for (int j = 0; j < 4; ++j) { H1[j]*=inv; H2[j]*=inv; H3[j]*=inv; a1[j]*=inv; a2[j]*=inv; a3[j]*=inv; }
    }
    __syncthreads();
  }

  // ---- inference ----
  if (act) {
    #pragma unroll
    for (int j = 0; j < 4; ++j) {
      v1L[off + j] = a1[j];
      v2L[off + j] = a2[j];
      v3L[off + j] = a3[j];
    }
  }
  if (tid < 64) { uv[tid] = qe1g[(size_t)b * 64 + tid]; siL[tid] = 0.f; }
  __syncthreads();
  int zr = tid >> 4;
  for (int st = 0; st < 3; ++st) {
    const float* qrg = (st == 0) ? qr1g : ((st == 1) ? qr2g : qr3g);
    if (tid < 32) qv[tid] = qrg[(size_t)b * 32 + tid];
    __syncthreads();
    if (tid < 240) {
      int ss = tid >> 3, k = tid & 7;
      float eu1 = 0.f, eu2 = 0.f;
      for (int e = k; e < 64; e += 8) { float u = uv[e]; eu1 += e1L[ss * 64 + e] * u; eu2 += e2L[ss * 64 + e] * u; }
      float rq1 = 0.f, rq2 = 0.f, rq3 = 0.f;
      size_t rbase = ((size_t)b * 30 + ss) * 32;
      for (int rr = k; rr < 32; rr += 8) {
        float q = qv[rr];
        rq1 += r1g[rbase + rr] * q; rq2 += r2g[rbase + rr] * q; rq3 += r3g[rbase + rr] * q;
      }
      #pragma unroll
      for (int d = 4; d > 0; d >>= 1) {
        eu1 += __shfl_down(eu1, d, 8); eu2 += __shfl_down(eu2, d, 8);
        rq1 += __shfl_down(rq1, d, 8); rq2 += __shfl_down(rq2, d, 8); rq3 += __shfl_down(rq3, d, 8);
      }
      if (k == 0) { alf[ss] = eu1 * rq1; alf[32 + ss] = eu1 * rq2; alf[64 + ss] = eu2 * rq3; }
    }
    float z[4] = {0.f, 0.f, 0.f, 0.f};
    {
      const float* fb = fwm + zr * 64 + fo * 4;
      for (int e = 0; e < 64; ++e) {
        float u = uv[e];
        const float* fr = fb + (size_t)e * 2048;
        #pragma unroll
        for (int j = 0; j < 4; ++j) z[j] += u * fr[j];
      }
    }
    {
      float q = qv[zr];
      #pragma unroll
      for (int j = 0; j < 4; ++j) zL[zr * 68 + fo * 4 + j] = q * z[j];
    }
    __syncthreads();
    if (tid < 64) {
      float F = 0.f;
      for (int rr = 0; rr < 32; ++rr) F += zL[rr * 68 + tid];
      float raw = c0v * F;
      for (int sp = 0; sp < 30; ++sp)
        raw += alf[sp] * v1L[sp * 64 + tid] + alf[32 + sp] * v2L[sp * 64 + tid] + alf[64 + sp] * v3L[sp * 64 + tid];
      float mean = wreduce64(raw) * (1.f / 64.f);
      float d = raw - mean;
      float var = wreduce64(d * d) * (1.f / 63.f);
      float y = lng[st * 64 + tid] * d / (sqrtf(var) + 1e-6f) + lnb[st * 64 + tid];
      siL[tid] += y;
      uv[tid] = y;
    }
    __syncthreads();
  }
  if (tid < 9) {
    float o = 0.f;
    for (int ff = 0; ff < 64; ++ff) o += siL[ff] * Zg[ff * 9 + tid];
    out[(size_t)b * 9 + tid] = o;
  }
}

extern "C" void kernel_launch(void* const* d_in, const int* in_sizes, int n_in,
                              void* d_out, int out_size, void* d_ws, size_t ws_size,
                              hipStream_t stream) {
  const int*   story = (const int*)d_in[0];
  const int*   query = (const int*)d_in[1];
  const float* WE    = (const float*)d_in[2];
  const float* PE    = (const float*)d_in[3];
  const float* ueW1  = (const float*)d_in[4];
  const float* ueb1  = (const float*)d_in[5];
  const float* ueW2  = (const float*)d_in[6];
  const float* ueb2  = (const float*)d_in[7];
  const float* urW1  = (const float*)d_in[8];
  const float* urb1  = (const float*)d_in[9];
  const float* urW2  = (const float*)d_in[10];
  const float* urb2  = (const float*)d_in[11];
  const float* fwm   = (const float*)d_in[12];
  const float* ieW1  = (const float*)d_in[13];
  const float* ieb1  = (const float*)d_in[14];
  const float* ieW2  = (const float*)d_in[15];
  const float* ieb2  = (const float*)d_in[16];
  const float* irW1  = (const float*)d_in[17];
  const float* irb1  = (const float*)d_in[18];
  const float* irW2  = (const float*)d_in[19];
  const float* irb2  = (const float*)d_in[20];
  const float* lng   = (const float*)d_in[21];
  const float* lnb   = (const float*)d_in[22];
  const float* Z     = (const float*)d_in[23];
  float* W = (float*)d_ws;
  float* out = (float*)d_out;

  embed_k<<<7936, 128, 0, stream>>>(story, query, WE, PE, W + OF_SENT, W + OF_QEMB);

  // stage 1: story e-heads (H slots 0,1), story r-heads (slots 2,3,4)
  mlp1_k<<<dim3(240, 2), 256, 0, stream>>>(W + OF_SENT, ueW1, 65536, ueb1, 512, W + OF_H, H_STRIDE);
  mlp1_k<<<dim3(240, 3), 256, 0, stream>>>(W + OF_SENT, urW1, 65536, urb1, 512, W + OF_H + 2 * H_STRIDE, H_STRIDE);
  // stage 1: query e-head 0 (QH slot 0), query r-heads (slots 1,2,3)
  mlp1_k<<<dim3(8, 1), 256, 0, stream>>>(W + OF_QEMB, ieW1, 65536, ieb1, 512, W + OF_QH, QH_STRIDE);
  mlp1_k<<<dim3(8, 3), 256, 0, stream>>>(W + OF_QEMB, irW1, 65536, irb1, 512, W + OF_QH + QH_STRIDE, QH_STRIDE);

  // stage 2
  mlp2_k<64><<<dim3(480, 2), 256, 0, stream>>>(W + OF_H, H_STRIDE, ueW2, 32768, ueb2, 64, W + OF_E1, 491520);
  mlp2_k<32><<<dim3(480, 3), 256, 0, stream>>>(W + OF_H + 2 * H_STRIDE, H_STRIDE, urW2, 16384, urb2, 32, W + OF_R1, 245760);
  mlp2_k<64><<<dim3(16, 1), 256, 0, stream>>>(W + OF_QH, QH_STRIDE, ieW2, 32768, ieb2, 64, W + OF_QE1, 16384);
  mlp2_k<32><<<dim3(16, 3), 256, 0, stream>>>(W + OF_QH + QH_STRIDE, QH_STRIDE, irW2, 16384, irb2, 32, W + OF_QR1, 8192);

  fnorm_k<<<1, 256, 0, stream>>>(fwm, W + OF_FN2);
  pstage_k<<<dim3(480, 4), 256, 0, stream>>>(fwm, W + OF_E1, W + OF_E2, W + OF_R1, W + OF_R2, W + OF_R3, W + OF_PP);
  gram_k<<<NB, 512, 0, stream>>>(W + OF_E1, W + OF_E2, W + OF_R1, W + OF_R2, W + OF_R3, W + OF_M);
  scan_k<<<NB, 512, 0, stream>>>(W + OF_M, W + OF_PP, W + OF_E1, W + OF_E2, W + OF_R1, W + OF_R2, W + OF_R3,
      W + OF_QE1, W + OF_QR1, W + OF_QR2, W + OF_QR3, W + OF_FN2, fwm, lng, lnb, Z, out);
}

// Round 5
// 375.333 us; speedup vs baseline: 1.9854x; 1.4901x over previous
//
#include <hip/hip_runtime.h>
#include <hip/hip_bf16.h>

// Sizes
#define NB 256
#define NS 30
#define NW 10
#define SYM 128
#define HID 512
#define ENT 64
#define ROLE 32

// Workspace offsets (floats)
static const size_t OF_SENT = 0;          // 7680*128
static const size_t OF_QEMB = 983040;     // 256*128
static const size_t OF_E1   = 1015808;    // 7680*64 (E2 contiguous, stride 491520)
static const size_t OF_E2   = 1507328;
static const size_t OF_R1   = 1998848;    // 7680*32 (R2,R3 contiguous, stride 245760)
static const size_t OF_R2   = 2244608;
static const size_t OF_R3   = 2490368;
static const size_t OF_QE1  = 2736128;    // 256*64
static const size_t OF_QR1  = 2752512;    // 256*32 (stride 8192)
static const size_t OF_QR2  = 2760704;
static const size_t OF_QR3  = 2768896;
static const size_t OF_PP   = 2777088;    // 3 * 7680*64 = 1,474,560 (summed over r-groups)
static const size_t OF_FN2  = 4251648;    // 1

__device__ __forceinline__ void fma4(float4& d, float a, const float4& v) {
  d.x += a * v.x; d.y += a * v.y; d.z += a * v.z; d.w += a * v.w;
}
__device__ __forceinline__ float wreduce64(float v) {
  #pragma unroll
  for (int o = 32; o > 0; o >>= 1) v += __shfl_xor(v, o);
  return v;
}

// ---------------- embedding ----------------
__global__ __launch_bounds__(128) void embed_k(const int* __restrict__ story, const int* __restrict__ query,
    const float* __restrict__ WE, const float* __restrict__ PE,
    float* __restrict__ sent, float* __restrict__ qemb) {
  int bs = blockIdx.x; int e = threadIdx.x;
  const int* idx; float* dst;
  if (bs < 7680) { idx = story + (size_t)bs * NW; dst = sent + (size_t)bs * SYM; }
  else           { idx = query + (size_t)(bs - 7680) * NW; dst = qemb + (size_t)(bs - 7680) * SYM; }
  float acc = 0.f;
  #pragma unroll
  for (int w = 0; w < NW; ++w) {
    int t = idx[w];
    acc += WE[t * SYM + e] * PE[w * SYM + e];
  }
  dst[e] = acc;
}

// ---------------- fused per-head MLP: tanh(tanh(X W1 + b1) W2 + b2), H in LDS ----------------
// grid (rowblocks, nheads). h < eHeads -> ENT head h; else ROLE head (h-eHeads).
__global__ __launch_bounds__(256) void mlpf_k(const float* __restrict__ X,
    const float* __restrict__ eW1, const float* __restrict__ eb1,
    const float* __restrict__ eW2, const float* __restrict__ eb2,
    const float* __restrict__ rW1, const float* __restrict__ rb1,
    const float* __restrict__ rW2, const float* __restrict__ rb2,
    float* __restrict__ Eout, size_t eostride,
    float* __restrict__ Rout, size_t rostride, int eHeads) {
  __shared__ float xt[16 * 128];
  __shared__ float ht[16 * 516];
  int r0 = blockIdx.x * 16, h = blockIdx.y, tid = threadIdx.x;
  bool isE = h < eHeads;
  int hh = isE ? h : h - eHeads;
  const float* W1 = (isE ? eW1 : rW1) + (size_t)hh * 65536;
  const float* b1 = (isE ? eb1 : rb1) + hh * 512;

  const float4* X4 = reinterpret_cast<const float4*>(X + (size_t)r0 * 128);
  float4* xt4 = reinterpret_cast<float4*>(xt);
  #pragma unroll
  for (int i = 0; i < 2; ++i) xt4[tid + i * 256] = X4[tid + i * 256];
  __syncthreads();

  // stage 1: thread = (cg 0..63 -> 8 cols, rg 0..3 -> 4 rows)
  {
    int cg = tid & 63, rg = tid >> 6;
    int c0 = cg * 8;
    float acc[4][8];
    #pragma unroll
    for (int r = 0; r < 4; ++r)
      #pragma unroll
      for (int j = 0; j < 8; ++j) acc[r][j] = 0.f;
    for (int k = 0; k < 128; k += 4) {
      float4 xr[4];
      #pragma unroll
      for (int r = 0; r < 4; ++r) xr[r] = *reinterpret_cast<const float4*>(&xt[(rg * 4 + r) * 128 + k]);
      const float* Wk = W1 + (size_t)k * 512 + c0;
      #pragma unroll
      for (int kk = 0; kk < 4; ++kk) {
        float4 wa = *reinterpret_cast<const float4*>(Wk + kk * 512);
        float4 wb = *reinterpret_cast<const float4*>(Wk + kk * 512 + 4);
        #pragma unroll
        for (int r = 0; r < 4; ++r) {
          float xv = reinterpret_cast<const float*>(&xr[r])[kk];
          acc[r][0] += xv * wa.x; acc[r][1] += xv * wa.y; acc[r][2] += xv * wa.z; acc[r][3] += xv * wa.w;
          acc[r][4] += xv * wb.x; acc[r][5] += xv * wb.y; acc[r][6] += xv * wb.z; acc[r][7] += xv * wb.w;
        }
      }
    }
    float4 ba = *reinterpret_cast<const float4*>(b1 + c0);
    float4 bb = *reinterpret_cast<const float4*>(b1 + c0 + 4);
    #pragma unroll
    for (int r = 0; r < 4; ++r) {
      float* dst = &ht[(rg * 4 + r) * 516 + c0];
      dst[0] = tanhf(acc[r][0] + ba.x); dst[1] = tanhf(acc[r][1] + ba.y);
      dst[2] = tanhf(acc[r][2] + ba.z); dst[3] = tanhf(acc[r][3] + ba.w);
      dst[4] = tanhf(acc[r][4] + bb.x); dst[5] = tanhf(acc[r][5] + bb.y);
      dst[6] = tanhf(acc[r][6] + bb.z); dst[7] = tanhf(acc[r][7] + bb.w);
    }
  }
  __syncthreads();

  // stage 2
  if (isE) {   // O = 64: thread = (c 0..63, rgr 0..3 -> 4 rows)
    const float* W2 = eW2 + (size_t)hh * 32768;
    const float* b2 = eb2 + hh * 64;
    int c = tid & 63, rgr = tid >> 6;
    float acc[4] = {0.f, 0.f, 0.f, 0.f};
    for (int k = 0; k < 512; ++k) {
      float w = W2[(size_t)k * 64 + c];
      #pragma unroll
      for (int i = 0; i < 4; ++i) acc[i] += ht[(rgr * 4 + i) * 516 + k] * w;
    }
    float bb = b2[c];
    #pragma unroll
    for (int i = 0; i < 4; ++i)
      Eout[(size_t)hh * eostride + (size_t)(r0 + rgr * 4 + i) * 64 + c] = tanhf(acc[i] + bb);
  } else {     // O = 32: thread = (c 0..31, rgr 0..7 -> 2 rows)
    const float* W2 = rW2 + (size_t)hh * 16384;
    const float* b2 = rb2 + hh * 32;
    int c = tid & 31, rgr = tid >> 5;
    float acc[2] = {0.f, 0.f};
    for (int k = 0; k < 512; ++k) {
      float w = W2[(size_t)k * 32 + c];
      #pragma unroll
      for (int i = 0; i < 2; ++i) acc[i] += ht[(rgr * 2 + i) * 516 + k] * w;
    }
    float bb = b2[c];
    #pragma unroll
    for (int i = 0; i < 2; ++i)
      Rout[(size_t)hh * rostride + (size_t)(r0 + rgr * 2 + i) * 32 + c] = tanhf(acc[i] + bb);
  }
}

// ---------------- ||fwm||^2 ----------------
__global__ __launch_bounds__(256) void fnorm_k(const float* __restrict__ fwm, float* __restrict__ o) {
  __shared__ float red[4];
  int tid = threadIdx.x;
  const float4* f4 = reinterpret_cast<const float4*>(fwm);
  float a = 0.f;
  for (int i = tid; i < 32768; i += 256) {
    float4 v = f4[i];
    a += v.x*v.x + v.y*v.y + v.z*v.z + v.w*v.w;
  }
  #pragma unroll
  for (int off = 32; off > 0; off >>= 1) a += __shfl_down(a, off);
  if ((tid & 63) == 0) red[tid >> 6] = a;
  __syncthreads();
  if (tid == 0) o[0] = red[0] + red[1] + red[2] + red[3];
}

// ---------------- P-stage: P1=sum_r r1(E1 fwm), P2=sum_r r2(E1 fwm), P3=sum_r r3(E2 fwm) ----------------
// grid 480; loops all 4 r-groups internally, writes summed P [3][7680][64].
__global__ __launch_bounds__(256) void pstage_k(const float* __restrict__ fwm,
    const float* __restrict__ e1g, const float* __restrict__ e2g,
    const float* __restrict__ r1g, const float* __restrict__ r2g, const float* __restrict__ r3g,
    float* __restrict__ Pp) {
  __shared__ float fwmT[8192];           // [64][128] slice
  __shared__ float e1t[16 * 65], e2t[16 * 65];
  __shared__ float r1t[512], r2t[512], r3t[512];   // [16][32]
  int rb = blockIdx.x, tid = threadIdx.x;
  int row = tid >> 4, fo = tid & 15;
  for (int i = tid; i < 1024; i += 256) {
    int rr = i >> 6, e = i & 63;
    e1t[rr * 65 + e] = e1g[((size_t)rb * 16 + rr) * 64 + e];
    e2t[rr * 65 + e] = e2g[((size_t)rb * 16 + rr) * 64 + e];
  }
  for (int i = tid; i < 512; i += 256) {
    r1t[i] = r1g[((size_t)rb * 16 + (i >> 5)) * 32 + (i & 31)];
    r2t[i] = r2g[((size_t)rb * 16 + (i >> 5)) * 32 + (i & 31)];
    r3t[i] = r3g[((size_t)rb * 16 + (i >> 5)) * 32 + (i & 31)];
  }
  float4 P1a = {0,0,0,0}, P2a = {0,0,0,0}, P3a = {0,0,0,0};
  const float4* fwm4 = reinterpret_cast<const float4*>(fwm);
  float4* fT4 = reinterpret_cast<float4*>(fwmT);
  for (int g = 0; g < 4; ++g) {
    for (int sub = 0; sub < 4; ++sub) {
      __syncthreads();
      for (int i = tid; i < 2048; i += 256) {
        int e = i >> 5, c4 = i & 31;
        fT4[i] = fwm4[(size_t)e * 512 + g * 128 + sub * 32 + c4];
      }
      __syncthreads();
      float4 t10 = {0,0,0,0}, t11 = {0,0,0,0}, t20 = {0,0,0,0}, t21 = {0,0,0,0};
      #pragma unroll 8
      for (int e = 0; e < 64; ++e) {
        float w1 = e1t[row * 65 + e], w2 = e2t[row * 65 + e];
        float4 va = fT4[e * 32 + fo], vb = fT4[e * 32 + 16 + fo];
        fma4(t10, w1, va); fma4(t11, w1, vb);
        fma4(t20, w2, va); fma4(t21, w2, vb);
      }
      int rl = g * 8 + sub * 2;
      float a0 = r1t[row * 32 + rl], a1 = r1t[row * 32 + rl + 1];
      float b0 = r2t[row * 32 + rl], b1 = r2t[row * 32 + rl + 1];
      float c0 = r3t[row * 32 + rl], c1 = r3t[row * 32 + rl + 1];
      fma4(P1a, a0, t10); fma4(P1a, a1, t11);
      fma4(P2a, b0, t10); fma4(P2a, b1, t11);
      fma4(P3a, c0, t20); fma4(P3a, c1, t21);
    }
  }
  float4* Pp4 = reinterpret_cast<float4*>(Pp);
  size_t base = ((size_t)rb * 16 + row) * 16 + fo;
  Pp4[base] = P1a;
  Pp4[122880 + base] = P2a;
  Pp4[245760 + base] = P3a;
}

// ---------------- scan + inference, 1024 threads, gram fused, dt2-free norm ----------------
__global__ __launch_bounds__(1024, 4) void scan_k(
    const float* __restrict__ Pp,
    const float* __restrict__ e1g, const float* __restrict__ e2g,
    const float* __restrict__ r1g, const float* __restrict__ r2g, const float* __restrict__ r3g,
    const float* __restrict__ qe1g, const float* __restrict__ qr1g, const float* __restrict__ qr2g,
    const float* __restrict__ qr3g, const float* __restrict__ fn2p, const float* __restrict__ fwm,
    const float* __restrict__ lng, const float* __restrict__ lnb, const float* __restrict__ Zg,
    float* __restrict__ out) {
  __shared__ float ML[8100];                       // reused as zL[32*66] in inference
  __shared__ float e1L[1980], e2L[1980];           // [30][66] padded
  __shared__ float v1L[1980], v2L[1980], v3L[1980];
  __shared__ float r1L[990], r2L[990], r3L[990];   // [30][33] padded
  __shared__ float uv[64], qv[32], alf[96], siL[64];
  __shared__ float redL[16], scal[2];
  int b = blockIdx.x, tid = threadIdx.x;
  int s = tid >> 5, fo = tid & 31;
  bool act = s < 30;
  int off = s * 66 + fo * 2;

  // H init from summed P (global, overlaps with LDS staging)
  float H1[2], H2[2], H3[2], a1[2], a2[2], a3[2];
  #pragma unroll
  for (int j = 0; j < 2; ++j) { H1[j]=0; H2[j]=0; H3[j]=0; a1[j]=0; a2[j]=0; a3[j]=0; }
  if (act) {
    size_t base = ((size_t)b * 30 + s) * 64 + fo * 2;
    #pragma unroll
    for (int j = 0; j < 2; ++j) {
      H1[j] = Pp[base + j];
      H2[j] = Pp[491520 + base + j];
      H3[j] = Pp[983040 + base + j];
    }
  }
  for (int i = tid; i < 1920; i += 1024) {
    int ss = i >> 6, e = i & 63;
    e1L[ss * 66 + e] = e1g[(size_t)b * 1920 + i];
    e2L[ss * 66 + e] = e2g[(size_t)b * 1920 + i];
  }
  for (int i = tid; i < 960; i += 1024) {
    int ss = i >> 5, rr = i & 31;
    r1L[ss * 33 + rr] = r1g[(size_t)b * 960 + i];
    r2L[ss * 33 + rr] = r2g[(size_t)b * 960 + i];
    r3L[ss * 33 + rr] = r3g[(size_t)b * 960 + i];
  }
  __syncthreads();

  // ---- fused gram: ML[9][900] ----
  if (tid < 900) {
    int si = tid / 30, sj = tid - si * 30;
    float g11 = 0, g12 = 0, g21 = 0, g22 = 0;
    for (int e = 0; e < 64; ++e) {
      float A1 = e1L[si * 66 + e], A2 = e2L[si * 66 + e];
      float C1 = e1L[sj * 66 + e], C2 = e2L[sj * 66 + e];
      g11 += A1 * C1; g12 += A1 * C2; g21 += A2 * C1; g22 += A2 * C2;
    }
    float R11=0,R12=0,R13=0,R21=0,R22=0,R23=0,R31=0,R32=0,R33=0;
    for (int r = 0; r < 32; ++r) {
      float x1 = r1L[si * 33 + r], x2 = r2L[si * 33 + r], x3 = r3L[si * 33 + r];
      float y1 = r1L[sj * 33 + r], y2 = r2L[sj * 33 + r], y3 = r3L[sj * 33 + r];
      R11 += x1*y1; R12 += x1*y2; R13 += x1*y3;
      R21 += x2*y1; R22 += x2*y2; R23 += x2*y3;
      R31 += x3*y1; R32 += x3*y2; R33 += x3*y3;
    }
    ML[tid]        = g11 * R11;
    ML[900 + tid]  = g11 * R12;
    ML[1800 + tid] = g12 * R13;
    ML[2700 + tid] = g11 * R21;
    ML[3600 + tid] = g11 * R22;
    ML[4500 + tid] = g12 * R23;
    ML[5400 + tid] = g21 * R31;
    ML[6300 + tid] = g21 * R32;
    ML[7200 + tid] = g22 * R33;
  }
  __syncthreads();

  float n2 = fn2p[0], c0v = 1.f;
  for (int layer = 0; layer < 3; ++layer) {
    float w[2], H2s[2], H3s[2], v1r[2], v2r[2], v3r[2];
    if (act) {
      #pragma unroll
      for (int j = 0; j < 2; ++j) {
        w[j] = H1[j]; H2s[j] = H2[j]; H3s[j] = H3[j];
        v1r[j] = e2L[off + j] - H1[j];
        v1L[off + j] = v1r[j];
      }
    }
    __syncthreads();
    if (act) {
      const float* MLs = ML + s * 30;
      for (int sp = 0; sp < 30; ++sp) {
        float m1 = MLs[sp], m2 = MLs[2700 + sp], m3 = MLs[5400 + sp];
        const float* vv = &v1L[sp * 66 + fo * 2];
        #pragma unroll
        for (int j = 0; j < 2; ++j) { float x = vv[j]; H1[j] += m1 * x; H2[j] += m2 * x; H3[j] += m3 * x; }
      }
      #pragma unroll
      for (int j = 0; j < 2; ++j) { v2r[j] = w[j] - H2[j]; v2L[off + j] = v2r[j]; }
    }
    __syncthreads();
    if (act) {
      const float* MLs = ML + s * 30;
      for (int sp = 0; sp < 30; ++sp) {
        float m1 = MLs[900 + sp], m2 = MLs[3600 + sp], m3 = MLs[6300 + sp];
        const float* vv = &v2L[sp * 66 + fo * 2];
        #pragma unroll
        for (int j = 0; j < 2; ++j) { float x = vv[j]; H1[j] += m1 * x; H2[j] += m2 * x; H3[j] += m3 * x; }
      }
      #pragma unroll
      for (int j = 0; j < 2; ++j) { v3r[j] = e1L[off + j] - H3[j]; v3L[off + j] = v3r[j]; }
    }
    __syncthreads();
    float local = 0.f;
    if (act) {
      const float* MLs = ML + s * 30;
      for (int sp = 0; sp < 30; ++sp) {
        float m1 = MLs[1800 + sp], m2 = MLs[4500 + sp], m3 = MLs[7200 + sp];
        const float* vv = &v3L[sp * 66 + fo * 2];
        #pragma unroll
        for (int j = 0; j < 2; ++j) { float x = vv[j]; H1[j] += m1 * x; H2[j] += m2 * x; H3[j] += m3 * x; }
      }
      // norm delta: 2*cr + dt2 == sum_i v_i . (H_i_start + H_i_end)   [K symmetry]
      #pragma unroll
      for (int j = 0; j < 2; ++j) {
        a1[j] += v1r[j]; a2[j] += v2r[j]; a3[j] += v3r[j];
        local += v1r[j] * (w[j] + H1[j]) + v2r[j] * (H2s[j] + H2[j]) + v3r[j] * (H3s[j] + H3[j]);
      }
    }
    local = wreduce64(local);
    if ((tid & 63) == 0) redL[tid >> 6] = local;
    __syncthreads();
    if (tid == 0) {
      float tot = n2;
      #pragma unroll
      for (int i = 0; i < 16; ++i) tot += redL[i];
      float fn = fmaxf(sqrtf(tot), 1.f);
      scal[0] = 1.f / fn; scal[1] = tot;
    }
    __syncthreads();
    float inv = scal[0]; n2 = scal[1] * inv * inv; c0v *= inv;
    if (act) {
      #pragma unroll
      for (int j = 0; j < 2; ++j) { H1[j]*=inv; H2[j]*=inv; H3[j]*=inv; a1[j]*=inv; a2[j]*=inv; a3[j]*=inv; }
    }
    __syncthreads();
  }

  // ---- inference ----
  if (act) {
    #pragma unroll
    for (int j = 0; j < 2; ++j) { v1L[off + j] = a1[j]; v2L[off + j] = a2[j]; v3L[off + j] = a3[j]; }
  }
  if (tid < 64) { uv[tid] = qe1g[(size_t)b * 64 + tid]; siL[tid] = 0.f; }
  __syncthreads();
  float* zL = ML;   // overlay (layers done)
  for (int st = 0; st < 3; ++st) {
    const float* qrg = (st == 0) ? qr1g : ((st == 1) ? qr2g : qr3g);
    if (tid < 32) qv[tid] = qrg[(size_t)b * 32 + tid];
    __syncthreads();
    // alf[s], per 32-lane group
    if (act) {
      int k = fo;
      float u0 = uv[k], u1 = uv[k + 32];
      float eu1 = e1L[s * 66 + k] * u0 + e1L[s * 66 + k + 32] * u1;
      float eu2 = e2L[s * 66 + k] * u0 + e2L[s * 66 + k + 32] * u1;
      float rq1 = r1L[s * 33 + k] * qv[k];
      float rq2 = r2L[s * 33 + k] * qv[k];
      float rq3 = r3L[s * 33 + k] * qv[k];
      #pragma unroll
      for (int d = 16; d > 0; d >>= 1) {
        eu1 += __shfl_down(eu1, d, 32); eu2 += __shfl_down(eu2, d, 32);
        rq1 += __shfl_down(rq1, d, 32); rq2 += __shfl_down(rq2, d, 32); rq3 += __shfl_down(rq3, d, 32);
      }
      if (k == 0) { alf[s] = eu1 * rq1; alf[32 + s] = eu1 * rq2; alf[64 + s] = eu2 * rq3; }
    }
    // z[r,f] = sum_e uv[e] * fwm[e,r,f]  (all 1024 threads: r = s, 2 f each)
    float z[2] = {0.f, 0.f};
    {
      const float* fb = fwm + s * 64 + fo * 2;
      for (int e = 0; e < 64; ++e) {
        float u = uv[e];
        const float* fr = fb + (size_t)e * 2048;
        z[0] += u * fr[0]; z[1] += u * fr[1];
      }
    }
    {
      float q = qv[s];
      zL[s * 66 + fo * 2]     = q * z[0];
      zL[s * 66 + fo * 2 + 1] = q * z[1];
    }
    __syncthreads();
    if (tid < 64) {
      float F = 0.f;
      for (int rr = 0; rr < 32; ++rr) F += zL[rr * 66 + tid];
      float raw = c0v * F;
      for (int sp = 0; sp < 30; ++sp)
        raw += alf[sp] * v1L[sp * 66 + tid] + alf[32 + sp] * v2L[sp * 66 + tid] + alf[64 + sp] * v3L[sp * 66 + tid];
      float mean = wreduce64(raw) * (1.f / 64.f);
      float d = raw - mean;
      float var = wreduce64(d * d) * (1.f / 63.f);
      float y = lng[st * 64 + tid] * d / (sqrtf(var) + 1e-6f) + lnb[st * 64 + tid];
      siL[tid] += y;
      uv[tid] = y;
    }
    __syncthreads();
  }
  if (tid < 9) {
    float o = 0.f;
    for (int ff = 0; ff < 64; ++ff) o += siL[ff] * Zg[ff * 9 + tid];
    out[(size_t)b * 9 + tid] = o;
  }
}

extern "C" void kernel_launch(void* const* d_in, const int* in_sizes, int n_in,
                              void* d_out, int out_size, void* d_ws, size_t ws_size,
                              hipStream_t stream) {
  const int*   story = (const int*)d_in[0];
  const int*   query = (const int*)d_in[1];
  const float* WE    = (const float*)d_in[2];
  const float* PE    = (const float*)d_in[3];
  const float* ueW1  = (const float*)d_in[4];
  const float* ueb1  = (const float*)d_in[5];
  const float* ueW2  = (const float*)d_in[6];
  const float* ueb2  = (const float*)d_in[7];
  const float* urW1  = (const float*)d_in[8];
  const float* urb1  = (const float*)d_in[9];
  const float* urW2  = (const float*)d_in[10];
  const float* urb2  = (const float*)d_in[11];
  const float* fwm   = (const float*)d_in[12];
  const float* ieW1  = (const float*)d_in[13];
  const float* ieb1  = (const float*)d_in[14];
  const float* ieW2  = (const float*)d_in[15];
  const float* ieb2  = (const float*)d_in[16];
  const float* irW1  = (const float*)d_in[17];
  const float* irb1  = (const float*)d_in[18];
  const float* irW2  = (const float*)d_in[19];
  const float* irb2  = (const float*)d_in[20];
  const float* lng   = (const float*)d_in[21];
  const float* lnb   = (const float*)d_in[22];
  const float* Z     = (const float*)d_in[23];
  float* W = (float*)d_ws;
  float* out = (float*)d_out;

  embed_k<<<7936, 128, 0, stream>>>(story, query, WE, PE, W + OF_SENT, W + OF_QEMB);

  // story: 5 heads (2 ENT + 3 ROLE), H kept in LDS
  mlpf_k<<<dim3(480, 5), 256, 0, stream>>>(W + OF_SENT,
      ueW1, ueb1, ueW2, ueb2, urW1, urb1, urW2, urb2,
      W + OF_E1, 491520, W + OF_R1, 245760, 2);
  // query: 4 heads (1 ENT + 3 ROLE)
  mlpf_k<<<dim3(16, 4), 256, 0, stream>>>(W + OF_QEMB,
      ieW1, ieb1, ieW2, ieb2, irW1, irb1, irW2, irb2,
      W + OF_QE1, 16384, W + OF_QR1, 8192, 1);

  fnorm_k<<<1, 256, 0, stream>>>(fwm, W + OF_FN2);
  pstage_k<<<480, 256, 0, stream>>>(fwm, W + OF_E1, W + OF_E2, W + OF_R1, W + OF_R2, W + OF_R3, W + OF_PP);
  scan_k<<<NB, 1024, 0, stream>>>(W + OF_PP, W + OF_E1, W + OF_E2, W + OF_R1, W + OF_R2, W + OF_R3,
      W + OF_QE1, W + OF_QR1, W + OF_QR2, W + OF_QR3, W + OF_FN2, fwm, lng, lnb, Z, out);
}

// Round 6
// 324.204 us; speedup vs baseline: 2.2985x; 1.1577x over previous
//
#include <hip/hip_runtime.h>
#include <hip/hip_bf16.h>

// Sizes
#define NB 256
#define NS 30
#define NW 10
#define SYM 128
#define HID 512
#define ENT 64
#define ROLE 32

typedef unsigned short ushortT;
typedef __attribute__((ext_vector_type(8))) short short8v;   // 8 bf16 (4 VGPRs)
typedef __attribute__((ext_vector_type(4))) float f32x4;

// Workspace offsets (in floats; bf16 arrays use 2 elems per float slot)
static const size_t OF_SENTB = 0;         // 7680*128 bf16 -> 491520 fl
static const size_t OF_QEMBB = 491520;    // 256*128 bf16 -> 16384 fl
static const size_t OF_W1TS  = 507904;    // 5*512*128 bf16 -> 163840 fl
static const size_t OF_W2TES = 671744;    // 2*64*512 bf16 -> 32768 fl
static const size_t OF_W2TRS = 704512;    // 3*32*512 bf16 -> 24576 fl
static const size_t OF_W1TQ  = 729088;    // 4*512*128 bf16 -> 131072 fl
static const size_t OF_W2TEQ = 860160;    // 1*64*512 bf16 -> 16384 fl
static const size_t OF_W2TRQ = 876544;    // 3*32*512 bf16 -> 24576 fl
static const size_t OF_E1    = 901120;    // 7680*64 x2 (stride 491520)
static const size_t OF_R1    = 1884160;   // 7680*32 x3 (stride 245760)
static const size_t OF_QE1   = 2621440;   // 256*64
static const size_t OF_QR1   = 2637824;   // 256*32 x3 (stride 8192)
static const size_t OF_PP    = 2662400;   // 3 * 7680*64
static const size_t OF_FN2   = 4136960;   // 1

__device__ __forceinline__ ushortT f2bf(float x) {
  unsigned u = __float_as_uint(x);
  unsigned r = (u + 0x7fffu + ((u >> 16) & 1u)) >> 16;
  return (ushortT)r;
}
__device__ __forceinline__ void fma4(float4& d, float a, const float4& v) {
  d.x += a * v.x; d.y += a * v.y; d.z += a * v.z; d.w += a * v.w;
}
__device__ __forceinline__ float wreduce64(float v) {
  #pragma unroll
  for (int o = 32; o > 0; o >>= 1) v += __shfl_xor(v, o);
  return v;
}

// ---------------- embedding (bf16 out) ----------------
__global__ __launch_bounds__(128) void embed_k(const int* __restrict__ story, const int* __restrict__ query,
    const float* __restrict__ WE, const float* __restrict__ PE,
    ushortT* __restrict__ sentb, ushortT* __restrict__ qembb) {
  int bs = blockIdx.x; int e = threadIdx.x;
  const int* idx; ushortT* dst;
  if (bs < 7680) { idx = story + (size_t)bs * NW; dst = sentb + (size_t)bs * SYM; }
  else           { idx = query + (size_t)(bs - 7680) * NW; dst = qembb + (size_t)(bs - 7680) * SYM; }
  float acc = 0.f;
  #pragma unroll
  for (int w = 0; w < NW; ++w) {
    int t = idx[w];
    acc += WE[t * SYM + e] * PE[w * SYM + e];
  }
  dst[e] = f2bf(acc);
}

// ---------------- transpose + bf16 convert: src[h][R][C] f32 -> dst[h][C][R] bf16 ----------------
__global__ __launch_bounds__(256) void tcvt_k(const float* __restrict__ src, ushortT* __restrict__ dst,
    int R, int Cshift) {
  int h = blockIdx.y;
  int C = 1 << Cshift;
  size_t n = (size_t)R << Cshift;
  const float* s = src + (size_t)h * n;
  ushortT* d = dst + (size_t)h * n;
  for (size_t i = (size_t)blockIdx.x * 256 + threadIdx.x; i < n; i += (size_t)gridDim.x * 256) {
    size_t r = i >> Cshift; size_t c = i & (C - 1);
    d[c * R + r] = f2bf(s[i]);
  }
}

// ---------------- MFMA fused 2-layer MLP ----------------
// block = 32 rows x 1 head; 4 waves. GEMM1 (K=128) -> tanh -> bf16 H in LDS -> GEMM2 (K=512) -> tanh.
__global__ __launch_bounds__(256) void mlpm_k(
    const ushortT* __restrict__ Xb,                    // [rows][128] bf16
    const ushortT* __restrict__ W1T,                   // [nheads][512][128] bf16
    const float* __restrict__ eb1, const float* __restrict__ rb1,
    const ushortT* __restrict__ W2Te,                  // [eH][64][512] bf16
    const ushortT* __restrict__ W2Tr,                  // [rH][32][512] bf16
    const float* __restrict__ eb2, const float* __restrict__ rb2,
    float* __restrict__ Eout, size_t eostride,
    float* __restrict__ Rout, size_t rostride, int eHeads) {
  __shared__ __align__(16) ushortT Hl[32 * 520];       // 33.3 KB, stride 520 (16B-aligned rows)
  int r0 = blockIdx.x * 32, h = blockIdx.y, tid = threadIdx.x;
  int wave = tid >> 6, lane = tid & 63;
  int lrow = lane & 15;          // row (A/D) or col (B) within tile
  int kgrp = lane >> 4;          // 0..3
  bool isE = h < eHeads;
  int hh = isE ? h : h - eHeads;
  const ushortT* W1h = W1T + (size_t)h * 512 * 128;
  const float* b1 = (isE ? eb1 : rb1) + (size_t)hh * 512;

  int lrw = (wave & 1) * 16;               // local row base for this wave
  int cw  = (wave >> 1) * 256;             // GEMM1 col base

  // preload A fragments for full K=128 (4 K-steps), reused across 16 col-tiles
  short8v afr[4];
  const ushortT* arow = Xb + (size_t)(r0 + lrw + lrow) * 128 + kgrp * 8;
  #pragma unroll
  for (int kt = 0; kt < 4; ++kt)
    afr[kt] = *reinterpret_cast<const short8v*>(arow + kt * 32);

  // ---- GEMM1: 16 col-tiles of 16 ----
  for (int ct = 0; ct < 16; ++ct) {
    int c0 = cw + ct * 16;
    f32x4 acc = {0.f, 0.f, 0.f, 0.f};
    const ushortT* bcol = W1h + (size_t)(c0 + lrow) * 128 + kgrp * 8;
    #pragma unroll
    for (int kt = 0; kt < 4; ++kt) {
      short8v bfr = *reinterpret_cast<const short8v*>(bcol + kt * 32);
      acc = __builtin_amdgcn_mfma_f32_16x16x32_bf16(afr[kt], bfr, acc, 0, 0, 0);
    }
    int lcol = c0 + lrow;
    float bb = b1[lcol];
    #pragma unroll
    for (int i = 0; i < 4; ++i) {
      float hv = tanhf(acc[i] + bb);
      Hl[(lrw + kgrp * 4 + i) * 520 + lcol] = f2bf(hv);
    }
  }
  __syncthreads();

  // ---- GEMM2 ----
  if (isE) {   // O = 64: wave -> rows lrw..lrw+15, cols (wave>>1)*32 .. +31 (2 tiles)
    const ushortT* W2h = W2Te + (size_t)hh * 64 * 512;
    const float* b2 = eb2 + (size_t)hh * 64;
    int c0w = (wave >> 1) * 32;
    f32x4 acc[2] = {{0.f,0.f,0.f,0.f},{0.f,0.f,0.f,0.f}};
    for (int kt = 0; kt < 16; ++kt) {
      int kb = kt * 32 + kgrp * 8;
      short8v afr2 = *reinterpret_cast<const short8v*>(&Hl[(lrw + lrow) * 520 + kb]);
      #pragma unroll
      for (int t = 0; t < 2; ++t) {
        short8v bfr = *reinterpret_cast<const short8v*>(W2h + (size_t)(c0w + t * 16 + lrow) * 512 + kb);
        acc[t] = __builtin_amdgcn_mfma_f32_16x16x32_bf16(afr2, bfr, acc[t], 0, 0, 0);
      }
    }
    #pragma unroll
    for (int t = 0; t < 2; ++t) {
      int col = c0w + t * 16 + lrow;
      float bb = b2[col];
      #pragma unroll
      for (int i = 0; i < 4; ++i) {
        int grow = r0 + lrw + kgrp * 4 + i;
        Eout[(size_t)hh * eostride + (size_t)grow * 64 + col] = tanhf(acc[t][i] + bb);
      }
    }
  } else {     // O = 32: wave -> rows lrw.., col-tile (wave>>1)
    const ushortT* W2h = W2Tr + (size_t)hh * 32 * 512;
    const float* b2 = rb2 + (size_t)hh * 32;
    int c0w = (wave >> 1) * 16;
    f32x4 acc = {0.f, 0.f, 0.f, 0.f};
    for (int kt = 0; kt < 16; ++kt) {
      int kb = kt * 32 + kgrp * 8;
      short8v afr2 = *reinterpret_cast<const short8v*>(&Hl[(lrw + lrow) * 520 + kb]);
      short8v bfr = *reinterpret_cast<const short8v*>(W2h + (size_t)(c0w + lrow) * 512 + kb);
      acc = __builtin_amdgcn_mfma_f32_16x16x32_bf16(afr2, bfr, acc, 0, 0, 0);
    }
    int col = c0w + lrow;
    float bb = b2[col];
    #pragma unroll
    for (int i = 0; i < 4; ++i) {
      int grow = r0 + lrw + kgrp * 4 + i;
      Rout[(size_t)hh * rostride + (size_t)grow * 32 + col] = tanhf(acc[i] + bb);
    }
  }
}

// ---------------- ||fwm||^2 ----------------
__global__ __launch_bounds__(256) void fnorm_k(const float* __restrict__ fwm, float* __restrict__ o) {
  __shared__ float red[4];
  int tid = threadIdx.x;
  const float4* f4 = reinterpret_cast<const float4*>(fwm);
  float a = 0.f;
  for (int i = tid; i < 32768; i += 256) {
    float4 v = f4[i];
    a += v.x*v.x + v.y*v.y + v.z*v.z + v.w*v.w;
  }
  #pragma unroll
  for (int off = 32; off > 0; off >>= 1) a += __shfl_down(a, off);
  if ((tid & 63) == 0) red[tid >> 6] = a;
  __syncthreads();
  if (tid == 0) o[0] = red[0] + red[1] + red[2] + red[3];
}

// ---------------- P-stage ----------------
__global__ __launch_bounds__(256) void pstage_k(const float* __restrict__ fwm,
    const float* __restrict__ e1g, const float* __restrict__ e2g,
    const float* __restrict__ r1g, const float* __restrict__ r2g, const float* __restrict__ r3g,
    float* __restrict__ Pp) {
  __shared__ float fwmT[8192];
  __shared__ float e1t[16 * 65], e2t[16 * 65];
  __shared__ float r1t[512], r2t[512], r3t[512];
  int rb = blockIdx.x, tid = threadIdx.x;
  int row = tid >> 4, fo = tid & 15;
  for (int i = tid; i < 1024; i += 256) {
    int rr = i >> 6, e = i & 63;
    e1t[rr * 65 + e] = e1g[((size_t)rb * 16 + rr) * 64 + e];
    e2t[rr * 65 + e] = e2g[((size_t)rb * 16 + rr) * 64 + e];
  }
  for (int i = tid; i < 512; i += 256) {
    r1t[i] = r1g[((size_t)rb * 16 + (i >> 5)) * 32 + (i & 31)];
    r2t[i] = r2g[((size_t)rb * 16 + (i >> 5)) * 32 + (i & 31)];
    r3t[i] = r3g[((size_t)rb * 16 + (i >> 5)) * 32 + (i & 31)];
  }
  float4 P1a = {0,0,0,0}, P2a = {0,0,0,0}, P3a = {0,0,0,0};
  const float4* fwm4 = reinterpret_cast<const float4*>(fwm);
  float4* fT4 = reinterpret_cast<float4*>(fwmT);
  for (int g = 0; g < 4; ++g) {
    for (int sub = 0; sub < 4; ++sub) {
      __syncthreads();
      for (int i = tid; i < 2048; i += 256) {
        int e = i >> 5, c4 = i & 31;
        fT4[i] = fwm4[(size_t)e * 512 + g * 128 + sub * 32 + c4];
      }
      __syncthreads();
      float4 t10 = {0,0,0,0}, t11 = {0,0,0,0}, t20 = {0,0,0,0}, t21 = {0,0,0,0};
      #pragma unroll 8
      for (int e = 0; e < 64; ++e) {
        float w1 = e1t[row * 65 + e], w2 = e2t[row * 65 + e];
        float4 va = fT4[e * 32 + fo], vb = fT4[e * 32 + 16 + fo];
        fma4(t10, w1, va); fma4(t11, w1, vb);
        fma4(t20, w2, va); fma4(t21, w2, vb);
      }
      int rl = g * 8 + sub * 2;
      float a0 = r1t[row * 32 + rl], a1 = r1t[row * 32 + rl + 1];
      float b0 = r2t[row * 32 + rl], b1 = r2t[row * 32 + rl + 1];
      float c0 = r3t[row * 32 + rl], c1 = r3t[row * 32 + rl + 1];
      fma4(P1a, a0, t10); fma4(P1a, a1, t11);
      fma4(P2a, b0, t10); fma4(P2a, b1, t11);
      fma4(P3a, c0, t20); fma4(P3a, c1, t21);
    }
  }
  float4* Pp4 = reinterpret_cast<float4*>(Pp);
  size_t base = ((size_t)rb * 16 + row) * 16 + fo;
  Pp4[base] = P1a;
  Pp4[122880 + base] = P2a;
  Pp4[245760 + base] = P3a;
}

// ---------------- scan + inference (1024 threads, gram fused, dt2-free norm) ----------------
__global__ __launch_bounds__(1024, 4) void scan_k(
    const float* __restrict__ Pp,
    const float* __restrict__ e1g, const float* __restrict__ e2g,
    const float* __restrict__ r1g, const float* __restrict__ r2g, const float* __restrict__ r3g,
    const float* __restrict__ qe1g, const float* __restrict__ qr1g, const float* __restrict__ qr2g,
    const float* __restrict__ qr3g, const float* __restrict__ fn2p, const float* __restrict__ fwm,
    const float* __restrict__ lng, const float* __restrict__ lnb, const float* __restrict__ Zg,
    float* __restrict__ out) {
  __shared__ float ML[8100];
  __shared__ float e1L[1980], e2L[1980];
  __shared__ float v1L[1980], v2L[1980], v3L[1980];
  __shared__ float r1L[990], r2L[990], r3L[990];
  __shared__ float uv[64], qv[32], alf[96], siL[64];
  __shared__ float redL[16], scal[2];
  int b = blockIdx.x, tid = threadIdx.x;
  int s = tid >> 5, fo = tid & 31;
  bool act = s < 30;
  int off = s * 66 + fo * 2;

  float H1[2], H2[2], H3[2], a1[2], a2[2], a3[2];
  #pragma unroll
  for (int j = 0; j < 2; ++j) { H1[j]=0; H2[j]=0; H3[j]=0; a1[j]=0; a2[j]=0; a3[j]=0; }
  if (act) {
    size_t base = ((size_t)b * 30 + s) * 64 + fo * 2;
    #pragma unroll
    for (int j = 0; j < 2; ++j) {
      H1[j] = Pp[base + j];
      H2[j] = Pp[491520 + base + j];
      H3[j] = Pp[983040 + base + j];
    }
  }
  for (int i = tid; i < 1920; i += 1024) {
    int ss = i >> 6, e = i & 63;
    e1L[ss * 66 + e] = e1g[(size_t)b * 1920 + i];
    e2L[ss * 66 + e] = e2g[(size_t)b * 1920 + i];
  }
  for (int i = tid; i < 960; i += 1024) {
    int ss = i >> 5, rr = i & 31;
    r1L[ss * 33 + rr] = r1g[(size_t)b * 960 + i];
    r2L[ss * 33 + rr] = r2g[(size_t)b * 960 + i];
    r3L[ss * 33 + rr] = r3g[(size_t)b * 960 + i];
  }
  __syncthreads();

  if (tid < 900) {
    int si = tid / 30, sj = tid - si * 30;
    float g11 = 0, g12 = 0, g21 = 0, g22 = 0;
    for (int e = 0; e < 64; ++e) {
      float A1 = e1L[si * 66 + e], A2 = e2L[si * 66 + e];
      float C1 = e1L[sj * 66 + e], C2 = e2L[sj * 66 + e];
      g11 += A1 * C1; g12 += A1 * C2; g21 += A2 * C1; g22 += A2 * C2;
    }
    float R11=0,R12=0,R13=0,R21=0,R22=0,R23=0,R31=0,R32=0,R33=0;
    for (int r = 0; r < 32; ++r) {
      float x1 = r1L[si * 33 + r], x2 = r2L[si * 33 + r], x3 = r3L[si * 33 + r];
      float y1 = r1L[sj * 33 + r], y2 = r2L[sj * 33 + r], y3 = r3L[sj * 33 + r];
      R11 += x1*y1; R12 += x1*y2; R13 += x1*y3;
      R21 += x2*y1; R22 += x2*y2; R23 += x2*y3;
      R31 += x3*y1; R32 += x3*y2; R33 += x3*y3;
    }
    ML[tid]        = g11 * R11;
    ML[900 + tid]  = g11 * R12;
    ML[1800 + tid] = g12 * R13;
    ML[2700 + tid] = g11 * R21;
    ML[3600 + tid] = g11 * R22;
    ML[4500 + tid] = g12 * R23;
    ML[5400 + tid] = g21 * R31;
    ML[6300 + tid] = g21 * R32;
    ML[7200 + tid] = g22 * R33;
  }
  __syncthreads();

  float n2 = fn2p[0], c0v = 1.f;
  for (int layer = 0; layer < 3; ++layer) {
    float w[2], H2s[2], H3s[2], v1r[2], v2r[2], v3r[2];
    if (act) {
      #pragma unroll
      for (int j = 0; j < 2; ++j) {
        w[j] = H1[j]; H2s[j] = H2[j]; H3s[j] = H3[j];
        v1r[j] = e2L[off + j] - H1[j];
        v1L[off + j] = v1r[j];
      }
    }
    __syncthreads();
    if (act) {
      const float* MLs = ML + s * 30;
      for (int sp = 0; sp < 30; ++sp) {
        float m1 = MLs[sp], m2 = MLs[2700 + sp], m3 = MLs[5400 + sp];
        const float* vv = &v1L[sp * 66 + fo * 2];
        #pragma unroll
        for (int j = 0; j < 2; ++j) { float x = vv[j]; H1[j] += m1 * x; H2[j] += m2 * x; H3[j] += m3 * x; }
      }
      #pragma unroll
      for (int j = 0; j < 2; ++j) { v2r[j] = w[j] - H2[j]; v2L[off + j] = v2r[j]; }
    }
    __syncthreads();
    if (act) {
      const float* MLs = ML + s * 30;
      for (int sp = 0; sp < 30; ++sp) {
        float m1 = MLs[900 + sp], m2 = MLs[3600 + sp], m3 = MLs[6300 + sp];
        const float* vv = &v2L[sp * 66 + fo * 2];
        #pragma unroll
        for (int j = 0; j < 2; ++j) { float x = vv[j]; H1[j] += m1 * x; H2[j] += m2 * x; H3[j] += m3 * x; }
      }
      #pragma unroll
      for (int j = 0; j < 2; ++j) { v3r[j] = e1L[off + j] - H3[j]; v3L[off + j] = v3r[j]; }
    }
    __syncthreads();
    float local = 0.f;
    if (act) {
      const float* MLs = ML + s * 30;
      for (int sp = 0; sp < 30; ++sp) {
        float m1 = MLs[1800 + sp], m2 = MLs[4500 + sp], m3 = MLs[7200 + sp];
        const float* vv = &v3L[sp * 66 + fo * 2];
        #pragma unroll
        for (int j = 0; j < 2; ++j) { float x = vv[j]; H1[j] += m1 * x; H2[j] += m2 * x; H3[j] += m3 * x; }
      }
      #pragma unroll
      for (int j = 0; j < 2; ++j) {
        a1[j] += v1r[j]; a2[j] += v2r[j]; a3[j] += v3r[j];
        local += v1r[j] * (w[j] + H1[j]) + v2r[j] * (H2s[j] + H2[j]) + v3r[j] * (H3s[j] + H3[j]);
      }
    }
    local = wreduce64(local);
    if ((tid & 63) == 0) redL[tid >> 6] = local;
    __syncthreads();
    if (tid == 0) {
      float tot = n2;
      #pragma unroll
      for (int i = 0; i < 16; ++i) tot += redL[i];
      float fn = fmaxf(sqrtf(tot), 1.f);
      scal[0] = 1.f / fn; scal[1] = tot;
    }
    __syncthreads();
    float inv = scal[0]; n2 = scal[1] * inv * inv; c0v *= inv;
    if (act) {
      #pragma unroll
      for (int j = 0; j < 2; ++j) { H1[j]*=inv; H2[j]*=inv; H3[j]*=inv; a1[j]*=inv; a2[j]*=inv; a3[j]*=inv; }
    }
    __syncthreads();
  }

  if (act) {
    #pragma unroll
    for (int j = 0; j < 2; ++j) { v1L[off + j] = a1[j]; v2L[off + j] = a2[j]; v3L[off + j] = a3[j]; }
  }
  if (tid < 64) { uv[tid] = qe1g[(size_t)b * 64 + tid]; siL[tid] = 0.f; }
  __syncthreads();
  float* zL = ML;
  for (int st = 0; st < 3; ++st) {
    const float* qrg = (st == 0) ? qr1g : ((st == 1) ? qr2g : qr3g);
    if (tid < 32) qv[tid] = qrg[(size_t)b * 32 + tid];
    __syncthreads();
    if (act) {
      int k = fo;
      float u0 = uv[k], u1 = uv[k + 32];
      float eu1 = e1L[s * 66 + k] * u0 + e1L[s * 66 + k + 32] * u1;
      float eu2 = e2L[s * 66 + k] * u0 + e2L[s * 66 + k + 32] * u1;
      float rq1 = r1L[s * 33 + k] * qv[k];
      float rq2 = r2L[s * 33 + k] * qv[k];
      float rq3 = r3L[s * 33 + k] * qv[k];
      #pragma unroll
      for (int d = 16; d > 0; d >>= 1) {
        eu1 += __shfl_down(eu1, d, 32); eu2 += __shfl_down(eu2, d, 32);
        rq1 += __shfl_down(rq1, d, 32); rq2 += __shfl_down(rq2, d, 32); rq3 += __shfl_down(rq3, d, 32);
      }
      if (k == 0) { alf[s] = eu1 * rq1; alf[32 + s] = eu1 * rq2; alf[64 + s] = eu2 * rq3; }
    }
    float z[2] = {0.f, 0.f};
    {
      const float* fb = fwm + s * 64 + fo * 2;
      for (int e = 0; e < 64; ++e) {
        float u = uv[e];
        const float* fr = fb + (size_t)e * 2048;
        z[0] += u * fr[0]; z[1] += u * fr[1];
      }
    }
    {
      float q = qv[s];
      zL[s * 66 + fo * 2]     = q * z[0];
      zL[s * 66 + fo * 2 + 1] = q * z[1];
    }
    __syncthreads();
    if (tid < 64) {
      float F = 0.f;
      for (int rr = 0; rr < 32; ++rr) F += zL[rr * 66 + tid];
      float raw = c0v * F;
      for (int sp = 0; sp < 30; ++sp)
        raw += alf[sp] * v1L[sp * 66 + tid] + alf[32 + sp] * v2L[sp * 66 + tid] + alf[64 + sp] * v3L[sp * 66 + tid];
      float mean = wreduce64(raw) * (1.f / 64.f);
      float d = raw - mean;
      float var = wreduce64(d * d) * (1.f / 63.f);
      float y = lng[st * 64 + tid] * d / (sqrtf(var) + 1e-6f) + lnb[st * 64 + tid];
      siL[tid] += y;
      uv[tid] = y;
    }
    __syncthreads();
  }
  if (tid < 9) {
    float o = 0.f;
    for (int ff = 0; ff < 64; ++ff) o += siL[ff] * Zg[ff * 9 + tid];
    out[(size_t)b * 9 + tid] = o;
  }
}

extern "C" void kernel_launch(void* const* d_in, const int* in_sizes, int n_in,
                              void* d_out, int out_size, void* d_ws, size_t ws_size,
                              hipStream_t stream) {
  const int*   story = (const int*)d_in[0];
  const int*   query = (const int*)d_in[1];
  const float* WE    = (const float*)d_in[2];
  const float* PE    = (const float*)d_in[3];
  const float* ueW1  = (const float*)d_in[4];
  const float* ueb1  = (const float*)d_in[5];
  const float* ueW2  = (const float*)d_in[6];
  const float* ueb2  = (const float*)d_in[7];
  const float* urW1  = (const float*)d_in[8];
  const float* urb1  = (const float*)d_in[9];
  const float* urW2  = (const float*)d_in[10];
  const float* urb2  = (const float*)d_in[11];
  const float* fwm   = (const float*)d_in[12];
  const float* ieW1  = (const float*)d_in[13];
  const float* ieb1  = (const float*)d_in[14];
  const float* ieW2  = (const float*)d_in[15];
  const float* ieb2  = (const float*)d_in[16];
  const float* irW1  = (const float*)d_in[17];
  const float* irb1  = (const float*)d_in[18];
  const float* irW2  = (const float*)d_in[19];
  const float* irb2  = (const float*)d_in[20];
  const float* lng   = (const float*)d_in[21];
  const float* lnb   = (const float*)d_in[22];
  const float* Z     = (const float*)d_in[23];
  float* W = (float*)d_ws;
  float* out = (float*)d_out;

  ushortT* sentB = (ushortT*)(W + OF_SENTB);
  ushortT* qembB = (ushortT*)(W + OF_QEMBB);
  ushortT* W1TS  = (ushortT*)(W + OF_W1TS);
  ushortT* W2TES = (ushortT*)(W + OF_W2TES);
  ushortT* W2TRS = (ushortT*)(W + OF_W2TRS);
  ushortT* W1TQ  = (ushortT*)(W + OF_W1TQ);
  ushortT* W2TEQ = (ushortT*)(W + OF_W2TEQ);
  ushortT* W2TRQ = (ushortT*)(W + OF_W2TRQ);

  embed_k<<<7936, 128, 0, stream>>>(story, query, WE, PE, sentB, qembB);

  // weight convert+transpose (bf16): story then query (query e-head: only head 0 of ie)
  tcvt_k<<<dim3(64, 2), 256, 0, stream>>>(ueW1, W1TS,               128, 9);
  tcvt_k<<<dim3(64, 3), 256, 0, stream>>>(urW1, W1TS + 2 * 65536,   128, 9);
  tcvt_k<<<dim3(32, 2), 256, 0, stream>>>(ueW2, W2TES,              512, 6);
  tcvt_k<<<dim3(16, 3), 256, 0, stream>>>(urW2, W2TRS,              512, 5);
  tcvt_k<<<dim3(64, 1), 256, 0, stream>>>(ieW1, W1TQ,               128, 9);
  tcvt_k<<<dim3(64, 3), 256, 0, stream>>>(irW1, W1TQ + 65536,       128, 9);
  tcvt_k<<<dim3(32, 1), 256, 0, stream>>>(ieW2, W2TEQ,              512, 6);
  tcvt_k<<<dim3(16, 3), 256, 0, stream>>>(irW2, W2TRQ,              512, 5);

  // MFMA MLPs: story (5 heads), query (4 heads)
  mlpm_k<<<dim3(240, 5), 256, 0, stream>>>(sentB, W1TS, ueb1, urb1, W2TES, W2TRS, ueb2, urb2,
      W + OF_E1, 491520, W + OF_R1, 245760, 2);
  mlpm_k<<<dim3(8, 4), 256, 0, stream>>>(qembB, W1TQ, ieb1, irb1, W2TEQ, W2TRQ, ieb2, irb2,
      W + OF_QE1, 16384, W + OF_QR1, 8192, 1);

  fnorm_k<<<1, 256, 0, stream>>>(fwm, W + OF_FN2);
  pstage_k<<<480, 256, 0, stream>>>(fwm, W + OF_E1, W + OF_E1 + 491520,
      W + OF_R1, W + OF_R1 + 245760, W + OF_R1 + 2 * 245760, W + OF_PP);
  scan_k<<<NB, 1024, 0, stream>>>(W + OF_PP, W + OF_E1, W + OF_E1 + 491520,
      W + OF_R1, W + OF_R1 + 245760, W + OF_R1 + 2 * 245760,
      W + OF_QE1, W + OF_QR1, W + OF_QR1 + 8192, W + OF_QR1 + 16384, W + OF_FN2, fwm, lng, lnb, Z, out);
}

// Round 7
// 273.599 us; speedup vs baseline: 2.7237x; 1.1850x over previous
//
#include <hip/hip_runtime.h>
#include <hip/hip_bf16.h>

// Sizes
#define NB 256
#define NS 30
#define NW 10
#define SYM 128
#define HID 512
#define ENT 64
#define ROLE 32

typedef unsigned short ushortT;
typedef __attribute__((ext_vector_type(8))) short short8v;   // 8 bf16
typedef __attribute__((ext_vector_type(4))) float f32x4;

// Workspace offsets (floats; bf16 arrays use 2 elems per float slot)
static const size_t OF_SENTB = 0;         // 7680*128 bf16 -> 491520 fl
static const size_t OF_QEMBB = 491520;    // 256*128 bf16 -> 16384 fl
static const size_t OF_W1A   = 507904;    // 9*512*128 bf16 -> 294912 fl
static const size_t OF_W2TE  = 802816;    // 3*64*512 bf16 -> 49152 fl
static const size_t OF_W2TR  = 851968;    // 6*32*512 bf16 -> 49152 fl
static const size_t OF_E1    = 901120;    // 7680*64 x2 (stride 491520)
static const size_t OF_R1    = 1884160;   // 7680*32 x3 (stride 245760)
static const size_t OF_QE1   = 2621440;   // 256*64
static const size_t OF_QR1   = 2637824;   // 256*32 x3 (stride 8192)
static const size_t OF_PP    = 2662400;   // 3 * 7680*64
static const size_t OF_FN2   = 4136960;   // 8 partials

__device__ __forceinline__ ushortT f2bf(float x) {
  unsigned u = __float_as_uint(x);
  unsigned r = (u + 0x7fffu + ((u >> 16) & 1u)) >> 16;
  return (ushortT)r;
}
__device__ __forceinline__ void fma4(float4& d, float a, const float4& v) {
  d.x += a * v.x; d.y += a * v.y; d.z += a * v.z; d.w += a * v.w;
}
__device__ __forceinline__ float dot4(const float4& a, const float4& b) {
  return a.x * b.x + a.y * b.y + a.z * b.z + a.w * b.w;
}
__device__ __forceinline__ float wreduce64(float v) {
  #pragma unroll
  for (int o = 32; o > 0; o >>= 1) v += __shfl_xor(v, o);
  return v;
}

// ---------------- embedding (bf16 out) ----------------
__global__ __launch_bounds__(128) void embed_k(const int* __restrict__ story, const int* __restrict__ query,
    const float* __restrict__ WE, const float* __restrict__ PE,
    ushortT* __restrict__ sentb, ushortT* __restrict__ qembb) {
  int bs = blockIdx.x; int e = threadIdx.x;
  const int* idx; ushortT* dst;
  if (bs < 7680) { idx = story + (size_t)bs * NW; dst = sentb + (size_t)bs * SYM; }
  else           { idx = query + (size_t)(bs - 7680) * NW; dst = qembb + (size_t)(bs - 7680) * SYM; }
  float acc = 0.f;
  #pragma unroll
  for (int w = 0; w < NW; ++w) {
    int t = idx[w];
    acc += WE[t * SYM + e] * PE[w * SYM + e];
  }
  dst[e] = f2bf(acc);
}

// ---------------- W1 transpose+convert: 9 heads [128][512] f32 -> [512][128] bf16 ----------------
__global__ __launch_bounds__(256) void tcvt1_k(const float* __restrict__ ueW1, const float* __restrict__ urW1,
    const float* __restrict__ ieW1, const float* __restrict__ irW1, ushortT* __restrict__ dst) {
  int y = blockIdx.y;
  const float* src = (y < 2) ? ueW1 + (size_t)y * 65536
                   : (y < 5) ? urW1 + (size_t)(y - 2) * 65536
                   : (y == 5) ? ieW1
                   : irW1 + (size_t)(y - 6) * 65536;
  ushortT* d = dst + (size_t)y * 65536;
  for (int i = blockIdx.x * 256 + threadIdx.x; i < 65536; i += gridDim.x * 256) {
    int r = i >> 9, c = i & 511;
    d[c * 128 + r] = f2bf(src[i]);
  }
}

// ---------------- W2 transpose+convert: y<3 e-heads [512][64]->[64][512]; y>=3 r-heads [512][32]->[32][512] ----------------
__global__ __launch_bounds__(256) void tcvt2_k(const float* __restrict__ ueW2, const float* __restrict__ urW2,
    const float* __restrict__ ieW2, const float* __restrict__ irW2,
    ushortT* __restrict__ dstE, ushortT* __restrict__ dstR) {
  int y = blockIdx.y;
  if (y < 3) {
    const float* src = (y < 2) ? ueW2 + (size_t)y * 32768 : ieW2;
    ushortT* d = dstE + (size_t)y * 32768;
    for (int i = blockIdx.x * 256 + threadIdx.x; i < 32768; i += gridDim.x * 256) {
      int r = i >> 6, c = i & 63;
      d[c * 512 + r] = f2bf(src[i]);
    }
  } else {
    int yy = y - 3;
    const float* src = (yy < 3) ? urW2 + (size_t)yy * 16384 : irW2 + (size_t)(yy - 3) * 16384;
    ushortT* d = dstR + (size_t)yy * 16384;
    for (int i = blockIdx.x * 256 + threadIdx.x; i < 16384; i += gridDim.x * 256) {
      int r = i >> 5, c = i & 31;
      d[c * 512 + r] = f2bf(src[i]);
    }
  }
}

// ---------------- MFMA fused 2-layer MLP ----------------
__global__ __launch_bounds__(256) void mlpm_k(
    const ushortT* __restrict__ Xb,
    const ushortT* __restrict__ W1T,
    const float* __restrict__ eb1, const float* __restrict__ rb1,
    const ushortT* __restrict__ W2Te,
    const ushortT* __restrict__ W2Tr,
    const float* __restrict__ eb2, const float* __restrict__ rb2,
    float* __restrict__ Eout, size_t eostride,
    float* __restrict__ Rout, size_t rostride, int eHeads) {
  __shared__ __align__(16) ushortT Hl[32 * 520];
  int r0 = blockIdx.x * 32, h = blockIdx.y, tid = threadIdx.x;
  int wave = tid >> 6, lane = tid & 63;
  int lrow = lane & 15;
  int kgrp = lane >> 4;
  bool isE = h < eHeads;
  int hh = isE ? h : h - eHeads;
  const ushortT* W1h = W1T + (size_t)h * 512 * 128;
  const float* b1 = (isE ? eb1 : rb1) + (size_t)hh * 512;

  int lrw = (wave & 1) * 16;
  int cw  = (wave >> 1) * 256;

  short8v afr[4];
  const ushortT* arow = Xb + (size_t)(r0 + lrw + lrow) * 128 + kgrp * 8;
  #pragma unroll
  for (int kt = 0; kt < 4; ++kt)
    afr[kt] = *reinterpret_cast<const short8v*>(arow + kt * 32);

  for (int ct = 0; ct < 16; ++ct) {
    int c0 = cw + ct * 16;
    f32x4 acc = {0.f, 0.f, 0.f, 0.f};
    const ushortT* bcol = W1h + (size_t)(c0 + lrow) * 128 + kgrp * 8;
    #pragma unroll
    for (int kt = 0; kt < 4; ++kt) {
      short8v bfr = *reinterpret_cast<const short8v*>(bcol + kt * 32);
      acc = __builtin_amdgcn_mfma_f32_16x16x32_bf16(afr[kt], bfr, acc, 0, 0, 0);
    }
    int lcol = c0 + lrow;
    float bb = b1[lcol];
    #pragma unroll
    for (int i = 0; i < 4; ++i) {
      float hv = tanhf(acc[i] + bb);
      Hl[(lrw + kgrp * 4 + i) * 520 + lcol] = f2bf(hv);
    }
  }
  __syncthreads();

  if (isE) {
    const ushortT* W2h = W2Te + (size_t)hh * 64 * 512;
    const float* b2 = eb2 + (size_t)hh * 64;
    int c0w = (wave >> 1) * 32;
    f32x4 acc[2] = {{0.f,0.f,0.f,0.f},{0.f,0.f,0.f,0.f}};
    for (int kt = 0; kt < 16; ++kt) {
      int kb = kt * 32 + kgrp * 8;
      short8v afr2 = *reinterpret_cast<const short8v*>(&Hl[(lrw + lrow) * 520 + kb]);
      #pragma unroll
      for (int t = 0; t < 2; ++t) {
        short8v bfr = *reinterpret_cast<const short8v*>(W2h + (size_t)(c0w + t * 16 + lrow) * 512 + kb);
        acc[t] = __builtin_amdgcn_mfma_f32_16x16x32_bf16(afr2, bfr, acc[t], 0, 0, 0);
      }
    }
    #pragma unroll
    for (int t = 0; t < 2; ++t) {
      int col = c0w + t * 16 + lrow;
      float bb = b2[col];
      #pragma unroll
      for (int i = 0; i < 4; ++i) {
        int grow = r0 + lrw + kgrp * 4 + i;
        Eout[(size_t)hh * eostride + (size_t)grow * 64 + col] = tanhf(acc[t][i] + bb);
      }
    }
  } else {
    const ushortT* W2h = W2Tr + (size_t)hh * 32 * 512;
    const float* b2 = rb2 + (size_t)hh * 32;
    int c0w = (wave >> 1) * 16;
    f32x4 acc = {0.f, 0.f, 0.f, 0.f};
    for (int kt = 0; kt < 16; ++kt) {
      int kb = kt * 32 + kgrp * 8;
      short8v afr2 = *reinterpret_cast<const short8v*>(&Hl[(lrw + lrow) * 520 + kb]);
      short8v bfr = *reinterpret_cast<const short8v*>(W2h + (size_t)(c0w + lrow) * 512 + kb);
      acc = __builtin_amdgcn_mfma_f32_16x16x32_bf16(afr2, bfr, acc, 0, 0, 0);
    }
    int col = c0w + lrow;
    float bb = b2[col];
    #pragma unroll
    for (int i = 0; i < 4; ++i) {
      int grow = r0 + lrw + kgrp * 4 + i;
      Rout[(size_t)hh * rostride + (size_t)grow * 32 + col] = tanhf(acc[i] + bb);
    }
  }
}

// ---------------- ||fwm||^2 partials (8 blocks) ----------------
__global__ __launch_bounds__(256) void fnorm_k(const float* __restrict__ fwm, float* __restrict__ o) {
  __shared__ float red[4];
  int tid = threadIdx.x;
  const float4* f4 = reinterpret_cast<const float4*>(fwm) + blockIdx.x * 4096;
  float a = 0.f;
  for (int i = tid; i < 4096; i += 256) {
    float4 v = f4[i];
    a += v.x*v.x + v.y*v.y + v.z*v.z + v.w*v.w;
  }
  #pragma unroll
  for (int off = 32; off > 0; off >>= 1) a += __shfl_down(a, off);
  if ((tid & 63) == 0) red[tid >> 6] = a;
  __syncthreads();
  if (tid == 0) o[blockIdx.x] = red[0] + red[1] + red[2] + red[3];
}

// ---------------- P-stage ----------------
__global__ __launch_bounds__(256) void pstage_k(const float* __restrict__ fwm,
    const float* __restrict__ e1g, const float* __restrict__ e2g,
    const float* __restrict__ r1g, const float* __restrict__ r2g, const float* __restrict__ r3g,
    float* __restrict__ Pp) {
  __shared__ float fwmT[8192];
  __shared__ float e1t[16 * 65], e2t[16 * 65];
  __shared__ float r1t[512], r2t[512], r3t[512];
  int rb = blockIdx.x, tid = threadIdx.x;
  int row = tid >> 4, fo = tid & 15;
  for (int i = tid; i < 1024; i += 256) {
    int rr = i >> 6, e = i & 63;
    e1t[rr * 65 + e] = e1g[((size_t)rb * 16 + rr) * 64 + e];
    e2t[rr * 65 + e] = e2g[((size_t)rb * 16 + rr) * 64 + e];
  }
  for (int i = tid; i < 512; i += 256) {
    r1t[i] = r1g[((size_t)rb * 16 + (i >> 5)) * 32 + (i & 31)];
    r2t[i] = r2g[((size_t)rb * 16 + (i >> 5)) * 32 + (i & 31)];
    r3t[i] = r3g[((size_t)rb * 16 + (i >> 5)) * 32 + (i & 31)];
  }
  float4 P1a = {0,0,0,0}, P2a = {0,0,0,0}, P3a = {0,0,0,0};
  const float4* fwm4 = reinterpret_cast<const float4*>(fwm);
  float4* fT4 = reinterpret_cast<float4*>(fwmT);
  for (int g = 0; g < 4; ++g) {
    for (int sub = 0; sub < 4; ++sub) {
      __syncthreads();
      for (int i = tid; i < 2048; i += 256) {
        int e = i >> 5, c4 = i & 31;
        fT4[i] = fwm4[(size_t)e * 512 + g * 128 + sub * 32 + c4];
      }
      __syncthreads();
      float4 t10 = {0,0,0,0}, t11 = {0,0,0,0}, t20 = {0,0,0,0}, t21 = {0,0,0,0};
      #pragma unroll 8
      for (int e = 0; e < 64; ++e) {
        float w1 = e1t[row * 65 + e], w2 = e2t[row * 65 + e];
        float4 va = fT4[e * 32 + fo], vb = fT4[e * 32 + 16 + fo];
        fma4(t10, w1, va); fma4(t11, w1, vb);
        fma4(t20, w2, va); fma4(t21, w2, vb);
      }
      int rl = g * 8 + sub * 2;
      float a0 = r1t[row * 32 + rl], a1 = r1t[row * 32 + rl + 1];
      float b0 = r2t[row * 32 + rl], b1 = r2t[row * 32 + rl + 1];
      float c0 = r3t[row * 32 + rl], c1 = r3t[row * 32 + rl + 1];
      fma4(P1a, a0, t10); fma4(P1a, a1, t11);
      fma4(P2a, b0, t10); fma4(P2a, b1, t11);
      fma4(P3a, c0, t20); fma4(P3a, c1, t21);
    }
  }
  float4* Pp4 = reinterpret_cast<float4*>(Pp);
  size_t base = ((size_t)rb * 16 + row) * 16 + fo;
  Pp4[base] = P1a;
  Pp4[122880 + base] = P2a;
  Pp4[245760 + base] = P3a;
}

// ---------------- scan + inference ----------------
// 1024 threads: s = tid>>5, g = (tid>>4)&1 (sp-split halves), fo = tid&15 (4 f each).
// MP[phase][s][sp][4] packed M-triples: 1 b128 m-read + 1 b128 v-read per iter.
__global__ __launch_bounds__(1024) void scan_k(
    const float* __restrict__ Pp,
    const float* __restrict__ e1g, const float* __restrict__ e2g,
    const float* __restrict__ r1g, const float* __restrict__ r2g, const float* __restrict__ r3g,
    const float* __restrict__ qe1g, const float* __restrict__ qr1g, const float* __restrict__ qr2g,
    const float* __restrict__ qr3g, const float* __restrict__ fn2p, const float* __restrict__ fwm,
    const float* __restrict__ lng, const float* __restrict__ lnb, const float* __restrict__ Zg,
    float* __restrict__ out) {
  __shared__ __align__(16) float MPL[10800];            // 3 x [30][30][4]; reused as zL
  __shared__ __align__(16) float e1L[2040], e2L[2040];  // [30][68]
  __shared__ __align__(16) float v1L[2040], v2L[2040], v3L[2040];
  __shared__ __align__(16) float r1L[1080], r2L[1080], r3L[1080];  // [30][36]
  __shared__ float uv[64], qv[32], alf[96], siL[64];
  __shared__ float redL[16], scal[2];
  int b = blockIdx.x, tid = threadIdx.x;
  int s = tid >> 5, g = (tid >> 4) & 1, fo = tid & 15;
  int fq = fo * 4;
  bool act = s < 30;                     // wave-uniform

  float H1[4], H2[4], H3[4], a1[4], a2[4], a3[4];
  #pragma unroll
  for (int j = 0; j < 4; ++j) { H1[j]=0; H2[j]=0; H3[j]=0; a1[j]=0; a2[j]=0; a3[j]=0; }
  if (act) {
    size_t base = (size_t)b * 1920 + s * 64 + fq;
    float4 h1 = *reinterpret_cast<const float4*>(Pp + base);
    float4 h2 = *reinterpret_cast<const float4*>(Pp + 491520 + base);
    float4 h3 = *reinterpret_cast<const float4*>(Pp + 983040 + base);
    H1[0]=h1.x; H1[1]=h1.y; H1[2]=h1.z; H1[3]=h1.w;
    H2[0]=h2.x; H2[1]=h2.y; H2[2]=h2.z; H2[3]=h2.w;
    H3[0]=h3.x; H3[1]=h3.y; H3[2]=h3.z; H3[3]=h3.w;
  }
  for (int i = tid; i < 1920; i += 1024) {
    int ss = i >> 6, e = i & 63;
    e1L[ss * 68 + e] = e1g[(size_t)b * 1920 + i];
    e2L[ss * 68 + e] = e2g[(size_t)b * 1920 + i];
  }
  for (int i = tid; i < 960; i += 1024) {
    int ss = i >> 5, rr = i & 31;
    r1L[ss * 36 + rr] = r1g[(size_t)b * 960 + i];
    r2L[ss * 36 + rr] = r2g[(size_t)b * 960 + i];
    r3L[ss * 36 + rr] = r3g[(size_t)b * 960 + i];
  }
  __syncthreads();

  // ---- fused gram -> packed MP (direct, no transposed reads later) ----
  if (tid < 900) {
    int si = tid / 30, sj = tid - si * 30;
    float g11 = 0, g12 = 0, g21 = 0, g22 = 0;
    {
      const float4* A1 = reinterpret_cast<const float4*>(&e1L[si * 68]);
      const float4* A2 = reinterpret_cast<const float4*>(&e2L[si * 68]);
      const float4* C1 = reinterpret_cast<const float4*>(&e1L[sj * 68]);
      const float4* C2 = reinterpret_cast<const float4*>(&e2L[sj * 68]);
      #pragma unroll 4
      for (int i = 0; i < 16; ++i) {
        float4 a1v = A1[i], a2v = A2[i], c1v = C1[i], c2v = C2[i];
        g11 += dot4(a1v, c1v); g12 += dot4(a1v, c2v);
        g21 += dot4(a2v, c1v); g22 += dot4(a2v, c2v);
      }
    }
    float R11=0,R12=0,R13=0,R21=0,R22=0,R23=0,R31=0,R32=0,R33=0;
    {
      const float4* X1 = reinterpret_cast<const float4*>(&r1L[si * 36]);
      const float4* X2 = reinterpret_cast<const float4*>(&r2L[si * 36]);
      const float4* X3 = reinterpret_cast<const float4*>(&r3L[si * 36]);
      const float4* Y1 = reinterpret_cast<const float4*>(&r1L[sj * 36]);
      const float4* Y2 = reinterpret_cast<const float4*>(&r2L[sj * 36]);
      const float4* Y3 = reinterpret_cast<const float4*>(&r3L[sj * 36]);
      #pragma unroll 4
      for (int i = 0; i < 8; ++i) {
        float4 x1 = X1[i], x2 = X2[i], x3 = X3[i];
        float4 y1 = Y1[i], y2 = Y2[i], y3 = Y3[i];
        R11 += dot4(x1, y1); R12 += dot4(x1, y2); R13 += dot4(x1, y3);
        R21 += dot4(x2, y1); R22 += dot4(x2, y2); R23 += dot4(x2, y3);
        R31 += dot4(x3, y1); R32 += dot4(x3, y2); R33 += dot4(x3, y3);
      }
    }
    float4* MPv = reinterpret_cast<float4*>(MPL);
    float4 p1; p1.x = g11 * R11; p1.y = g11 * R21; p1.z = g21 * R31; p1.w = 0.f;
    float4 p2; p2.x = g11 * R12; p2.y = g11 * R22; p2.z = g21 * R32; p2.w = 0.f;
    float4 p3; p3.x = g12 * R13; p3.y = g12 * R23; p3.z = g22 * R33; p3.w = 0.f;
    MPv[tid] = p1;
    MPv[900 + tid] = p2;
    MPv[1800 + tid] = p3;
  }
  __syncthreads();

  float n2 = 0.f;
  #pragma unroll
  for (int i = 0; i < 8; ++i) n2 += fn2p[i];
  float c0v = 1.f;

  // propagation phase: H{1,2,3} += MP[.]{x,y,z} * v, sp-split over g + shfl combine
  auto prop = [&](const float* vsrc, int mbase) {
    float d1[4] = {0,0,0,0}, d2[4] = {0,0,0,0}, d3[4] = {0,0,0,0};
    if (act) {
      const float4* mrow = reinterpret_cast<const float4*>(MPL) + mbase + s * 30 + g * 15;
      const float* vb = vsrc + g * 15 * 68 + fq;
      #pragma unroll 5
      for (int i = 0; i < 15; ++i) {
        float4 m = mrow[i];
        float4 vv = *reinterpret_cast<const float4*>(vb + i * 68);
        d1[0]+=m.x*vv.x; d1[1]+=m.x*vv.y; d1[2]+=m.x*vv.z; d1[3]+=m.x*vv.w;
        d2[0]+=m.y*vv.x; d2[1]+=m.y*vv.y; d2[2]+=m.y*vv.z; d2[3]+=m.y*vv.w;
        d3[0]+=m.z*vv.x; d3[1]+=m.z*vv.y; d3[2]+=m.z*vv.z; d3[3]+=m.z*vv.w;
      }
    }
    #pragma unroll
    for (int j = 0; j < 4; ++j) {
      H1[j] += d1[j] + __shfl_xor(d1[j], 16);
      H2[j] += d2[j] + __shfl_xor(d2[j], 16);
      H3[j] += d3[j] + __shfl_xor(d3[j], 16);
    }
  };

  for (int layer = 0; layer < 3; ++layer) {
    float w[4], H2s[4], H3s[4], v1r[4], v2r[4], v3r[4];
    if (act) {
      float4 e2v = *reinterpret_cast<const float4*>(&e2L[s * 68 + fq]);
      w[0]=H1[0]; w[1]=H1[1]; w[2]=H1[2]; w[3]=H1[3];
      #pragma unroll
      for (int j = 0; j < 4; ++j) { H2s[j] = H2[j]; H3s[j] = H3[j]; }
      v1r[0] = e2v.x - H1[0]; v1r[1] = e2v.y - H1[1]; v1r[2] = e2v.z - H1[2]; v1r[3] = e2v.w - H1[3];
      if (g == 0) {
        float4 t; t.x=v1r[0]; t.y=v1r[1]; t.z=v1r[2]; t.w=v1r[3];
        *reinterpret_cast<float4*>(&v1L[s * 68 + fq]) = t;
      }
    }
    __syncthreads();
    prop(v1L, 0);
    if (act) {
      #pragma unroll
      for (int j = 0; j < 4; ++j) v2r[j] = w[j] - H2[j];
      if (g == 0) {
        float4 t; t.x=v2r[0]; t.y=v2r[1]; t.z=v2r[2]; t.w=v2r[3];
        *reinterpret_cast<float4*>(&v2L[s * 68 + fq]) = t;
      }
    }
    __syncthreads();
    prop(v2L, 900);
    if (act) {
      float4 e1v = *reinterpret_cast<const float4*>(&e1L[s * 68 + fq]);
      v3r[0] = e1v.x - H3[0]; v3r[1] = e1v.y - H3[1]; v3r[2] = e1v.z - H3[2]; v3r[3] = e1v.w - H3[3];
      if (g == 0) {
        float4 t; t.x=v3r[0]; t.y=v3r[1]; t.z=v3r[2]; t.w=v3r[3];
        *reinterpret_cast<float4*>(&v3L[s * 68 + fq]) = t;
      }
    }
    __syncthreads();
    prop(v3L, 1800);
    float local = 0.f;
    if (act) {
      #pragma unroll
      for (int j = 0; j < 4; ++j) { a1[j] += v1r[j]; a2[j] += v2r[j]; a3[j] += v3r[j]; }
      if (g == 0) {
        #pragma unroll
        for (int j = 0; j < 4; ++j)
          local += v1r[j] * (w[j] + H1[j]) + v2r[j] * (H2s[j] + H2[j]) + v3r[j] * (H3s[j] + H3[j]);
      }
    }
    local = wreduce64(local);
    if ((tid & 63) == 0) redL[tid >> 6] = local;
    __syncthreads();
    if (tid == 0) {
      float tot = n2;
      #pragma unroll
      for (int i = 0; i < 16; ++i) tot += redL[i];
      float fn = fmaxf(sqrtf(tot), 1.f);
      scal[0] = 1.f / fn; scal[1] = tot;
    }
    __syncthreads();
    float inv = scal[0]; n2 = scal[1] * inv * inv; c0v *= inv;
    if (act) {
      #pragma unroll
      for (int j = 0; j < 4; ++j) { H1[j]*=inv; H2[j]*=inv; H3[j]*=inv; a1[j]*=inv; a2[j]*=inv; a3[j]*=inv; }
    }
    __syncthreads();
  }

  // ---- inference ----
  if (act && g == 0) {
    float4 t1; t1.x=a1[0]; t1.y=a1[1]; t1.z=a1[2]; t1.w=a1[3];
    float4 t2; t2.x=a2[0]; t2.y=a2[1]; t2.z=a2[2]; t2.w=a2[3];
    float4 t3; t3.x=a3[0]; t3.y=a3[1]; t3.z=a3[2]; t3.w=a3[3];
    *reinterpret_cast<float4*>(&v1L[s * 68 + fq]) = t1;
    *reinterpret_cast<float4*>(&v2L[s * 68 + fq]) = t2;
    *reinterpret_cast<float4*>(&v3L[s * 68 + fq]) = t3;
  }
  if (tid < 64) { uv[tid] = qe1g[(size_t)b * 64 + tid]; siL[tid] = 0.f; }
  __syncthreads();
  float* zL = MPL;   // overlay (MP no longer needed)
  int k32 = tid & 31;
  for (int st = 0; st < 3; ++st) {
    const float* qrg = (st == 0) ? qr1g : ((st == 1) ? qr2g : qr3g);
    if (tid < 32) qv[tid] = qrg[(size_t)b * 32 + tid];
    __syncthreads();
    if (act) {
      float u0 = uv[k32], u1 = uv[k32 + 32];
      float eu1 = e1L[s * 68 + k32] * u0 + e1L[s * 68 + k32 + 32] * u1;
      float eu2 = e2L[s * 68 + k32] * u0 + e2L[s * 68 + k32 + 32] * u1;
      float rq1 = r1L[s * 36 + k32] * qv[k32];
      float rq2 = r2L[s * 36 + k32] * qv[k32];
      float rq3 = r3L[s * 36 + k32] * qv[k32];
      #pragma unroll
      for (int d = 16; d > 0; d >>= 1) {
        eu1 += __shfl_down(eu1, d, 32); eu2 += __shfl_down(eu2, d, 32);
        rq1 += __shfl_down(rq1, d, 32); rq2 += __shfl_down(rq2, d, 32); rq3 += __shfl_down(rq3, d, 32);
      }
      if (k32 == 0) { alf[s] = eu1 * rq1; alf[32 + s] = eu1 * rq2; alf[64 + s] = eu2 * rq3; }
    }
    float z0 = 0.f, z1 = 0.f;
    {
      const float* fb = fwm + s * 64 + k32 * 2;
      for (int e = 0; e < 64; ++e) {
        float u = uv[e];
        z0 += u * fb[(size_t)e * 2048];
        z1 += u * fb[(size_t)e * 2048 + 1];
      }
    }
    {
      float q = qv[s];
      zL[s * 68 + k32 * 2]     = q * z0;
      zL[s * 68 + k32 * 2 + 1] = q * z1;
    }
    __syncthreads();
    if (tid < 64) {
      float F = 0.f;
      for (int rr = 0; rr < 32; ++rr) F += zL[rr * 68 + tid];
      float raw = c0v * F;
      for (int sp = 0; sp < 30; ++sp)
        raw += alf[sp] * v1L[sp * 68 + tid] + alf[32 + sp] * v2L[sp * 68 + tid] + alf[64 + sp] * v3L[sp * 68 + tid];
      float mean = wreduce64(raw) * (1.f / 64.f);
      float d = raw - mean;
      float var = wreduce64(d * d) * (1.f / 63.f);
      float y = lng[st * 64 + tid] * d / (sqrtf(var) + 1e-6f) + lnb[st * 64 + tid];
      siL[tid] += y;
      uv[tid] = y;
    }
    __syncthreads();
  }
  if (tid < 9) {
    float o = 0.f;
    for (int ff = 0; ff < 64; ++ff) o += siL[ff] * Zg[ff * 9 + tid];
    out[(size_t)b * 9 + tid] = o;
  }
}

extern "C" void kernel_launch(void* const* d_in, const int* in_sizes, int n_in,
                              void* d_out, int out_size, void* d_ws, size_t ws_size,
                              hipStream_t stream) {
  const int*   story = (const int*)d_in[0];
  const int*   query = (const int*)d_in[1];
  const float* WE    = (const float*)d_in[2];
  const float* PE    = (const float*)d_in[3];
  const float* ueW1  = (const float*)d_in[4];
  const float* ueb1  = (const float*)d_in[5];
  const float* ueW2  = (const float*)d_in[6];
  const float* ueb2  = (const float*)d_in[7];
  const float* urW1  = (const float*)d_in[8];
  const float* urb1  = (const float*)d_in[9];
  const float* urW2  = (const float*)d_in[10];
  const float* urb2  = (const float*)d_in[11];
  const float* fwm   = (const float*)d_in[12];
  const float* ieW1  = (const float*)d_in[13];
  const float* ieb1  = (const float*)d_in[14];
  const float* ieW2  = (const float*)d_in[15];
  const float* ieb2  = (const float*)d_in[16];
  const float* irW1  = (const float*)d_in[17];
  const float* irb1  = (const float*)d_in[18];
  const float* irW2  = (const float*)d_in[19];
  const float* irb2  = (const float*)d_in[20];
  const float* lng   = (const float*)d_in[21];
  const float* lnb   = (const float*)d_in[22];
  const float* Z     = (const float*)d_in[23];
  float* W = (float*)d_ws;
  float* out = (float*)d_out;

  ushortT* sentB = (ushortT*)(W + OF_SENTB);
  ushortT* qembB = (ushortT*)(W + OF_QEMBB);
  ushortT* W1A   = (ushortT*)(W + OF_W1A);
  ushortT* W2TE  = (ushortT*)(W + OF_W2TE);
  ushortT* W2TR  = (ushortT*)(W + OF_W2TR);

  embed_k<<<7936, 128, 0, stream>>>(story, query, WE, PE, sentB, qembB);

  tcvt1_k<<<dim3(32, 9), 256, 0, stream>>>(ueW1, urW1, ieW1, irW1, W1A);
  tcvt2_k<<<dim3(16, 9), 256, 0, stream>>>(ueW2, urW2, ieW2, irW2, W2TE, W2TR);

  // story heads 0..4 (ue0,ue1,ur0,ur1,ur2); query heads 5..8 (ie0,ir0,ir1,ir2)
  mlpm_k<<<dim3(240, 5), 256, 0, stream>>>(sentB, W1A, ueb1, urb1, W2TE, W2TR, ueb2, urb2,
      W + OF_E1, 491520, W + OF_R1, 245760, 2);
  mlpm_k<<<dim3(8, 4), 256, 0, stream>>>(qembB, W1A + (size_t)5 * 65536, ieb1, irb1,
      W2TE + (size_t)2 * 32768, W2TR + (size_t)3 * 16384, ieb2, irb2,
      W + OF_QE1, 16384, W + OF_QR1, 8192, 1);

  fnorm_k<<<8, 256, 0, stream>>>(fwm, W + OF_FN2);
  pstage_k<<<480, 256, 0, stream>>>(fwm, W + OF_E1, W + OF_E1 + 491520,
      W + OF_R1, W + OF_R1 + 245760, W + OF_R1 + 2 * 245760, W + OF_PP);
  scan_k<<<NB, 1024, 0, stream>>>(W + OF_PP, W + OF_E1, W + OF_E1 + 491520,
      W + OF_R1, W + OF_R1 + 245760, W + OF_R1 + 2 * 245760,
      W + OF_QE1, W + OF_QR1, W + OF_QR1 + 8192, W + OF_QR1 + 16384, W + OF_FN2, fwm, lng, lnb, Z, out);
}

// Round 8
// 236.177 us; speedup vs baseline: 3.1552x; 1.1584x over previous
//
#include <hip/hip_runtime.h>
#include <hip/hip_bf16.h>

// Sizes
#define NB 256
#define NS 30
#define NW 10
#define SYM 128
#define HID 512
#define ENT 64
#define ROLE 32

typedef unsigned short ushortT;
typedef __attribute__((ext_vector_type(8))) short short8v;   // 8 bf16
typedef __attribute__((ext_vector_type(4))) float f32x4;

// Workspace offsets (floats; bf16 arrays use 2 elems per float slot)
static const size_t OF_SENTB = 0;         // 7680*128 bf16 -> 491520 fl
static const size_t OF_QEMBB = 491520;    // 256*128 bf16 -> 16384 fl
static const size_t OF_W1A   = 507904;    // 9*512*128 bf16 -> 294912 fl
static const size_t OF_W2TE  = 802816;    // 3*64*512 bf16 -> 49152 fl
static const size_t OF_W2TR  = 851968;    // 6*32*512 bf16 -> 49152 fl
static const size_t OF_FWMB  = 901120;    // 64*2048 bf16 -> 65536 fl  (fwm^T [f][e*32+r])
static const size_t OF_E1    = 966656;    // 7680*64 x2 (stride 491520)
static const size_t OF_R1    = 1949696;   // 7680*32 x3 (stride 245760)
static const size_t OF_QE1   = 2686976;   // 256*64
static const size_t OF_QR1   = 2703360;   // 256*32 x3 (stride 8192)
static const size_t OF_FN2   = 2727936;   // 8 partials

__device__ __forceinline__ ushortT f2bf(float x) {
  unsigned u = __float_as_uint(x);
  unsigned r = (u + 0x7fffu + ((u >> 16) & 1u)) >> 16;
  return (ushortT)r;
}
__device__ __forceinline__ float dot4(const float4& a, const float4& b) {
  return a.x * b.x + a.y * b.y + a.z * b.z + a.w * b.w;
}
__device__ __forceinline__ float wreduce64(float v) {
  #pragma unroll
  for (int o = 32; o > 0; o >>= 1) v += __shfl_xor(v, o);
  return v;
}

// ---------------- embedding (bf16 out) ----------------
__global__ __launch_bounds__(128) void embed_k(const int* __restrict__ story, const int* __restrict__ query,
    const float* __restrict__ WE, const float* __restrict__ PE,
    ushortT* __restrict__ sentb, ushortT* __restrict__ qembb) {
  int bs = blockIdx.x; int e = threadIdx.x;
  const int* idx; ushortT* dst;
  if (bs < 7680) { idx = story + (size_t)bs * NW; dst = sentb + (size_t)bs * SYM; }
  else           { idx = query + (size_t)(bs - 7680) * NW; dst = qembb + (size_t)(bs - 7680) * SYM; }
  float acc = 0.f;
  #pragma unroll
  for (int w = 0; w < NW; ++w) {
    int t = idx[w];
    acc += WE[t * SYM + e] * PE[w * SYM + e];
  }
  dst[e] = f2bf(acc);
}

// ---------------- W1 transpose+convert ----------------
__global__ __launch_bounds__(256) void tcvt1_k(const float* __restrict__ ueW1, const float* __restrict__ urW1,
    const float* __restrict__ ieW1, const float* __restrict__ irW1, ushortT* __restrict__ dst) {
  int y = blockIdx.y;
  const float* src = (y < 2) ? ueW1 + (size_t)y * 65536
                   : (y < 5) ? urW1 + (size_t)(y - 2) * 65536
                   : (y == 5) ? ieW1
                   : irW1 + (size_t)(y - 6) * 65536;
  ushortT* d = dst + (size_t)y * 65536;
  for (int i = blockIdx.x * 256 + threadIdx.x; i < 65536; i += gridDim.x * 256) {
    int r = i >> 9, c = i & 511;
    d[c * 128 + r] = f2bf(src[i]);
  }
}

// ---------------- W2 transpose+convert ----------------
__global__ __launch_bounds__(256) void tcvt2_k(const float* __restrict__ ueW2, const float* __restrict__ urW2,
    const float* __restrict__ ieW2, const float* __restrict__ irW2,
    ushortT* __restrict__ dstE, ushortT* __restrict__ dstR) {
  int y = blockIdx.y;
  if (y < 3) {
    const float* src = (y < 2) ? ueW2 + (size_t)y * 32768 : ieW2;
    ushortT* d = dstE + (size_t)y * 32768;
    for (int i = blockIdx.x * 256 + threadIdx.x; i < 32768; i += gridDim.x * 256) {
      int r = i >> 6, c = i & 63;
      d[c * 512 + r] = f2bf(src[i]);
    }
  } else {
    int yy = y - 3;
    const float* src = (yy < 3) ? urW2 + (size_t)yy * 16384 : irW2 + (size_t)(yy - 3) * 16384;
    ushortT* d = dstR + (size_t)yy * 16384;
    for (int i = blockIdx.x * 256 + threadIdx.x; i < 16384; i += gridDim.x * 256) {
      int r = i >> 5, c = i & 31;
      d[c * 512 + r] = f2bf(src[i]);
    }
  }
}

// ---------------- fwm -> bf16 transposed [f][e*32+r] ----------------
__global__ __launch_bounds__(256) void fwmcvt_k(const float* __restrict__ fwm, ushortT* __restrict__ dst) {
  int f = blockIdx.x;  // 64
  for (int kk = threadIdx.x; kk < 2048; kk += 256)
    dst[(size_t)f * 2048 + kk] = f2bf(fwm[(size_t)kk * 64 + f]);
}

// ---------------- MFMA fused 2-layer MLP ----------------
__global__ __launch_bounds__(256) void mlpm_k(
    const ushortT* __restrict__ Xb,
    const ushortT* __restrict__ W1T,
    const float* __restrict__ eb1, const float* __restrict__ rb1,
    const ushortT* __restrict__ W2Te,
    const ushortT* __restrict__ W2Tr,
    const float* __restrict__ eb2, const float* __restrict__ rb2,
    float* __restrict__ Eout, size_t eostride,
    float* __restrict__ Rout, size_t rostride, int eHeads) {
  __shared__ __align__(16) ushortT Hl[32 * 520];
  int r0 = blockIdx.x * 32, h = blockIdx.y, tid = threadIdx.x;
  int wave = tid >> 6, lane = tid & 63;
  int lrow = lane & 15;
  int kgrp = lane >> 4;
  bool isE = h < eHeads;
  int hh = isE ? h : h - eHeads;
  const ushortT* W1h = W1T + (size_t)h * 512 * 128;
  const float* b1 = (isE ? eb1 : rb1) + (size_t)hh * 512;

  int lrw = (wave & 1) * 16;
  int cw  = (wave >> 1) * 256;

  short8v afr[4];
  const ushortT* arow = Xb + (size_t)(r0 + lrw + lrow) * 128 + kgrp * 8;
  #pragma unroll
  for (int kt = 0; kt < 4; ++kt)
    afr[kt] = *reinterpret_cast<const short8v*>(arow + kt * 32);

  for (int ct = 0; ct < 16; ++ct) {
    int c0 = cw + ct * 16;
    f32x4 acc = {0.f, 0.f, 0.f, 0.f};
    const ushortT* bcol = W1h + (size_t)(c0 + lrow) * 128 + kgrp * 8;
    #pragma unroll
    for (int kt = 0; kt < 4; ++kt) {
      short8v bfr = *reinterpret_cast<const short8v*>(bcol + kt * 32);
      acc = __builtin_amdgcn_mfma_f32_16x16x32_bf16(afr[kt], bfr, acc, 0, 0, 0);
    }
    int lcol = c0 + lrow;
    float bb = b1[lcol];
    #pragma unroll
    for (int i = 0; i < 4; ++i) {
      float hv = tanhf(acc[i] + bb);
      Hl[(lrw + kgrp * 4 + i) * 520 + lcol] = f2bf(hv);
    }
  }
  __syncthreads();

  if (isE) {
    const ushortT* W2h = W2Te + (size_t)hh * 64 * 512;
    const float* b2 = eb2 + (size_t)hh * 64;
    int c0w = (wave >> 1) * 32;
    f32x4 acc[2] = {{0.f,0.f,0.f,0.f},{0.f,0.f,0.f,0.f}};
    for (int kt = 0; kt < 16; ++kt) {
      int kb = kt * 32 + kgrp * 8;
      short8v afr2 = *reinterpret_cast<const short8v*>(&Hl[(lrw + lrow) * 520 + kb]);
      #pragma unroll
      for (int t = 0; t < 2; ++t) {
        short8v bfr = *reinterpret_cast<const short8v*>(W2h + (size_t)(c0w + t * 16 + lrow) * 512 + kb);
        acc[t] = __builtin_amdgcn_mfma_f32_16x16x32_bf16(afr2, bfr, acc[t], 0, 0, 0);
      }
    }
    #pragma unroll
    for (int t = 0; t < 2; ++t) {
      int col = c0w + t * 16 + lrow;
      float bb = b2[col];
      #pragma unroll
      for (int i = 0; i < 4; ++i) {
        int grow = r0 + lrw + kgrp * 4 + i;
        Eout[(size_t)hh * eostride + (size_t)grow * 64 + col] = tanhf(acc[t][i] + bb);
      }
    }
  } else {
    const ushortT* W2h = W2Tr + (size_t)hh * 32 * 512;
    const float* b2 = rb2 + (size_t)hh * 32;
    int c0w = (wave >> 1) * 16;
    f32x4 acc = {0.f, 0.f, 0.f, 0.f};
    for (int kt = 0; kt < 16; ++kt) {
      int kb = kt * 32 + kgrp * 8;
      short8v afr2 = *reinterpret_cast<const short8v*>(&Hl[(lrw + lrow) * 520 + kb]);
      short8v bfr = *reinterpret_cast<const short8v*>(W2h + (size_t)(c0w + lrow) * 512 + kb);
      acc = __builtin_amdgcn_mfma_f32_16x16x32_bf16(afr2, bfr, acc, 0, 0, 0);
    }
    int col = c0w + lrow;
    float bb = b2[col];
    #pragma unroll
    for (int i = 0; i < 4; ++i) {
      int grow = r0 + lrw + kgrp * 4 + i;
      Rout[(size_t)hh * rostride + (size_t)grow * 32 + col] = tanhf(acc[i] + bb);
    }
  }
}

// ---------------- ||fwm||^2 partials (8 blocks) ----------------
__global__ __launch_bounds__(256) void fnorm_k(const float* __restrict__ fwm, float* __restrict__ o) {
  __shared__ float red[4];
  int tid = threadIdx.x;
  const float4* f4 = reinterpret_cast<const float4*>(fwm) + blockIdx.x * 4096;
  float a = 0.f;
  for (int i = tid; i < 4096; i += 256) {
    float4 v = f4[i];
    a += v.x*v.x + v.y*v.y + v.z*v.z + v.w*v.w;
  }
  #pragma unroll
  for (int off = 32; off > 0; off >>= 1) a += __shfl_down(a, off);
  if ((tid & 63) == 0) red[tid >> 6] = a;
  __syncthreads();
  if (tid == 0) o[blockIdx.x] = red[0] + red[1] + red[2] + red[3];
}

// ---------------- scan: in-kernel MFMA P + gram + layers + inference ----------------
__global__ __launch_bounds__(1024) void scan_k(
    const ushortT* __restrict__ fwmBT,
    const float* __restrict__ e1g, const float* __restrict__ e2g,
    const float* __restrict__ r1g, const float* __restrict__ r2g, const float* __restrict__ r3g,
    const float* __restrict__ qe1g, const float* __restrict__ qr1g, const float* __restrict__ qr2g,
    const float* __restrict__ qr3g, const float* __restrict__ fn2p, const float* __restrict__ fwm,
    const float* __restrict__ lng, const float* __restrict__ lnb, const float* __restrict__ Zg,
    float* __restrict__ out) {
  __shared__ __align__(16) float MPL[10800];            // gram M; reused as zL + partials in inference
  __shared__ __align__(16) float e1L[2040], e2L[2040];  // [30][68]
  __shared__ __align__(16) float v1L[2040], v2L[2040], v3L[2040];
  __shared__ __align__(16) float r1L[1080], r2L[1080], r3L[1080];  // [30][36]
  __shared__ float uv[64], qv[32], alf[96], siL[64];
  __shared__ float redL[16], scal[2];
  int b = blockIdx.x, tid = threadIdx.x;
  int s = tid >> 5, g = (tid >> 4) & 1, fo = tid & 15;
  int fq = fo * 4;
  bool act = s < 30;

  for (int i = tid; i < 1920; i += 1024) {
    int ss = i >> 6, e = i & 63;
    e1L[ss * 68 + e] = e1g[(size_t)b * 1920 + i];
    e2L[ss * 68 + e] = e2g[(size_t)b * 1920 + i];
  }
  for (int i = tid; i < 960; i += 1024) {
    int ss = i >> 5, rr = i & 31;
    r1L[ss * 36 + rr] = r1g[(size_t)b * 960 + i];
    r2L[ss * 36 + rr] = r2g[(size_t)b * 960 + i];
    r3L[ss * 36 + rr] = r3g[(size_t)b * 960 + i];
  }
  __syncthreads();

  // ---- P via MFMA: P_c[s,f] = sum_e e_c[s,e] * (sum_r r_c[s,r] * fwm[e,r,f]) ----
  // 12 active waves: combo(3) x mtile(2) x nhalf(2). A = bf16(r-row), one K=32 step per e.
  {
    int wv = tid >> 6, lane = tid & 63;
    if (wv < 12) {
      int combo = wv >> 2;
      int mt = (wv >> 1) & 1;
      int nh = wv & 1;
      int kg = lane >> 4;
      int arow = mt * 16 + (lane & 15);
      const float* eArr = (combo == 2) ? e2L : e1L;
      const float* rArr = (combo == 0) ? r1L : (combo == 1) ? r2L : r3L;
      short8v rfr = {0, 0, 0, 0, 0, 0, 0, 0};
      if (arow < 30) {
        #pragma unroll
        for (int j = 0; j < 8; ++j)
          ((ushortT*)&rfr)[j] = f2bf(rArr[arow * 36 + kg * 8 + j]);
      }
      int rb0 = mt * 16 + kg * 4;
      const float* eb0 = eArr + min(rb0 + 0, 29) * 68;
      const float* eb1 = eArr + min(rb0 + 1, 29) * 68;
      const float* eb2 = eArr + min(rb0 + 2, 29) * 68;
      const float* eb3 = eArr + min(rb0 + 3, 29) * 68;
      const ushortT* bbase = fwmBT + (size_t)(nh * 32 + (lane & 15)) * 2048 + kg * 8;
      f32x4 P0 = {0, 0, 0, 0}, P1v = {0, 0, 0, 0};
      const f32x4 zero = {0, 0, 0, 0};
      for (int e = 0; e < 64; ++e) {
        short8v b0 = *reinterpret_cast<const short8v*>(bbase + e * 32);
        short8v b1 = *reinterpret_cast<const short8v*>(bbase + 16 * 2048 + e * 32);
        f32x4 t0 = __builtin_amdgcn_mfma_f32_16x16x32_bf16(rfr, b0, zero, 0, 0, 0);
        f32x4 t1 = __builtin_amdgcn_mfma_f32_16x16x32_bf16(rfr, b1, zero, 0, 0, 0);
        float e0 = eb0[e], e1v = eb1[e], e2v = eb2[e], e3v = eb3[e];
        P0[0] += e0 * t0[0]; P0[1] += e1v * t0[1]; P0[2] += e2v * t0[2]; P0[3] += e3v * t0[3];
        P1v[0] += e0 * t1[0]; P1v[1] += e1v * t1[1]; P1v[2] += e2v * t1[2]; P1v[3] += e3v * t1[3];
      }
      float* dst = (combo == 0) ? v1L : (combo == 1) ? v2L : v3L;
      int fb = nh * 32 + (lane & 15);
      #pragma unroll
      for (int i = 0; i < 4; ++i) {
        int row = rb0 + i;
        if (row < 30) {
          dst[row * 68 + fb] = P0[i];
          dst[row * 68 + 16 + fb] = P1v[i];
        }
      }
    }
  }
  __syncthreads();

  // ---- extract H from P (in v-arrays) ----
  float H1[4], H2[4], H3[4], a1[4], a2[4], a3[4];
  #pragma unroll
  for (int j = 0; j < 4; ++j) { a1[j] = 0; a2[j] = 0; a3[j] = 0; }
  if (act) {
    float4 h1 = *reinterpret_cast<const float4*>(&v1L[s * 68 + fq]);
    float4 h2 = *reinterpret_cast<const float4*>(&v2L[s * 68 + fq]);
    float4 h3 = *reinterpret_cast<const float4*>(&v3L[s * 68 + fq]);
    H1[0]=h1.x; H1[1]=h1.y; H1[2]=h1.z; H1[3]=h1.w;
    H2[0]=h2.x; H2[1]=h2.y; H2[2]=h2.z; H2[3]=h2.w;
    H3[0]=h3.x; H3[1]=h3.y; H3[2]=h3.z; H3[3]=h3.w;
  } else {
    #pragma unroll
    for (int j = 0; j < 4; ++j) { H1[j]=0; H2[j]=0; H3[j]=0; }
  }

  // ---- fused gram -> packed MP ----
  if (tid < 900) {
    int si = tid / 30, sj = tid - si * 30;
    float g11 = 0, g12 = 0, g21 = 0, g22 = 0;
    {
      const float4* A1 = reinterpret_cast<const float4*>(&e1L[si * 68]);
      const float4* A2 = reinterpret_cast<const float4*>(&e2L[si * 68]);
      const float4* C1 = reinterpret_cast<const float4*>(&e1L[sj * 68]);
      const float4* C2 = reinterpret_cast<const float4*>(&e2L[sj * 68]);
      #pragma unroll 4
      for (int i = 0; i < 16; ++i) {
        float4 a1v = A1[i], a2v = A2[i], c1v = C1[i], c2v = C2[i];
        g11 += dot4(a1v, c1v); g12 += dot4(a1v, c2v);
        g21 += dot4(a2v, c1v); g22 += dot4(a2v, c2v);
      }
    }
    float R11=0,R12=0,R13=0,R21=0,R22=0,R23=0,R31=0,R32=0,R33=0;
    {
      const float4* X1 = reinterpret_cast<const float4*>(&r1L[si * 36]);
      const float4* X2 = reinterpret_cast<const float4*>(&r2L[si * 36]);
      const float4* X3 = reinterpret_cast<const float4*>(&r3L[si * 36]);
      const float4* Y1 = reinterpret_cast<const float4*>(&r1L[sj * 36]);
      const float4* Y2 = reinterpret_cast<const float4*>(&r2L[sj * 36]);
      const float4* Y3 = reinterpret_cast<const float4*>(&r3L[sj * 36]);
      #pragma unroll 4
      for (int i = 0; i < 8; ++i) {
        float4 x1 = X1[i], x2 = X2[i], x3 = X3[i];
        float4 y1 = Y1[i], y2 = Y2[i], y3 = Y3[i];
        R11 += dot4(x1, y1); R12 += dot4(x1, y2); R13 += dot4(x1, y3);
        R21 += dot4(x2, y1); R22 += dot4(x2, y2); R23 += dot4(x2, y3);
        R31 += dot4(x3, y1); R32 += dot4(x3, y2); R33 += dot4(x3, y3);
      }
    }
    float4* MPv = reinterpret_cast<float4*>(MPL);
    float4 p1; p1.x = g11 * R11; p1.y = g11 * R21; p1.z = g21 * R31; p1.w = 0.f;
    float4 p2; p2.x = g11 * R12; p2.y = g11 * R22; p2.z = g21 * R32; p2.w = 0.f;
    float4 p3; p3.x = g12 * R13; p3.y = g12 * R23; p3.z = g22 * R33; p3.w = 0.f;
    MPv[tid] = p1;
    MPv[900 + tid] = p2;
    MPv[1800 + tid] = p3;
  }
  __syncthreads();

  float n2 = 0.f;
  #pragma unroll
  for (int i = 0; i < 8; ++i) n2 += fn2p[i];
  float c0v = 1.f;

  auto prop = [&](const float* vsrc, int mbase) {
    float d1[4] = {0,0,0,0}, d2[4] = {0,0,0,0}, d3[4] = {0,0,0,0};
    if (act) {
      const float4* mrow = reinterpret_cast<const float4*>(MPL) + mbase + s * 30 + g * 15;
      const float* vb = vsrc + g * 15 * 68 + fq;
      #pragma unroll 5
      for (int i = 0; i < 15; ++i) {
        float4 m = mrow[i];
        float4 vv = *reinterpret_cast<const float4*>(vb + i * 68);
        d1[0]+=m.x*vv.x; d1[1]+=m.x*vv.y; d1[2]+=m.x*vv.z; d1[3]+=m.x*vv.w;
        d2[0]+=m.y*vv.x; d2[1]+=m.y*vv.y; d2[2]+=m.y*vv.z; d2[3]+=m.y*vv.w;
        d3[0]+=m.z*vv.x; d3[1]+=m.z*vv.y; d3[2]+=m.z*vv.z; d3[3]+=m.z*vv.w;
      }
    }
    #pragma unroll
    for (int j = 0; j < 4; ++j) {
      H1[j] += d1[j] + __shfl_xor(d1[j], 16);
      H2[j] += d2[j] + __shfl_xor(d2[j], 16);
      H3[j] += d3[j] + __shfl_xor(d3[j], 16);
    }
  };

  for (int layer = 0; layer < 3; ++layer) {
    float w[4], H2s[4], H3s[4], v1r[4], v2r[4], v3r[4];
    if (act) {
      float4 e2v = *reinterpret_cast<const float4*>(&e2L[s * 68 + fq]);
      w[0]=H1[0]; w[1]=H1[1]; w[2]=H1[2]; w[3]=H1[3];
      #pragma unroll
      for (int j = 0; j < 4; ++j) { H2s[j] = H2[j]; H3s[j] = H3[j]; }
      v1r[0] = e2v.x - H1[0]; v1r[1] = e2v.y - H1[1]; v1r[2] = e2v.z - H1[2]; v1r[3] = e2v.w - H1[3];
      if (g == 0) {
        float4 t; t.x=v1r[0]; t.y=v1r[1]; t.z=v1r[2]; t.w=v1r[3];
        *reinterpret_cast<float4*>(&v1L[s * 68 + fq]) = t;
      }
    }
    __syncthreads();
    prop(v1L, 0);
    if (act) {
      #pragma unroll
      for (int j = 0; j < 4; ++j) v2r[j] = w[j] - H2[j];
      if (g == 0) {
        float4 t; t.x=v2r[0]; t.y=v2r[1]; t.z=v2r[2]; t.w=v2r[3];
        *reinterpret_cast<float4*>(&v2L[s * 68 + fq]) = t;
      }
    }
    __syncthreads();
    prop(v2L, 900);
    if (act) {
      float4 e1v = *reinterpret_cast<const float4*>(&e1L[s * 68 + fq]);
      v3r[0] = e1v.x - H3[0]; v3r[1] = e1v.y - H3[1]; v3r[2] = e1v.z - H3[2]; v3r[3] = e1v.w - H3[3];
      if (g == 0) {
        float4 t; t.x=v3r[0]; t.y=v3r[1]; t.z=v3r[2]; t.w=v3r[3];
        *reinterpret_cast<float4*>(&v3L[s * 68 + fq]) = t;
      }
    }
    __syncthreads();
    prop(v3L, 1800);
    float local = 0.f;
    if (act) {
      #pragma unroll
      for (int j = 0; j < 4; ++j) { a1[j] += v1r[j]; a2[j] += v2r[j]; a3[j] += v3r[j]; }
      if (g == 0) {
        #pragma unroll
        for (int j = 0; j < 4; ++j)
          local += v1r[j] * (w[j] + H1[j]) + v2r[j] * (H2s[j] + H2[j]) + v3r[j] * (H3s[j] + H3[j]);
      }
    }
    local = wreduce64(local);
    if ((tid & 63) == 0) redL[tid >> 6] = local;
    __syncthreads();
    if (tid == 0) {
      float tot = n2;
      #pragma unroll
      for (int i = 0; i < 16; ++i) tot += redL[i];
      float fn = fmaxf(sqrtf(tot), 1.f);
      scal[0] = 1.f / fn; scal[1] = tot;
    }
    __syncthreads();
    float inv = scal[0]; n2 = scal[1] * inv * inv; c0v *= inv;
    if (act) {
      #pragma unroll
      for (int j = 0; j < 4; ++j) { H1[j]*=inv; H2[j]*=inv; H3[j]*=inv; a1[j]*=inv; a2[j]*=inv; a3[j]*=inv; }
    }
    __syncthreads();
  }

  // ---- inference ----
  if (act && g == 0) {
    float4 t1; t1.x=a1[0]; t1.y=a1[1]; t1.z=a1[2]; t1.w=a1[3];
    float4 t2; t2.x=a2[0]; t2.y=a2[1]; t2.z=a2[2]; t2.w=a2[3];
    float4 t3; t3.x=a3[0]; t3.y=a3[1]; t3.z=a3[2]; t3.w=a3[3];
    *reinterpret_cast<float4*>(&v1L[s * 68 + fq]) = t1;
    *reinterpret_cast<float4*>(&v2L[s * 68 + fq]) = t2;
    *reinterpret_cast<float4*>(&v3L[s * 68 + fq]) = t3;
  }
  if (tid < 64) { uv[tid] = qe1g[(size_t)b * 64 + tid]; siL[tid] = 0.f; }
  __syncthreads();
  float* zL = MPL;               // rows [0..32)*68
  float* partL = MPL + 4096;     // [16][64]
  int k32 = tid & 31;
  for (int st = 0; st < 3; ++st) {
    const float* qrg = (st == 0) ? qr1g : ((st == 1) ? qr2g : qr3g);
    if (tid < 32) qv[tid] = qrg[(size_t)b * 32 + tid];
    __syncthreads();
    if (act) {
      float u0 = uv[k32], u1 = uv[k32 + 32];
      float eu1 = e1L[s * 68 + k32] * u0 + e1L[s * 68 + k32 + 32] * u1;
      float eu2 = e2L[s * 68 + k32] * u0 + e2L[s * 68 + k32 + 32] * u1;
      float rq1 = r1L[s * 36 + k32] * qv[k32];
      float rq2 = r2L[s * 36 + k32] * qv[k32];
      float rq3 = r3L[s * 36 + k32] * qv[k32];
      #pragma unroll
      for (int d = 16; d > 0; d >>= 1) {
        eu1 += __shfl_down(eu1, d, 32); eu2 += __shfl_down(eu2, d, 32);
        rq1 += __shfl_down(rq1, d, 32); rq2 += __shfl_down(rq2, d, 32); rq3 += __shfl_down(rq3, d, 32);
      }
      if (k32 == 0) { alf[s] = eu1 * rq1; alf[32 + s] = eu1 * rq2; alf[64 + s] = eu2 * rq3; }
    }
    float z0 = 0.f, z1 = 0.f;
    {
      const float* fb = fwm + s * 64 + k32 * 2;
      for (int e = 0; e < 64; ++e) {
        float u = uv[e];
        z0 += u * fb[(size_t)e * 2048];
        z1 += u * fb[(size_t)e * 2048 + 1];
      }
    }
    {
      float q = qv[s];
      zL[s * 68 + k32 * 2]     = q * z0;
      zL[s * 68 + k32 * 2 + 1] = q * z1;
    }
    __syncthreads();
    // parallel raw partials: parts 0..14 -> 2 sp each; part 15 -> c0v * F
    {
      int p = tid >> 6, f = tid & 63;
      float part;
      if (p < 15) {
        int sp = p * 2;
        part = alf[sp] * v1L[sp * 68 + f] + alf[32 + sp] * v2L[sp * 68 + f] + alf[64 + sp] * v3L[sp * 68 + f]
             + alf[sp + 1] * v1L[(sp + 1) * 68 + f] + alf[33 + sp] * v2L[(sp + 1) * 68 + f]
             + alf[65 + sp] * v3L[(sp + 1) * 68 + f];
      } else {
        float F = 0.f;
        #pragma unroll 8
        for (int rr = 0; rr < 32; ++rr) F += zL[rr * 68 + f];
        part = c0v * F;
      }
      partL[p * 64 + f] = part;
    }
    __syncthreads();
    if (tid < 64) {
      float raw = 0.f;
      #pragma unroll
      for (int p = 0; p < 16; ++p) raw += partL[p * 64 + tid];
      float mean = wreduce64(raw) * (1.f / 64.f);
      float d = raw - mean;
      float var = wreduce64(d * d) * (1.f / 63.f);
      float y = lng[st * 64 + tid] * d / (sqrtf(var) + 1e-6f) + lnb[st * 64 + tid];
      siL[tid] += y;
      uv[tid] = y;
    }
    __syncthreads();
  }
  if (tid < 9) {
    float o = 0.f;
    for (int ff = 0; ff < 64; ++ff) o += siL[ff] * Zg[ff * 9 + tid];
    out[(size_t)b * 9 + tid] = o;
  }
}

extern "C" void kernel_launch(void* const* d_in, const int* in_sizes, int n_in,
                              void* d_out, int out_size, void* d_ws, size_t ws_size,
                              hipStream_t stream) {
  const int*   story = (const int*)d_in[0];
  const int*   query = (const int*)d_in[1];
  const float* WE    = (const float*)d_in[2];
  const float* PE    = (const float*)d_in[3];
  const float* ueW1  = (const float*)d_in[4];
  const float* ueb1  = (const float*)d_in[5];
  const float* ueW2  = (const float*)d_in[6];
  const float* ueb2  = (const float*)d_in[7];
  const float* urW1  = (const float*)d_in[8];
  const float* urb1  = (const float*)d_in[9];
  const float* urW2  = (const float*)d_in[10];
  const float* urb2  = (const float*)d_in[11];
  const float* fwm   = (const float*)d_in[12];
  const float* ieW1  = (const float*)d_in[13];
  const float* ieb1  = (const float*)d_in[14];
  const float* ieW2  = (const float*)d_in[15];
  const float* ieb2  = (const float*)d_in[16];
  const float* irW1  = (const float*)d_in[17];
  const float* irb1  = (const float*)d_in[18];
  const float* irW2  = (const float*)d_in[19];
  const float* irb2  = (const float*)d_in[20];
  const float* lng   = (const float*)d_in[21];
  const float* lnb   = (const float*)d_in[22];
  const float* Z     = (const float*)d_in[23];
  float* W = (float*)d_ws;
  float* out = (float*)d_out;

  ushortT* sentB = (ushortT*)(W + OF_SENTB);
  ushortT* qembB = (ushortT*)(W + OF_QEMBB);
  ushortT* W1A   = (ushortT*)(W + OF_W1A);
  ushortT* W2TE  = (ushortT*)(W + OF_W2TE);
  ushortT* W2TR  = (ushortT*)(W + OF_W2TR);
  ushortT* fwmBT = (ushortT*)(W + OF_FWMB);

  embed_k<<<7936, 128, 0, stream>>>(story, query, WE, PE, sentB, qembB);

  tcvt1_k<<<dim3(32, 9), 256, 0, stream>>>(ueW1, urW1, ieW1, irW1, W1A);
  tcvt2_k<<<dim3(16, 9), 256, 0, stream>>>(ueW2, urW2, ieW2, irW2, W2TE, W2TR);
  fwmcvt_k<<<64, 256, 0, stream>>>(fwm, fwmBT);

  // story heads 0..4 (ue0,ue1,ur0,ur1,ur2); query heads 5..8 (ie0,ir0,ir1,ir2)
  mlpm_k<<<dim3(240, 5), 256, 0, stream>>>(sentB, W1A, ueb1, urb1, W2TE, W2TR, ueb2, urb2,
      W + OF_E1, 491520, W + OF_R1, 245760, 2);
  mlpm_k<<<dim3(8, 4), 256, 0, stream>>>(qembB, W1A + (size_t)5 * 65536, ieb1, irb1,
      W2TE + (size_t)2 * 32768, W2TR + (size_t)3 * 16384, ieb2, irb2,
      W + OF_QE1, 16384, W + OF_QR1, 8192, 1);

  fnorm_k<<<8, 256, 0, stream>>>(fwm, W + OF_FN2);
  scan_k<<<NB, 1024, 0, stream>>>(fwmBT, W + OF_E1, W + OF_E1 + 491520,
      W + OF_R1, W + OF_R1 + 245760, W + OF_R1 + 2 * 245760,
      W + OF_QE1, W + OF_QR1, W + OF_QR1 + 8192, W + OF_QR1 + 16384, W + OF_FN2, fwm, lng, lnb, Z, out);
}

// Round 9
// 208.505 us; speedup vs baseline: 3.5740x; 1.1327x over previous
//
#include <hip/hip_runtime.h>
#include <hip/hip_bf16.h>

// Sizes
#define NB 256
#define NS 30
#define NW 10
#define SYM 128
#define HID 512
#define ENT 64
#define ROLE 32

typedef unsigned short ushortT;
typedef __attribute__((ext_vector_type(8))) short short8v;   // 8 bf16
typedef __attribute__((ext_vector_type(4))) float f32x4;

// Workspace offsets (floats; bf16 arrays use 2 elems per float slot)
static const size_t OF_SENTB = 0;         // 7680*128 bf16 -> 491520 fl
static const size_t OF_QEMBB = 491520;    // 256*128 bf16 -> 16384 fl
static const size_t OF_W1A   = 507904;    // 9*512*128 bf16 -> 294912 fl
static const size_t OF_W2TE  = 802816;    // 3*64*512 bf16 -> 49152 fl
static const size_t OF_W2TR  = 851968;    // 6*32*512 bf16 -> 49152 fl
static const size_t OF_FWMB  = 901120;    // 64*2048 bf16 -> 65536 fl  (fwm^T [f][e*32+r])
static const size_t OF_E1    = 966656;    // 7680*64 x2 (stride 491520)
static const size_t OF_R1    = 1949696;   // 7680*32 x3 (stride 245760)
static const size_t OF_QE1   = 2686976;   // 256*64
static const size_t OF_QR1   = 2703360;   // 256*32 x3 (stride 8192)
static const size_t OF_PP    = 2727936;   // 3 * 7680*64 = 1,474,560
static const size_t OF_FN2   = 4202496;   // 8 partials

__device__ __forceinline__ ushortT f2bf(float x) {
  unsigned u = __float_as_uint(x);
  unsigned r = (u + 0x7fffu + ((u >> 16) & 1u)) >> 16;
  return (ushortT)r;
}
__device__ __forceinline__ float dot4(const float4& a, const float4& b) {
  return a.x * b.x + a.y * b.y + a.z * b.z + a.w * b.w;
}
__device__ __forceinline__ float wreduce64(float v) {
  #pragma unroll
  for (int o = 32; o > 0; o >>= 1) v += __shfl_xor(v, o);
  return v;
}

// ---------------- embedding (bf16 out) ----------------
__global__ __launch_bounds__(128) void embed_k(const int* __restrict__ story, const int* __restrict__ query,
    const float* __restrict__ WE, const float* __restrict__ PE,
    ushortT* __restrict__ sentb, ushortT* __restrict__ qembb) {
  int bs = blockIdx.x; int e = threadIdx.x;
  const int* idx; ushortT* dst;
  if (bs < 7680) { idx = story + (size_t)bs * NW; dst = sentb + (size_t)bs * SYM; }
  else           { idx = query + (size_t)(bs - 7680) * NW; dst = qembb + (size_t)(bs - 7680) * SYM; }
  float acc = 0.f;
  #pragma unroll
  for (int w = 0; w < NW; ++w) {
    int t = idx[w];
    acc += WE[t * SYM + e] * PE[w * SYM + e];
  }
  dst[e] = f2bf(acc);
}

// ---------------- merged convert/transpose kernel (19 y-slices) ----------------
__global__ __launch_bounds__(256) void cvt_k(
    const float* __restrict__ ueW1, const float* __restrict__ urW1,
    const float* __restrict__ ieW1, const float* __restrict__ irW1,
    const float* __restrict__ ueW2, const float* __restrict__ urW2,
    const float* __restrict__ ieW2, const float* __restrict__ irW2,
    const float* __restrict__ fwm,
    ushortT* __restrict__ W1A, ushortT* __restrict__ W2TE,
    ushortT* __restrict__ W2TR, ushortT* __restrict__ fwmBT) {
  int y = blockIdx.y;
  if (y < 9) {
    const float* src = (y < 2) ? ueW1 + (size_t)y * 65536
                     : (y < 5) ? urW1 + (size_t)(y - 2) * 65536
                     : (y == 5) ? ieW1
                     : irW1 + (size_t)(y - 6) * 65536;
    ushortT* d = W1A + (size_t)y * 65536;
    for (int i = blockIdx.x * 256 + threadIdx.x; i < 65536; i += gridDim.x * 256) {
      int r = i >> 9, c = i & 511;
      d[c * 128 + r] = f2bf(src[i]);
    }
  } else if (y < 12) {
    int yy = y - 9;
    const float* src = (yy < 2) ? ueW2 + (size_t)yy * 32768 : ieW2;
    ushortT* d = W2TE + (size_t)yy * 32768;
    for (int i = blockIdx.x * 256 + threadIdx.x; i < 32768; i += gridDim.x * 256) {
      int r = i >> 6, c = i & 63;
      d[c * 512 + r] = f2bf(src[i]);
    }
  } else if (y < 18) {
    int yy = y - 12;
    const float* src = (yy < 3) ? urW2 + (size_t)yy * 16384 : irW2 + (size_t)(yy - 3) * 16384;
    ushortT* d = W2TR + (size_t)yy * 16384;
    for (int i = blockIdx.x * 256 + threadIdx.x; i < 16384; i += gridDim.x * 256) {
      int r = i >> 5, c = i & 31;
      d[c * 512 + r] = f2bf(src[i]);
    }
  } else {
    for (int i = blockIdx.x * 256 + threadIdx.x; i < 131072; i += gridDim.x * 256) {
      int f = i >> 11, kk = i & 2047;
      fwmBT[(size_t)f * 2048 + kk] = f2bf(fwm[(size_t)kk * 64 + f]);
    }
  }
}

// ---------------- MFMA fused 2-layer MLP ----------------
__global__ __launch_bounds__(256) void mlpm_k(
    const ushortT* __restrict__ Xb,
    const ushortT* __restrict__ W1T,
    const float* __restrict__ eb1, const float* __restrict__ rb1,
    const ushortT* __restrict__ W2Te,
    const ushortT* __restrict__ W2Tr,
    const float* __restrict__ eb2, const float* __restrict__ rb2,
    float* __restrict__ Eout, size_t eostride,
    float* __restrict__ Rout, size_t rostride, int eHeads) {
  __shared__ __align__(16) ushortT Hl[32 * 520];
  int r0 = blockIdx.x * 32, h = blockIdx.y, tid = threadIdx.x;
  int wave = tid >> 6, lane = tid & 63;
  int lrow = lane & 15;
  int kgrp = lane >> 4;
  bool isE = h < eHeads;
  int hh = isE ? h : h - eHeads;
  const ushortT* W1h = W1T + (size_t)h * 512 * 128;
  const float* b1 = (isE ? eb1 : rb1) + (size_t)hh * 512;

  int lrw = (wave & 1) * 16;
  int cw  = (wave >> 1) * 256;

  short8v afr[4];
  const ushortT* arow = Xb + (size_t)(r0 + lrw + lrow) * 128 + kgrp * 8;
  #pragma unroll
  for (int kt = 0; kt < 4; ++kt)
    afr[kt] = *reinterpret_cast<const short8v*>(arow + kt * 32);

  for (int ct = 0; ct < 16; ++ct) {
    int c0 = cw + ct * 16;
    f32x4 acc = {0.f, 0.f, 0.f, 0.f};
    const ushortT* bcol = W1h + (size_t)(c0 + lrow) * 128 + kgrp * 8;
    #pragma unroll
    for (int kt = 0; kt < 4; ++kt) {
      short8v bfr = *reinterpret_cast<const short8v*>(bcol + kt * 32);
      acc = __builtin_amdgcn_mfma_f32_16x16x32_bf16(afr[kt], bfr, acc, 0, 0, 0);
    }
    int lcol = c0 + lrow;
    float bb = b1[lcol];
    #pragma unroll
    for (int i = 0; i < 4; ++i) {
      float hv = tanhf(acc[i] + bb);
      Hl[(lrw + kgrp * 4 + i) * 520 + lcol] = f2bf(hv);
    }
  }
  __syncthreads();

  if (isE) {
    const ushortT* W2h = W2Te + (size_t)hh * 64 * 512;
    const float* b2 = eb2 + (size_t)hh * 64;
    int c0w = (wave >> 1) * 32;
    f32x4 acc[2] = {{0.f,0.f,0.f,0.f},{0.f,0.f,0.f,0.f}};
    for (int kt = 0; kt < 16; ++kt) {
      int kb = kt * 32 + kgrp * 8;
      short8v afr2 = *reinterpret_cast<const short8v*>(&Hl[(lrw + lrow) * 520 + kb]);
      #pragma unroll
      for (int t = 0; t < 2; ++t) {
        short8v bfr = *reinterpret_cast<const short8v*>(W2h + (size_t)(c0w + t * 16 + lrow) * 512 + kb);
        acc[t] = __builtin_amdgcn_mfma_f32_16x16x32_bf16(afr2, bfr, acc[t], 0, 0, 0);
      }
    }
    #pragma unroll
    for (int t = 0; t < 2; ++t) {
      int col = c0w + t * 16 + lrow;
      float bb = b2[col];
      #pragma unroll
      for (int i = 0; i < 4; ++i) {
        int grow = r0 + lrw + kgrp * 4 + i;
        Eout[(size_t)hh * eostride + (size_t)grow * 64 + col] = tanhf(acc[t][i] + bb);
      }
    }
  } else {
    const ushortT* W2h = W2Tr + (size_t)hh * 32 * 512;
    const float* b2 = rb2 + (size_t)hh * 32;
    int c0w = (wave >> 1) * 16;
    f32x4 acc = {0.f, 0.f, 0.f, 0.f};
    for (int kt = 0; kt < 16; ++kt) {
      int kb = kt * 32 + kgrp * 8;
      short8v afr2 = *reinterpret_cast<const short8v*>(&Hl[(lrw + lrow) * 520 + kb]);
      short8v bfr = *reinterpret_cast<const short8v*>(W2h + (size_t)(c0w + lrow) * 512 + kb);
      acc = __builtin_amdgcn_mfma_f32_16x16x32_bf16(afr2, bfr, acc, 0, 0, 0);
    }
    int col = c0w + lrow;
    float bb = b2[col];
    #pragma unroll
    for (int i = 0; i < 4; ++i) {
      int grow = r0 + lrw + kgrp * 4 + i;
      Rout[(size_t)hh * rostride + (size_t)grow * 32 + col] = tanhf(acc[i] + bb);
    }
  }
}

// ---------------- ||fwm||^2 partials (8 blocks) ----------------
__global__ __launch_bounds__(256) void fnorm_k(const float* __restrict__ fwm, float* __restrict__ o) {
  __shared__ float red[4];
  int tid = threadIdx.x;
  const float4* f4 = reinterpret_cast<const float4*>(fwm) + blockIdx.x * 4096;
  float a = 0.f;
  for (int i = tid; i < 4096; i += 256) {
    float4 v = f4[i];
    a += v.x*v.x + v.y*v.y + v.z*v.z + v.w*v.w;
  }
  #pragma unroll
  for (int off = 32; off > 0; off >>= 1) a += __shfl_down(a, off);
  if ((tid & 63) == 0) red[tid >> 6] = a;
  __syncthreads();
  if (tid == 0) o[blockIdx.x] = red[0] + red[1] + red[2] + red[3];
}

// ---------------- standalone MFMA P-stage ----------------
// grid 480 (16 s-rows each), 256 thr / 4 waves; wave = one 16-wide f-tile.
// Per e: 1 B-load (shared by 3 MFMAs) + e-scaled accumulation into P1/P2/P3.
__global__ __launch_bounds__(256) void pstage_k(const ushortT* __restrict__ fwmBT,
    const float* __restrict__ e1g, const float* __restrict__ e2g,
    const float* __restrict__ r1g, const float* __restrict__ r2g, const float* __restrict__ r3g,
    float* __restrict__ Pp) {
  __shared__ __align__(16) float e1t[16 * 68], e2t[16 * 68];
  int rb = blockIdx.x, tid = threadIdx.x;
  {
    int row = tid >> 4, c4 = tid & 15;
    float4 v1 = *reinterpret_cast<const float4*>(e1g + ((size_t)rb * 16 + row) * 64 + c4 * 4);
    float4 v2 = *reinterpret_cast<const float4*>(e2g + ((size_t)rb * 16 + row) * 64 + c4 * 4);
    *reinterpret_cast<float4*>(&e1t[row * 68 + c4 * 4]) = v1;
    *reinterpret_cast<float4*>(&e2t[row * 68 + c4 * 4]) = v2;
  }
  int wave = tid >> 6, lane = tid & 63;
  int c = lane & 15, kg = lane >> 4;
  int f0 = wave * 16;
  size_t rbase = ((size_t)rb * 16 + c) * 32 + kg * 8;
  short8v rA, rB, rC;
  {
    float4 x0 = *reinterpret_cast<const float4*>(r1g + rbase);
    float4 x1 = *reinterpret_cast<const float4*>(r1g + rbase + 4);
    ushortT* p = (ushortT*)&rA;
    p[0]=f2bf(x0.x); p[1]=f2bf(x0.y); p[2]=f2bf(x0.z); p[3]=f2bf(x0.w);
    p[4]=f2bf(x1.x); p[5]=f2bf(x1.y); p[6]=f2bf(x1.z); p[7]=f2bf(x1.w);
    x0 = *reinterpret_cast<const float4*>(r2g + rbase);
    x1 = *reinterpret_cast<const float4*>(r2g + rbase + 4);
    p = (ushortT*)&rB;
    p[0]=f2bf(x0.x); p[1]=f2bf(x0.y); p[2]=f2bf(x0.z); p[3]=f2bf(x0.w);
    p[4]=f2bf(x1.x); p[5]=f2bf(x1.y); p[6]=f2bf(x1.z); p[7]=f2bf(x1.w);
    x0 = *reinterpret_cast<const float4*>(r3g + rbase);
    x1 = *reinterpret_cast<const float4*>(r3g + rbase + 4);
    p = (ushortT*)&rC;
    p[0]=f2bf(x0.x); p[1]=f2bf(x0.y); p[2]=f2bf(x0.z); p[3]=f2bf(x0.w);
    p[4]=f2bf(x1.x); p[5]=f2bf(x1.y); p[6]=f2bf(x1.z); p[7]=f2bf(x1.w);
  }
  __syncthreads();
  const ushortT* bbase = fwmBT + (size_t)(f0 + c) * 2048 + kg * 8;
  f32x4 P1 = {0,0,0,0}, P2 = {0,0,0,0}, P3 = {0,0,0,0};
  const f32x4 zero = {0,0,0,0};
  int r0 = kg * 4;
  for (int e4 = 0; e4 < 16; ++e4) {
    float4 ea[4], eb[4];
    #pragma unroll
    for (int i = 0; i < 4; ++i) {
      ea[i] = *reinterpret_cast<const float4*>(&e1t[(r0 + i) * 68 + e4 * 4]);
      eb[i] = *reinterpret_cast<const float4*>(&e2t[(r0 + i) * 68 + e4 * 4]);
    }
    #pragma unroll
    for (int sub = 0; sub < 4; ++sub) {
      int e = e4 * 4 + sub;
      short8v B = *reinterpret_cast<const short8v*>(bbase + (size_t)e * 32);
      f32x4 T1 = __builtin_amdgcn_mfma_f32_16x16x32_bf16(rA, B, zero, 0, 0, 0);
      f32x4 T2 = __builtin_amdgcn_mfma_f32_16x16x32_bf16(rB, B, zero, 0, 0, 0);
      f32x4 T3 = __builtin_amdgcn_mfma_f32_16x16x32_bf16(rC, B, zero, 0, 0, 0);
      #pragma unroll
      for (int i = 0; i < 4; ++i) {
        float e1v = reinterpret_cast<const float*>(&ea[i])[sub];
        float e2v = reinterpret_cast<const float*>(&eb[i])[sub];
        P1[i] += e1v * T1[i];
        P2[i] += e1v * T2[i];
        P3[i] += e2v * T3[i];
      }
    }
  }
  #pragma unroll
  for (int i = 0; i < 4; ++i) {
    size_t row = (size_t)rb * 16 + kg * 4 + i;
    Pp[row * 64 + f0 + c]               = P1[i];
    Pp[491520 + row * 64 + f0 + c]      = P2[i];
    Pp[2 * 491520 + row * 64 + f0 + c]  = P3[i];
  }
}

// ---------------- scan: gram + layers + inference (P from Pp) ----------------
__global__ __launch_bounds__(1024) void scan_k(
    const float* __restrict__ Pp,
    const float* __restrict__ e1g, const float* __restrict__ e2g,
    const float* __restrict__ r1g, const float* __restrict__ r2g, const float* __restrict__ r3g,
    const float* __restrict__ qe1g, const float* __restrict__ qr1g, const float* __restrict__ qr2g,
    const float* __restrict__ qr3g, const float* __restrict__ fn2p, const float* __restrict__ fwm,
    const float* __restrict__ lng, const float* __restrict__ lnb, const float* __restrict__ Zg,
    float* __restrict__ out) {
  __shared__ __align__(16) float MPL[10800];            // gram M; reused as zL + partials in inference
  __shared__ __align__(16) float e1L[2040], e2L[2040];  // [30][68]
  __shared__ __align__(16) float v1L[2040], v2L[2040], v3L[2040];
  __shared__ __align__(16) float r1L[1080], r2L[1080], r3L[1080];  // [30][36]
  __shared__ float uv[64], qv[32], alf[96], siL[64];
  __shared__ float redL[16], scal[2];
  int b = blockIdx.x, tid = threadIdx.x;
  int s = tid >> 5, g = (tid >> 4) & 1, fo = tid & 15;
  int fq = fo * 4;
  bool act = s < 30;

  float H1[4], H2[4], H3[4], a1[4], a2[4], a3[4];
  #pragma unroll
  for (int j = 0; j < 4; ++j) { a1[j] = 0; a2[j] = 0; a3[j] = 0; }
  if (act) {
    size_t base = (size_t)b * 1920 + s * 64 + fq;
    float4 h1 = *reinterpret_cast<const float4*>(Pp + base);
    float4 h2 = *reinterpret_cast<const float4*>(Pp + 491520 + base);
    float4 h3 = *reinterpret_cast<const float4*>(Pp + 983040 + base);
    H1[0]=h1.x; H1[1]=h1.y; H1[2]=h1.z; H1[3]=h1.w;
    H2[0]=h2.x; H2[1]=h2.y; H2[2]=h2.z; H2[3]=h2.w;
    H3[0]=h3.x; H3[1]=h3.y; H3[2]=h3.z; H3[3]=h3.w;
  } else {
    #pragma unroll
    for (int j = 0; j < 4; ++j) { H1[j]=0; H2[j]=0; H3[j]=0; }
  }
  for (int i = tid; i < 1920; i += 1024) {
    int ss = i >> 6, e = i & 63;
    e1L[ss * 68 + e] = e1g[(size_t)b * 1920 + i];
    e2L[ss * 68 + e] = e2g[(size_t)b * 1920 + i];
  }
  for (int i = tid; i < 960; i += 1024) {
    int ss = i >> 5, rr = i & 31;
    r1L[ss * 36 + rr] = r1g[(size_t)b * 960 + i];
    r2L[ss * 36 + rr] = r2g[(size_t)b * 960 + i];
    r3L[ss * 36 + rr] = r3g[(size_t)b * 960 + i];
  }
  __syncthreads();

  // ---- fused gram -> packed MP ----
  if (tid < 900) {
    int si = tid / 30, sj = tid - si * 30;
    float g11 = 0, g12 = 0, g21 = 0, g22 = 0;
    {
      const float4* A1 = reinterpret_cast<const float4*>(&e1L[si * 68]);
      const float4* A2 = reinterpret_cast<const float4*>(&e2L[si * 68]);
      const float4* C1 = reinterpret_cast<const float4*>(&e1L[sj * 68]);
      const float4* C2 = reinterpret_cast<const float4*>(&e2L[sj * 68]);
      #pragma unroll 4
      for (int i = 0; i < 16; ++i) {
        float4 a1v = A1[i], a2v = A2[i], c1v = C1[i], c2v = C2[i];
        g11 += dot4(a1v, c1v); g12 += dot4(a1v, c2v);
        g21 += dot4(a2v, c1v); g22 += dot4(a2v, c2v);
      }
    }
    float R11=0,R12=0,R13=0,R21=0,R22=0,R23=0,R31=0,R32=0,R33=0;
    {
      const float4* X1 = reinterpret_cast<const float4*>(&r1L[si * 36]);
      const float4* X2 = reinterpret_cast<const float4*>(&r2L[si * 36]);
      const float4* X3 = reinterpret_cast<const float4*>(&r3L[si * 36]);
      const float4* Y1 = reinterpret_cast<const float4*>(&r1L[sj * 36]);
      const float4* Y2 = reinterpret_cast<const float4*>(&r2L[sj * 36]);
      const float4* Y3 = reinterpret_cast<const float4*>(&r3L[sj * 36]);
      #pragma unroll 4
      for (int i = 0; i < 8; ++i) {
        float4 x1 = X1[i], x2 = X2[i], x3 = X3[i];
        float4 y1 = Y1[i], y2 = Y2[i], y3 = Y3[i];
        R11 += dot4(x1, y1); R12 += dot4(x1, y2); R13 += dot4(x1, y3);
        R21 += dot4(x2, y1); R22 += dot4(x2, y2); R23 += dot4(x2, y3);
        R31 += dot4(x3, y1); R32 += dot4(x3, y2); R33 += dot4(x3, y3);
      }
    }
    float4* MPv = reinterpret_cast<float4*>(MPL);
    float4 p1; p1.x = g11 * R11; p1.y = g11 * R21; p1.z = g21 * R31; p1.w = 0.f;
    float4 p2; p2.x = g11 * R12; p2.y = g11 * R22; p2.z = g21 * R32; p2.w = 0.f;
    float4 p3; p3.x = g12 * R13; p3.y = g12 * R23; p3.z = g22 * R33; p3.w = 0.f;
    MPv[tid] = p1;
    MPv[900 + tid] = p2;
    MPv[1800 + tid] = p3;
  }
  __syncthreads();

  float n2 = 0.f;
  #pragma unroll
  for (int i = 0; i < 8; ++i) n2 += fn2p[i];
  float c0v = 1.f;

  auto prop = [&](const float* vsrc, int mbase) {
    float d1[4] = {0,0,0,0}, d2[4] = {0,0,0,0}, d3[4] = {0,0,0,0};
    if (act) {
      const float4* mrow = reinterpret_cast<const float4*>(MPL) + mbase + s * 30 + g * 15;
      const float* vb = vsrc + g * 15 * 68 + fq;
      #pragma unroll 5
      for (int i = 0; i < 15; ++i) {
        float4 m = mrow[i];
        float4 vv = *reinterpret_cast<const float4*>(vb + i * 68);
        d1[0]+=m.x*vv.x; d1[1]+=m.x*vv.y; d1[2]+=m.x*vv.z; d1[3]+=m.x*vv.w;
        d2[0]+=m.y*vv.x; d2[1]+=m.y*vv.y; d2[2]+=m.y*vv.z; d2[3]+=m.y*vv.w;
        d3[0]+=m.z*vv.x; d3[1]+=m.z*vv.y; d3[2]+=m.z*vv.z; d3[3]+=m.z*vv.w;
      }
    }
    #pragma unroll
    for (int j = 0; j < 4; ++j) {
      H1[j] += d1[j] + __shfl_xor(d1[j], 16);
      H2[j] += d2[j] + __shfl_xor(d2[j], 16);
      H3[j] += d3[j] + __shfl_xor(d3[j], 16);
    }
  };

  for (int layer = 0; layer < 3; ++layer) {
    float w[4], H2s[4], H3s[4], v1r[4], v2r[4], v3r[4];
    if (act) {
      float4 e2v = *reinterpret_cast<const float4*>(&e2L[s * 68 + fq]);
      w[0]=H1[0]; w[1]=H1[1]; w[2]=H1[2]; w[3]=H1[3];
      #pragma unroll
      for (int j = 0; j < 4; ++j) { H2s[j] = H2[j]; H3s[j] = H3[j]; }
      v1r[0] = e2v.x - H1[0]; v1r[1] = e2v.y - H1[1]; v1r[2] = e2v.z - H1[2]; v1r[3] = e2v.w - H1[3];
      if (g == 0) {
        float4 t; t.x=v1r[0]; t.y=v1r[1]; t.z=v1r[2]; t.w=v1r[3];
        *reinterpret_cast<float4*>(&v1L[s * 68 + fq]) = t;
      }
    }
    __syncthreads();
    prop(v1L, 0);
    if (act) {
      #pragma unroll
      for (int j = 0; j < 4; ++j) v2r[j] = w[j] - H2[j];
      if (g == 0) {
        float4 t; t.x=v2r[0]; t.y=v2r[1]; t.z=v2r[2]; t.w=v2r[3];
        *reinterpret_cast<float4*>(&v2L[s * 68 + fq]) = t;
      }
    }
    __syncthreads();
    prop(v2L, 900);
    if (act) {
      float4 e1v = *reinterpret_cast<const float4*>(&e1L[s * 68 + fq]);
      v3r[0] = e1v.x - H3[0]; v3r[1] = e1v.y - H3[1]; v3r[2] = e1v.z - H3[2]; v3r[3] = e1v.w - H3[3];
      if (g == 0) {
        float4 t; t.x=v3r[0]; t.y=v3r[1]; t.z=v3r[2]; t.w=v3r[3];
        *reinterpret_cast<float4*>(&v3L[s * 68 + fq]) = t;
      }
    }
    __syncthreads();
    prop(v3L, 1800);
    float local = 0.f;
    if (act) {
      #pragma unroll
      for (int j = 0; j < 4; ++j) { a1[j] += v1r[j]; a2[j] += v2r[j]; a3[j] += v3r[j]; }
      if (g == 0) {
        #pragma unroll
        for (int j = 0; j < 4; ++j)
          local += v1r[j] * (w[j] + H1[j]) + v2r[j] * (H2s[j] + H2[j]) + v3r[j] * (H3s[j] + H3[j]);
      }
    }
    local = wreduce64(local);
    if ((tid & 63) == 0) redL[tid >> 6] = local;
    __syncthreads();
    if (tid == 0) {
      float tot = n2;
      #pragma unroll
      for (int i = 0; i < 16; ++i) tot += redL[i];
      float fn = fmaxf(sqrtf(tot), 1.f);
      scal[0] = 1.f / fn; scal[1] = tot;
    }
    __syncthreads();
    float inv = scal[0]; n2 = scal[1] * inv * inv; c0v *= inv;
    if (act) {
      #pragma unroll
      for (int j = 0; j < 4; ++j) { H1[j]*=inv; H2[j]*=inv; H3[j]*=inv; a1[j]*=inv; a2[j]*=inv; a3[j]*=inv; }
    }
    __syncthreads();
  }

  // ---- inference ----
  if (act && g == 0) {
    float4 t1; t1.x=a1[0]; t1.y=a1[1]; t1.z=a1[2]; t1.w=a1[3];
    float4 t2; t2.x=a2[0]; t2.y=a2[1]; t2.z=a2[2]; t2.w=a2[3];
    float4 t3; t3.x=a3[0]; t3.y=a3[1]; t3.z=a3[2]; t3.w=a3[3];
    *reinterpret_cast<float4*>(&v1L[s * 68 + fq]) = t1;
    *reinterpret_cast<float4*>(&v2L[s * 68 + fq]) = t2;
    *reinterpret_cast<float4*>(&v3L[s * 68 + fq]) = t3;
  }
  if (tid < 64) { uv[tid] = qe1g[(size_t)b * 64 + tid]; siL[tid] = 0.f; }
  __syncthreads();
  float* zL = MPL;               // rows [0..32)*68
  float* partL = MPL + 4096;     // [16][64]
  int k32 = tid & 31;
  for (int st = 0; st < 3; ++st) {
    const float* qrg = (st == 0) ? qr1g : ((st == 1) ? qr2g : qr3g);
    if (tid < 32) qv[tid] = qrg[(size_t)b * 32 + tid];
    __syncthreads();
    if (act) {
      float u0 = uv[k32], u1 = uv[k32 + 32];
      float eu1 = e1L[s * 68 + k32] * u0 + e1L[s * 68 + k32 + 32] * u1;
      float eu2 = e2L[s * 68 + k32] * u0 + e2L[s * 68 + k32 + 32] * u1;
      float rq1 = r1L[s * 36 + k32] * qv[k32];
      float rq2 = r2L[s * 36 + k32] * qv[k32];
      float rq3 = r3L[s * 36 + k32] * qv[k32];
      #pragma unroll
      for (int d = 16; d > 0; d >>= 1) {
        eu1 += __shfl_down(eu1, d, 32); eu2 += __shfl_down(eu2, d, 32);
        rq1 += __shfl_down(rq1, d, 32); rq2 += __shfl_down(rq2, d, 32); rq3 += __shfl_down(rq3, d, 32);
      }
      if (k32 == 0) { alf[s] = eu1 * rq1; alf[32 + s] = eu1 * rq2; alf[64 + s] = eu2 * rq3; }
    }
    float z0 = 0.f, z1 = 0.f;
    {
      const float* fb = fwm + s * 64 + k32 * 2;
      for (int e = 0; e < 64; ++e) {
        float u = uv[e];
        z0 += u * fb[(size_t)e * 2048];
        z1 += u * fb[(size_t)e * 2048 + 1];
      }
    }
    {
      float q = qv[s];
      zL[s * 68 + k32 * 2]     = q * z0;
      zL[s * 68 + k32 * 2 + 1] = q * z1;
    }
    __syncthreads();
    {
      int p = tid >> 6, f = tid & 63;
      float part;
      if (p < 15) {
        int sp = p * 2;
        part = alf[sp] * v1L[sp * 68 + f] + alf[32 + sp] * v2L[sp * 68 + f] + alf[64 + sp] * v3L[sp * 68 + f]
             + alf[sp + 1] * v1L[(sp + 1) * 68 + f] + alf[33 + sp] * v2L[(sp + 1) * 68 + f]
             + alf[65 + sp] * v3L[(sp + 1) * 68 + f];
      } else {
        float F = 0.f;
        #pragma unroll 8
        for (int rr = 0; rr < 32; ++rr) F += zL[rr * 68 + f];
        part = c0v * F;
      }
      partL[p * 64 + f] = part;
    }
    __syncthreads();
    if (tid < 64) {
      float raw = 0.f;
      #pragma unroll
      for (int p = 0; p < 16; ++p) raw += partL[p * 64 + tid];
      float mean = wreduce64(raw) * (1.f / 64.f);
      float d = raw - mean;
      float var = wreduce64(d * d) * (1.f / 63.f);
      float y = lng[st * 64 + tid] * d / (sqrtf(var) + 1e-6f) + lnb[st * 64 + tid];
      siL[tid] += y;
      uv[tid] = y;
    }
    __syncthreads();
  }
  if (tid < 9) {
    float o = 0.f;
    for (int ff = 0; ff < 64; ++ff) o += siL[ff] * Zg[ff * 9 + tid];
    out[(size_t)b * 9 + tid] = o;
  }
}

extern "C" void kernel_launch(void* const* d_in, const int* in_sizes, int n_in,
                              void* d_out, int out_size, void* d_ws, size_t ws_size,
                              hipStream_t stream) {
  const int*   story = (const int*)d_in[0];
  const int*   query = (const int*)d_in[1];
  const float* WE    = (const float*)d_in[2];
  const float* PE    = (const float*)d_in[3];
  const float* ueW1  = (const float*)d_in[4];
  const float* ueb1  = (const float*)d_in[5];
  const float* ueW2  = (const float*)d_in[6];
  const float* ueb2  = (const float*)d_in[7];
  const float* urW1  = (const float*)d_in[8];
  const float* urb1  = (const float*)d_in[9];
  const float* urW2  = (const float*)d_in[10];
  const float* urb2  = (const float*)d_in[11];
  const float* fwm   = (const float*)d_in[12];
  const float* ieW1  = (const float*)d_in[13];
  const float* ieb1  = (const float*)d_in[14];
  const float* ieW2  = (const float*)d_in[15];
  const float* ieb2  = (const float*)d_in[16];
  const float* irW1  = (const float*)d_in[17];
  const float* irb1  = (const float*)d_in[18];
  const float* irW2  = (const float*)d_in[19];
  const float* irb2  = (const float*)d_in[20];
  const float* lng   = (const float*)d_in[21];
  const float* lnb   = (const float*)d_in[22];
  const float* Z     = (const float*)d_in[23];
  float* W = (float*)d_ws;
  float* out = (float*)d_out;

  ushortT* sentB = (ushortT*)(W + OF_SENTB);
  ushortT* qembB = (ushortT*)(W + OF_QEMBB);
  ushortT* W1A   = (ushortT*)(W + OF_W1A);
  ushortT* W2TE  = (ushortT*)(W + OF_W2TE);
  ushortT* W2TR  = (ushortT*)(W + OF_W2TR);
  ushortT* fwmBT = (ushortT*)(W + OF_FWMB);

  embed_k<<<7936, 128, 0, stream>>>(story, query, WE, PE, sentB, qembB);

  cvt_k<<<dim3(32, 19), 256, 0, stream>>>(ueW1, urW1, ieW1, irW1,
      ueW2, urW2, ieW2, irW2, fwm, W1A, W2TE, W2TR, fwmBT);

  // story heads 0..4 (ue0,ue1,ur0,ur1,ur2); query heads 5..8 (ie0,ir0,ir1,ir2)
  mlpm_k<<<dim3(240, 5), 256, 0, stream>>>(sentB, W1A, ueb1, urb1, W2TE, W2TR, ueb2, urb2,
      W + OF_E1, 491520, W + OF_R1, 245760, 2);
  mlpm_k<<<dim3(8, 4), 256, 0, stream>>>(qembB, W1A + (size_t)5 * 65536, ieb1, irb1,
      W2TE + (size_t)2 * 32768, W2TR + (size_t)3 * 16384, ieb2, irb2,
      W + OF_QE1, 16384, W + OF_QR1, 8192, 1);

  fnorm_k<<<8, 256, 0, stream>>>(fwm, W + OF_FN2);
  pstage_k<<<480, 256, 0, stream>>>(fwmBT, W + OF_E1, W + OF_E1 + 491520,
      W + OF_R1, W + OF_R1 + 245760, W + OF_R1 + 2 * 245760, W + OF_PP);
  scan_k<<<NB, 1024, 0, stream>>>(W + OF_PP, W + OF_E1, W + OF_E1 + 491520,
      W + OF_R1, W + OF_R1 + 245760, W + OF_R1 + 2 * 245760,
      W + OF_QE1, W + OF_QR1, W + OF_QR1 + 8192, W + OF_QR1 + 16384, W + OF_FN2, fwm, lng, lnb, Z, out);
}

// Round 10
// 191.131 us; speedup vs baseline: 3.8989x; 1.0909x over previous
//
#include <hip/hip_runtime.h>
#include <hip/hip_bf16.h>

// Sizes
#define NB 256
#define NS 30
#define NW 10
#define SYM 128
#define HID 512
#define ENT 64
#define ROLE 32

typedef unsigned short ushortT;
typedef __attribute__((ext_vector_type(8))) short short8v;   // 8 bf16
typedef __attribute__((ext_vector_type(4))) float f32x4;

// Workspace offsets (floats; bf16 arrays use 2 elems per float slot)
static const size_t OF_SENTB = 0;         // 7680*128 bf16 -> 491520 fl
static const size_t OF_QEMBB = 491520;    // 256*128 bf16 -> 16384 fl
static const size_t OF_W1A   = 507904;    // 9*512*128 bf16 -> 294912 fl
static const size_t OF_W2TE  = 802816;    // 3*64*512 bf16 -> 49152 fl
static const size_t OF_W2TR  = 851968;    // 6*32*512 bf16 -> 49152 fl
static const size_t OF_FWMB  = 901120;    // 64*2048 bf16 -> 65536 fl  (fwm^T [f][e*32+r])
static const size_t OF_E1    = 966656;    // 7680*64 x2 (stride 491520)
static const size_t OF_R1    = 1949696;   // 7680*32 x3 (stride 245760)
static const size_t OF_QE1   = 2686976;   // 256*64
static const size_t OF_QR1   = 2703360;   // 256*32 x3 (stride 8192)
static const size_t OF_PP    = 2727936;   // 3 * 7680*64 = 1,474,560
static const size_t OF_FN2   = 4202496;   // 8 partials

__device__ __forceinline__ ushortT f2bf(float x) {
  unsigned u = __float_as_uint(x);
  unsigned r = (u + 0x7fffu + ((u >> 16) & 1u)) >> 16;
  return (ushortT)r;
}
__device__ __forceinline__ float dot4(const float4& a, const float4& b) {
  return a.x * b.x + a.y * b.y + a.z * b.z + a.w * b.w;
}
__device__ __forceinline__ float wreduce64(float v) {
  #pragma unroll
  for (int o = 32; o > 0; o >>= 1) v += __shfl_xor(v, o);
  return v;
}

// ---------------- unified prep: embed + all transposes/converts + fnorm partials ----------------
// blocks [0,3968): embed (2 rows each). [3968,+144): W1 tiles. +24: W2E. +48: W2R. +32: fwmBT. +8: fnorm.
__global__ __launch_bounds__(256) void prep_k(
    const int* __restrict__ story, const int* __restrict__ query,
    const float* __restrict__ WE, const float* __restrict__ PE,
    const float* __restrict__ ueW1, const float* __restrict__ urW1,
    const float* __restrict__ ieW1, const float* __restrict__ irW1,
    const float* __restrict__ ueW2, const float* __restrict__ urW2,
    const float* __restrict__ ieW2, const float* __restrict__ irW2,
    const float* __restrict__ fwm,
    ushortT* __restrict__ sentb, ushortT* __restrict__ qembb,
    ushortT* __restrict__ W1A, ushortT* __restrict__ W2TE,
    ushortT* __restrict__ W2TR, ushortT* __restrict__ fwmBT,
    float* __restrict__ fn2) {
  __shared__ float tl[64 * 65];
  __shared__ float red[4];
  int bx = blockIdx.x, tid = threadIdx.x;
  if (bx < 3968) {
    int row = bx * 2 + (tid >> 7);
    int e = tid & 127;
    const int* idx; ushortT* dst;
    if (row < 7680) { idx = story + (size_t)row * NW; dst = sentb + (size_t)row * SYM; }
    else            { idx = query + (size_t)(row - 7680) * NW; dst = qembb + (size_t)(row - 7680) * SYM; }
    float acc = 0.f;
    #pragma unroll
    for (int w = 0; w < NW; ++w) acc += WE[idx[w] * SYM + e] * PE[w * SYM + e];
    dst[e] = f2bf(acc);
    return;
  }
  bx -= 3968;
  const float* src; ushortT* dst; int R, C, tr0, tc0;
  if (bx < 144) {            // W1: [128][512] -> [512][128], 9 heads x 16 tiles
    int h = bx >> 4, t = bx & 15;
    src = (h < 2) ? ueW1 + (size_t)h * 65536 : (h < 5) ? urW1 + (size_t)(h - 2) * 65536
        : (h == 5) ? ieW1 : irW1 + (size_t)(h - 6) * 65536;
    dst = W1A + (size_t)h * 65536;
    R = 128; C = 512; tr0 = (t >> 3) * 64; tc0 = (t & 7) * 64;
  } else if (bx < 168) {     // W2E: [512][64] -> [64][512], 3 heads x 8 tiles
    int h = (bx - 144) >> 3, t = (bx - 144) & 7;
    src = (h < 2) ? ueW2 + (size_t)h * 32768 : ieW2;
    dst = W2TE + (size_t)h * 32768;
    R = 512; C = 64; tr0 = t * 64; tc0 = 0;
  } else if (bx < 216) {     // W2R: [512][32] -> [32][512], 6 heads x 8 tiles
    int h = (bx - 168) >> 3, t = (bx - 168) & 7;
    src = (h < 3) ? urW2 + (size_t)h * 16384 : irW2 + (size_t)(h - 3) * 16384;
    dst = W2TR + (size_t)h * 16384;
    R = 512; C = 32; tr0 = t * 64; tc0 = 0;
  } else if (bx < 248) {     // fwm: [2048][64] -> [64][2048], 32 tiles
    int t = bx - 216;
    src = fwm; dst = fwmBT; R = 2048; C = 64; tr0 = t * 64; tc0 = 0;
  } else {                   // fnorm partials (8 blocks)
    int blk = bx - 248;
    const float4* f4 = reinterpret_cast<const float4*>(fwm) + blk * 4096;
    float a = 0.f;
    for (int i = tid; i < 4096; i += 256) {
      float4 v = f4[i];
      a += v.x*v.x + v.y*v.y + v.z*v.z + v.w*v.w;
    }
    a = wreduce64(a);
    if ((tid & 63) == 0) red[tid >> 6] = a;
    __syncthreads();
    if (tid == 0) fn2[blk] = red[0] + red[1] + red[2] + red[3];
    return;
  }
  int TC = (C < 64) ? C : 64;
  int n = 64 * TC;
  for (int i = tid; i < n; i += 256) {
    int r = i / TC, c = i % TC;
    tl[r * 65 + c] = src[(size_t)(tr0 + r) * C + tc0 + c];
  }
  __syncthreads();
  for (int i = tid; i < n; i += 256) {
    int c = i >> 6, r = i & 63;
    dst[(size_t)(tc0 + c) * R + tr0 + r] = f2bf(tl[r * 65 + c]);
  }
}

// ---------------- MFMA fused 2-layer MLP (story y=0..4; query y=5..8 on x<8) ----------------
__global__ __launch_bounds__(256) void mlpm_k(
    const ushortT* __restrict__ sentB, const ushortT* __restrict__ qembB,
    const ushortT* __restrict__ W1A,
    const float* __restrict__ ueb1, const float* __restrict__ urb1,
    const float* __restrict__ ieb1, const float* __restrict__ irb1,
    const ushortT* __restrict__ W2TE, const ushortT* __restrict__ W2TR,
    const float* __restrict__ ueb2, const float* __restrict__ urb2,
    const float* __restrict__ ieb2, const float* __restrict__ irb2,
    float* __restrict__ E1, float* __restrict__ R1,
    float* __restrict__ QE1, float* __restrict__ QR1) {
  __shared__ __align__(16) ushortT Hl[32 * 520];
  int y = blockIdx.y;
  bool isQ = y >= 5;
  if (isQ && blockIdx.x >= 8) return;
  int r0 = blockIdx.x * 32, tid = threadIdx.x;
  int wave = tid >> 6, lane = tid & 63;
  int lrow = lane & 15;
  int kgrp = lane >> 4;
  const ushortT* Xb = isQ ? qembB : sentB;
  const ushortT* W1h = W1A + (size_t)y * 65536;
  const float* b1 = (y < 2) ? ueb1 + y * 512 : (y < 5) ? urb1 + (y - 2) * 512
                  : (y == 5) ? ieb1 : irb1 + (y - 6) * 512;
  bool isE = (y < 2) || (y == 5);

  int lrw = (wave & 1) * 16;
  int cw  = (wave >> 1) * 256;

  short8v afr[4];
  const ushortT* arow = Xb + (size_t)(r0 + lrw + lrow) * 128 + kgrp * 8;
  #pragma unroll
  for (int kt = 0; kt < 4; ++kt)
    afr[kt] = *reinterpret_cast<const short8v*>(arow + kt * 32);

  for (int ct = 0; ct < 16; ++ct) {
    int c0 = cw + ct * 16;
    f32x4 acc = {0.f, 0.f, 0.f, 0.f};
    const ushortT* bcol = W1h + (size_t)(c0 + lrow) * 128 + kgrp * 8;
    #pragma unroll
    for (int kt = 0; kt < 4; ++kt) {
      short8v bfr = *reinterpret_cast<const short8v*>(bcol + kt * 32);
      acc = __builtin_amdgcn_mfma_f32_16x16x32_bf16(afr[kt], bfr, acc, 0, 0, 0);
    }
    int lcol = c0 + lrow;
    float bb = b1[lcol];
    #pragma unroll
    for (int i = 0; i < 4; ++i) {
      float hv = tanhf(acc[i] + bb);
      Hl[(lrw + kgrp * 4 + i) * 520 + lcol] = f2bf(hv);
    }
  }
  __syncthreads();

  if (isE) {
    int slot = (y == 5) ? 2 : y;
    const ushortT* W2h = W2TE + (size_t)slot * 32768;
    const float* b2 = (y == 5) ? ieb2 : ueb2 + y * 64;
    float* Out = (y == 5) ? QE1 : E1 + (size_t)y * 491520;
    int c0w = (wave >> 1) * 32;
    f32x4 acc[2] = {{0.f,0.f,0.f,0.f},{0.f,0.f,0.f,0.f}};
    for (int kt = 0; kt < 16; ++kt) {
      int kb = kt * 32 + kgrp * 8;
      short8v afr2 = *reinterpret_cast<const short8v*>(&Hl[(lrw + lrow) * 520 + kb]);
      #pragma unroll
      for (int t = 0; t < 2; ++t) {
        short8v bfr = *reinterpret_cast<const short8v*>(W2h + (size_t)(c0w + t * 16 + lrow) * 512 + kb);
        acc[t] = __builtin_amdgcn_mfma_f32_16x16x32_bf16(afr2, bfr, acc[t], 0, 0, 0);
      }
    }
    #pragma unroll
    for (int t = 0; t < 2; ++t) {
      int col = c0w + t * 16 + lrow;
      float bb = b2[col];
      #pragma unroll
      for (int i = 0; i < 4; ++i) {
        int grow = r0 + lrw + kgrp * 4 + i;
        Out[(size_t)grow * 64 + col] = tanhf(acc[t][i] + bb);
      }
    }
  } else {
    int slot = (y < 5) ? (y - 2) : (3 + y - 6);
    const ushortT* W2h = W2TR + (size_t)slot * 16384;
    const float* b2 = (y < 5) ? urb2 + (y - 2) * 32 : irb2 + (y - 6) * 32;
    float* Out = (y < 5) ? R1 + (size_t)(y - 2) * 245760 : QR1 + (size_t)(y - 6) * 8192;
    int c0w = (wave >> 1) * 16;
    f32x4 acc = {0.f, 0.f, 0.f, 0.f};
    for (int kt = 0; kt < 16; ++kt) {
      int kb = kt * 32 + kgrp * 8;
      short8v afr2 = *reinterpret_cast<const short8v*>(&Hl[(lrw + lrow) * 520 + kb]);
      short8v bfr = *reinterpret_cast<const short8v*>(W2h + (size_t)(c0w + lrow) * 512 + kb);
      acc = __builtin_amdgcn_mfma_f32_16x16x32_bf16(afr2, bfr, acc, 0, 0, 0);
    }
    int col = c0w + lrow;
    float bb = b2[col];
    #pragma unroll
    for (int i = 0; i < 4; ++i) {
      int grow = r0 + lrw + kgrp * 4 + i;
      Out[(size_t)grow * 32 + col] = tanhf(acc[i] + bb);
    }
  }
}

// ---------------- standalone MFMA P-stage ----------------
__global__ __launch_bounds__(256) void pstage_k(const ushortT* __restrict__ fwmBT,
    const float* __restrict__ e1g, const float* __restrict__ e2g,
    const float* __restrict__ r1g, const float* __restrict__ r2g, const float* __restrict__ r3g,
    float* __restrict__ Pp) {
  __shared__ __align__(16) float e1t[16 * 68], e2t[16 * 68];
  int rb = blockIdx.x, tid = threadIdx.x;
  {
    int row = tid >> 4, c4 = tid & 15;
    float4 v1 = *reinterpret_cast<const float4*>(e1g + ((size_t)rb * 16 + row) * 64 + c4 * 4);
    float4 v2 = *reinterpret_cast<const float4*>(e2g + ((size_t)rb * 16 + row) * 64 + c4 * 4);
    *reinterpret_cast<float4*>(&e1t[row * 68 + c4 * 4]) = v1;
    *reinterpret_cast<float4*>(&e2t[row * 68 + c4 * 4]) = v2;
  }
  int wave = tid >> 6, lane = tid & 63;
  int c = lane & 15, kg = lane >> 4;
  int f0 = wave * 16;
  size_t rbase = ((size_t)rb * 16 + c) * 32 + kg * 8;
  short8v rA, rB, rC;
  {
    float4 x0 = *reinterpret_cast<const float4*>(r1g + rbase);
    float4 x1 = *reinterpret_cast<const float4*>(r1g + rbase + 4);
    ushortT* p = (ushortT*)&rA;
    p[0]=f2bf(x0.x); p[1]=f2bf(x0.y); p[2]=f2bf(x0.z); p[3]=f2bf(x0.w);
    p[4]=f2bf(x1.x); p[5]=f2bf(x1.y); p[6]=f2bf(x1.z); p[7]=f2bf(x1.w);
    x0 = *reinterpret_cast<const float4*>(r2g + rbase);
    x1 = *reinterpret_cast<const float4*>(r2g + rbase + 4);
    p = (ushortT*)&rB;
    p[0]=f2bf(x0.x); p[1]=f2bf(x0.y); p[2]=f2bf(x0.z); p[3]=f2bf(x0.w);
    p[4]=f2bf(x1.x); p[5]=f2bf(x1.y); p[6]=f2bf(x1.z); p[7]=f2bf(x1.w);
    x0 = *reinterpret_cast<const float4*>(r3g + rbase);
    x1 = *reinterpret_cast<const float4*>(r3g + rbase + 4);
    p = (ushortT*)&rC;
    p[0]=f2bf(x0.x); p[1]=f2bf(x0.y); p[2]=f2bf(x0.z); p[3]=f2bf(x0.w);
    p[4]=f2bf(x1.x); p[5]=f2bf(x1.y); p[6]=f2bf(x1.z); p[7]=f2bf(x1.w);
  }
  __syncthreads();
  const ushortT* bbase = fwmBT + (size_t)(f0 + c) * 2048 + kg * 8;
  f32x4 P1 = {0,0,0,0}, P2 = {0,0,0,0}, P3 = {0,0,0,0};
  const f32x4 zero = {0,0,0,0};
  int r0 = kg * 4;
  for (int e4 = 0; e4 < 16; ++e4) {
    float4 ea[4], eb[4];
    #pragma unroll
    for (int i = 0; i < 4; ++i) {
      ea[i] = *reinterpret_cast<const float4*>(&e1t[(r0 + i) * 68 + e4 * 4]);
      eb[i] = *reinterpret_cast<const float4*>(&e2t[(r0 + i) * 68 + e4 * 4]);
    }
    #pragma unroll
    for (int sub = 0; sub < 4; ++sub) {
      int e = e4 * 4 + sub;
      short8v B = *reinterpret_cast<const short8v*>(bbase + (size_t)e * 32);
      f32x4 T1 = __builtin_amdgcn_mfma_f32_16x16x32_bf16(rA, B, zero, 0, 0, 0);
      f32x4 T2 = __builtin_amdgcn_mfma_f32_16x16x32_bf16(rB, B, zero, 0, 0, 0);
      f32x4 T3 = __builtin_amdgcn_mfma_f32_16x16x32_bf16(rC, B, zero, 0, 0, 0);
      #pragma unroll
      for (int i = 0; i < 4; ++i) {
        float e1v = reinterpret_cast<const float*>(&ea[i])[sub];
        float e2v = reinterpret_cast<const float*>(&eb[i])[sub];
        P1[i] += e1v * T1[i];
        P2[i] += e1v * T2[i];
        P3[i] += e2v * T3[i];
      }
    }
  }
  #pragma unroll
  for (int i = 0; i < 4; ++i) {
    size_t row = (size_t)rb * 16 + kg * 4 + i;
    Pp[row * 64 + f0 + c]               = P1[i];
    Pp[491520 + row * 64 + f0 + c]      = P2[i];
    Pp[2 * 491520 + row * 64 + f0 + c]  = P3[i];
  }
}

// ---------------- scan: gram + layers + inference ----------------
__global__ __launch_bounds__(1024) void scan_k(
    const float* __restrict__ Pp,
    const float* __restrict__ e1g, const float* __restrict__ e2g,
    const float* __restrict__ r1g, const float* __restrict__ r2g, const float* __restrict__ r3g,
    const float* __restrict__ qe1g, const float* __restrict__ qr1g, const float* __restrict__ qr2g,
    const float* __restrict__ qr3g, const float* __restrict__ fn2p, const float* __restrict__ fwm,
    const float* __restrict__ lng, const float* __restrict__ lnb, const float* __restrict__ Zg,
    float* __restrict__ out) {
  __shared__ __align__(16) float MPL[10800];            // gram M; reused as zL + partials
  __shared__ __align__(16) float e1L[2040], e2L[2040];  // [30][68]
  __shared__ __align__(16) float v1L[2040], v2L[2040], v3L[2040];
  __shared__ __align__(16) float r1L[1080], r2L[1080], r3L[1080];  // [30][36]
  __shared__ float uv[64], qv[96], alf[96], siL[64];
  __shared__ float redL[16], scal[2];
  int b = blockIdx.x, tid = threadIdx.x;
  int s = tid >> 5, g = (tid >> 4) & 1, fo = tid & 15;
  int fq = fo * 4;
  bool act = s < 30;

  float H1[4], H2[4], H3[4], a1[4], a2[4], a3[4];
  #pragma unroll
  for (int j = 0; j < 4; ++j) { a1[j] = 0; a2[j] = 0; a3[j] = 0; }
  if (act) {
    size_t base = (size_t)b * 1920 + s * 64 + fq;
    float4 h1 = *reinterpret_cast<const float4*>(Pp + base);
    float4 h2 = *reinterpret_cast<const float4*>(Pp + 491520 + base);
    float4 h3 = *reinterpret_cast<const float4*>(Pp + 983040 + base);
    H1[0]=h1.x; H1[1]=h1.y; H1[2]=h1.z; H1[3]=h1.w;
    H2[0]=h2.x; H2[1]=h2.y; H2[2]=h2.z; H2[3]=h2.w;
    H3[0]=h3.x; H3[1]=h3.y; H3[2]=h3.z; H3[3]=h3.w;
  } else {
    #pragma unroll
    for (int j = 0; j < 4; ++j) { H1[j]=0; H2[j]=0; H3[j]=0; }
  }
  // vectorized staging: 480+480 e-float4s, 3x240 r-float4s
  for (int i = tid; i < 1680; i += 1024) {
    if (i < 480) {
      int ss = i >> 4, c4 = i & 15;
      *reinterpret_cast<float4*>(&e1L[ss * 68 + c4 * 4]) =
          *reinterpret_cast<const float4*>(e1g + (size_t)b * 1920 + i * 4);
    } else if (i < 960) {
      int j = i - 480;
      int ss = j >> 4, c4 = j & 15;
      *reinterpret_cast<float4*>(&e2L[ss * 68 + c4 * 4]) =
          *reinterpret_cast<const float4*>(e2g + (size_t)b * 1920 + j * 4);
    } else {
      int j = i - 960;
      int which = j / 240, jj = j - which * 240;
      int ss = jj >> 3, c4 = jj & 7;
      float* dstL = (which == 0) ? r1L : (which == 1) ? r2L : r3L;
      const float* srcG = (which == 0) ? r1g : (which == 1) ? r2g : r3g;
      *reinterpret_cast<float4*>(&dstL[ss * 36 + c4 * 4]) =
          *reinterpret_cast<const float4*>(srcG + (size_t)b * 960 + jj * 4);
    }
  }
  __syncthreads();

  // ---- fused gram -> packed MP ----
  if (tid < 900) {
    int si = tid / 30, sj = tid - si * 30;
    float g11 = 0, g12 = 0, g21 = 0, g22 = 0;
    {
      const float4* A1 = reinterpret_cast<const float4*>(&e1L[si * 68]);
      const float4* A2 = reinterpret_cast<const float4*>(&e2L[si * 68]);
      const float4* C1 = reinterpret_cast<const float4*>(&e1L[sj * 68]);
      const float4* C2 = reinterpret_cast<const float4*>(&e2L[sj * 68]);
      #pragma unroll 4
      for (int i = 0; i < 16; ++i) {
        float4 a1v = A1[i], a2v = A2[i], c1v = C1[i], c2v = C2[i];
        g11 += dot4(a1v, c1v); g12 += dot4(a1v, c2v);
        g21 += dot4(a2v, c1v); g22 += dot4(a2v, c2v);
      }
    }
    float R11=0,R12=0,R13=0,R21=0,R22=0,R23=0,R31=0,R32=0,R33=0;
    {
      const float4* X1 = reinterpret_cast<const float4*>(&r1L[si * 36]);
      const float4* X2 = reinterpret_cast<const float4*>(&r2L[si * 36]);
      const float4* X3 = reinterpret_cast<const float4*>(&r3L[si * 36]);
      const float4* Y1 = reinterpret_cast<const float4*>(&r1L[sj * 36]);
      const float4* Y2 = reinterpret_cast<const float4*>(&r2L[sj * 36]);
      const float4* Y3 = reinterpret_cast<const float4*>(&r3L[sj * 36]);
      #pragma unroll 4
      for (int i = 0; i < 8; ++i) {
        float4 x1 = X1[i], x2 = X2[i], x3 = X3[i];
        float4 y1 = Y1[i], y2 = Y2[i], y3 = Y3[i];
        R11 += dot4(x1, y1); R12 += dot4(x1, y2); R13 += dot4(x1, y3);
        R21 += dot4(x2, y1); R22 += dot4(x2, y2); R23 += dot4(x2, y3);
        R31 += dot4(x3, y1); R32 += dot4(x3, y2); R33 += dot4(x3, y3);
      }
    }
    float4* MPv = reinterpret_cast<float4*>(MPL);
    float4 p1; p1.x = g11 * R11; p1.y = g11 * R21; p1.z = g21 * R31; p1.w = 0.f;
    float4 p2; p2.x = g11 * R12; p2.y = g11 * R22; p2.z = g21 * R32; p2.w = 0.f;
    float4 p3; p3.x = g12 * R13; p3.y = g12 * R23; p3.z = g22 * R33; p3.w = 0.f;
    MPv[tid] = p1;
    MPv[900 + tid] = p2;
    MPv[1800 + tid] = p3;
  }
  __syncthreads();

  float n2 = 0.f;
  #pragma unroll
  for (int i = 0; i < 8; ++i) n2 += fn2p[i];
  float c0v = 1.f;

  auto prop = [&](const float* vsrc, int mbase) {
    float d1[4] = {0,0,0,0}, d2[4] = {0,0,0,0}, d3[4] = {0,0,0,0};
    if (act) {
      const float4* mrow = reinterpret_cast<const float4*>(MPL) + mbase + s * 30 + g * 15;
      const float* vb = vsrc + g * 15 * 68 + fq;
      #pragma unroll 5
      for (int i = 0; i < 15; ++i) {
        float4 m = mrow[i];
        float4 vv = *reinterpret_cast<const float4*>(vb + i * 68);
        d1[0]+=m.x*vv.x; d1[1]+=m.x*vv.y; d1[2]+=m.x*vv.z; d1[3]+=m.x*vv.w;
        d2[0]+=m.y*vv.x; d2[1]+=m.y*vv.y; d2[2]+=m.y*vv.z; d2[3]+=m.y*vv.w;
        d3[0]+=m.z*vv.x; d3[1]+=m.z*vv.y; d3[2]+=m.z*vv.z; d3[3]+=m.z*vv.w;
      }
    }
    #pragma unroll
    for (int j = 0; j < 4; ++j) {
      H1[j] += d1[j] + __shfl_xor(d1[j], 16);
      H2[j] += d2[j] + __shfl_xor(d2[j], 16);
      H3[j] += d3[j] + __shfl_xor(d3[j], 16);
    }
  };

  for (int layer = 0; layer < 3; ++layer) {
    float w[4], H2s[4], H3s[4], v1r[4], v2r[4], v3r[4];
    if (act) {
      float4 e2v = *reinterpret_cast<const float4*>(&e2L[s * 68 + fq]);
      w[0]=H1[0]; w[1]=H1[1]; w[2]=H1[2]; w[3]=H1[3];
      #pragma unroll
      for (int j = 0; j < 4; ++j) { H2s[j] = H2[j]; H3s[j] = H3[j]; }
      v1r[0] = e2v.x - H1[0]; v1r[1] = e2v.y - H1[1]; v1r[2] = e2v.z - H1[2]; v1r[3] = e2v.w - H1[3];
      if (g == 0) {
        float4 t; t.x=v1r[0]; t.y=v1r[1]; t.z=v1r[2]; t.w=v1r[3];
        *reinterpret_cast<float4*>(&v1L[s * 68 + fq]) = t;
      }
    }
    __syncthreads();
    prop(v1L, 0);
    if (act) {
      #pragma unroll
      for (int j = 0; j < 4; ++j) v2r[j] = w[j] - H2[j];
      if (g == 0) {
        float4 t; t.x=v2r[0]; t.y=v2r[1]; t.z=v2r[2]; t.w=v2r[3];
        *reinterpret_cast<float4*>(&v2L[s * 68 + fq]) = t;
      }
    }
    __syncthreads();
    prop(v2L, 900);
    if (act) {
      float4 e1v = *reinterpret_cast<const float4*>(&e1L[s * 68 + fq]);
      v3r[0] = e1v.x - H3[0]; v3r[1] = e1v.y - H3[1]; v3r[2] = e1v.z - H3[2]; v3r[3] = e1v.w - H3[3];
      if (g == 0) {
        float4 t; t.x=v3r[0]; t.y=v3r[1]; t.z=v3r[2]; t.w=v3r[3];
        *reinterpret_cast<float4*>(&v3L[s * 68 + fq]) = t;
      }
    }
    __syncthreads();
    prop(v3L, 1800);
    float local = 0.f;
    if (act) {
      #pragma unroll
      for (int j = 0; j < 4; ++j) { a1[j] += v1r[j]; a2[j] += v2r[j]; a3[j] += v3r[j]; }
      if (g == 0) {
        #pragma unroll
        for (int j = 0; j < 4; ++j)
          local += v1r[j] * (w[j] + H1[j]) + v2r[j] * (H2s[j] + H2[j]) + v3r[j] * (H3s[j] + H3[j]);
      }
    }
    local = wreduce64(local);
    if ((tid & 63) == 0) redL[tid >> 6] = local;
    __syncthreads();
    if (tid == 0) {
      float tot = n2;
      #pragma unroll
      for (int i = 0; i < 16; ++i) tot += redL[i];
      float fn = fmaxf(sqrtf(tot), 1.f);
      scal[0] = 1.f / fn; scal[1] = tot;
    }
    __syncthreads();
    float inv = scal[0]; n2 = scal[1] * inv * inv; c0v *= inv;
    if (act) {
      #pragma unroll
      for (int j = 0; j < 4; ++j) { H1[j]*=inv; H2[j]*=inv; H3[j]*=inv; a1[j]*=inv; a2[j]*=inv; a3[j]*=inv; }
    }
  }

  // ---- inference ----
  if (act && g == 0) {
    float4 t1; t1.x=a1[0]; t1.y=a1[1]; t1.z=a1[2]; t1.w=a1[3];
    float4 t2; t2.x=a2[0]; t2.y=a2[1]; t2.z=a2[2]; t2.w=a2[3];
    float4 t3; t3.x=a3[0]; t3.y=a3[1]; t3.z=a3[2]; t3.w=a3[3];
    *reinterpret_cast<float4*>(&v1L[s * 68 + fq]) = t1;
    *reinterpret_cast<float4*>(&v2L[s * 68 + fq]) = t2;
    *reinterpret_cast<float4*>(&v3L[s * 68 + fq]) = t3;
  }
  if (tid < 64) { uv[tid] = qe1g[(size_t)b * 64 + tid]; siL[tid] = 0.f; }
  if (tid >= 128 && tid < 224) {
    int t = tid - 128, st = t >> 5, k = t & 31;
    const float* qrg = (st == 0) ? qr1g : ((st == 1) ? qr2g : qr3g);
    qv[t] = qrg[(size_t)b * 32 + k];
  }
  __syncthreads();
  float* zL = MPL;               // rows [0..32)*68
  float* partL = MPL + 4096;     // [16][64]
  int k32 = tid & 31;
  for (int st = 0; st < 3; ++st) {
    const float* qs = qv + st * 32;
    if (act) {
      float u0 = uv[k32], u1 = uv[k32 + 32];
      float eu1 = e1L[s * 68 + k32] * u0 + e1L[s * 68 + k32 + 32] * u1;
      float eu2 = e2L[s * 68 + k32] * u0 + e2L[s * 68 + k32 + 32] * u1;
      float rq1 = r1L[s * 36 + k32] * qs[k32];
      float rq2 = r2L[s * 36 + k32] * qs[k32];
      float rq3 = r3L[s * 36 + k32] * qs[k32];
      #pragma unroll
      for (int d = 16; d > 0; d >>= 1) {
        eu1 += __shfl_down(eu1, d, 32); eu2 += __shfl_down(eu2, d, 32);
        rq1 += __shfl_down(rq1, d, 32); rq2 += __shfl_down(rq2, d, 32); rq3 += __shfl_down(rq3, d, 32);
      }
      if (k32 == 0) { alf[s] = eu1 * rq1; alf[32 + s] = eu1 * rq2; alf[64 + s] = eu2 * rq3; }
    }
    float z0 = 0.f, z1 = 0.f;
    {
      const float2* fb = reinterpret_cast<const float2*>(fwm + s * 64 + k32 * 2);
      for (int e = 0; e < 64; ++e) {
        float u = uv[e];
        float2 v = fb[(size_t)e * 1024];
        z0 += u * v.x; z1 += u * v.y;
      }
    }
    {
      float q = qs[s];
      zL[s * 68 + k32 * 2]     = q * z0;
      zL[s * 68 + k32 * 2 + 1] = q * z1;
    }
    __syncthreads();
    {
      int p = tid >> 6, f = tid & 63;
      float part;
      if (p < 15) {
        int sp = p * 2;
        part = alf[sp] * v1L[sp * 68 + f] + alf[32 + sp] * v2L[sp * 68 + f] + alf[64 + sp] * v3L[sp * 68 + f]
             + alf[sp + 1] * v1L[(sp + 1) * 68 + f] + alf[33 + sp] * v2L[(sp + 1) * 68 + f]
             + alf[65 + sp] * v3L[(sp + 1) * 68 + f];
      } else {
        float F = 0.f;
        #pragma unroll 8
        for (int rr = 0; rr < 32; ++rr) F += zL[rr * 68 + f];
        part = c0v * F;
      }
      partL[p * 64 + f] = part;
    }
    __syncthreads();
    if (tid < 64) {
      float raw = 0.f;
      #pragma unroll
      for (int p = 0; p < 16; ++p) raw += partL[p * 64 + tid];
      float mean = wreduce64(raw) * (1.f / 64.f);
      float d = raw - mean;
      float var = wreduce64(d * d) * (1.f / 63.f);
      float y = lng[st * 64 + tid] * d / (sqrtf(var) + 1e-6f) + lnb[st * 64 + tid];
      siL[tid] += y;
      uv[tid] = y;
    }
    __syncthreads();
  }
  if (tid < 9) {
    float o = 0.f;
    for (int ff = 0; ff < 64; ++ff) o += siL[ff] * Zg[ff * 9 + tid];
    out[(size_t)b * 9 + tid] = o;
  }
}

extern "C" void kernel_launch(void* const* d_in, const int* in_sizes, int n_in,
                              void* d_out, int out_size, void* d_ws, size_t ws_size,
                              hipStream_t stream) {
  const int*   story = (const int*)d_in[0];
  const int*   query = (const int*)d_in[1];
  const float* WE    = (const float*)d_in[2];
  const float* PE    = (const float*)d_in[3];
  const float* ueW1  = (const float*)d_in[4];
  const float* ueb1  = (const float*)d_in[5];
  const float* ueW2  = (const float*)d_in[6];
  const float* ueb2  = (const float*)d_in[7];
  const float* urW1  = (const float*)d_in[8];
  const float* urb1  = (const float*)d_in[9];
  const float* urW2  = (const float*)d_in[10];
  const float* urb2  = (const float*)d_in[11];
  const float* fwm   = (const float*)d_in[12];
  const float* ieW1  = (const float*)d_in[13];
  const float* ieb1  = (const float*)d_in[14];
  const float* ieW2  = (const float*)d_in[15];
  const float* ieb2  = (const float*)d_in[16];
  const float* irW1  = (const float*)d_in[17];
  const float* irb1  = (const float*)d_in[18];
  const float* irW2  = (const float*)d_in[19];
  const float* irb2  = (const float*)d_in[20];
  const float* lng   = (const float*)d_in[21];
  const float* lnb   = (const float*)d_in[22];
  const float* Z     = (const float*)d_in[23];
  float* W = (float*)d_ws;
  float* out = (float*)d_out;

  ushortT* sentB = (ushortT*)(W + OF_SENTB);
  ushortT* qembB = (ushortT*)(W + OF_QEMBB);
  ushortT* W1A   = (ushortT*)(W + OF_W1A);
  ushortT* W2TE  = (ushortT*)(W + OF_W2TE);
  ushortT* W2TR  = (ushortT*)(W + OF_W2TR);
  ushortT* fwmBT = (ushortT*)(W + OF_FWMB);

  prep_k<<<4232, 256, 0, stream>>>(story, query, WE, PE,
      ueW1, urW1, ieW1, irW1, ueW2, urW2, ieW2, irW2, fwm,
      sentB, qembB, W1A, W2TE, W2TR, fwmBT, W + OF_FN2);

  mlpm_k<<<dim3(240, 9), 256, 0, stream>>>(sentB, qembB, W1A,
      ueb1, urb1, ieb1, irb1, W2TE, W2TR, ueb2, urb2, ieb2, irb2,
      W + OF_E1, W + OF_R1, W + OF_QE1, W + OF_QR1);

  pstage_k<<<480, 256, 0, stream>>>(fwmBT, W + OF_E1, W + OF_E1 + 491520,
      W + OF_R1, W + OF_R1 + 245760, W + OF_R1 + 2 * 245760, W + OF_PP);

  scan_k<<<NB, 1024, 0, stream>>>(W + OF_PP, W + OF_E1, W + OF_E1 + 491520,
      W + OF_R1, W + OF_R1 + 245760, W + OF_R1 + 2 * 245760,
      W + OF_QE1, W + OF_QR1, W + OF_QR1 + 8192, W + OF_QR1 + 16384, W + OF_FN2, fwm, lng, lnb, Z, out);
}

// Round 11
// 167.844 us; speedup vs baseline: 4.4398x; 1.1387x over previous
//
#include <hip/hip_runtime.h>
#include <hip/hip_bf16.h>

// Sizes
#define NB 256
#define NS 30
#define NW 10
#define SYM 128
#define HID 512
#define ENT 64
#define ROLE 32

typedef unsigned short ushortT;
typedef __attribute__((ext_vector_type(8))) short short8v;   // 8 bf16
typedef __attribute__((ext_vector_type(4))) float f32x4;

// Workspace offsets (floats; bf16 arrays use 2 elems per float slot)
static const size_t OF_SENTB = 0;         // 7680*128 bf16 -> 491520 fl
static const size_t OF_QEMBB = 491520;    // 256*128 bf16 -> 16384 fl
static const size_t OF_W1A   = 507904;    // 9*512*128 bf16 -> 294912 fl
static const size_t OF_W2TE  = 802816;    // 3*64*512 bf16 -> 49152 fl
static const size_t OF_W2TR  = 851968;    // 6*32*512 bf16 -> 49152 fl
static const size_t OF_FWMB  = 901120;    // 64*2048 bf16 -> 65536 fl  (fwm^T [f][e*32+r])
static const size_t OF_E1    = 966656;    // 7680*64 x2 (stride 491520)
static const size_t OF_R1    = 1949696;   // 7680*32 x3 (stride 245760)
static const size_t OF_QE1   = 2686976;   // 256*64
static const size_t OF_QR1   = 2703360;   // 256*32 x3 (stride 8192)
static const size_t OF_PP    = 2727936;   // 3 * 7680*64 = 1,474,560
static const size_t OF_FN2   = 4202496;   // 8 partials
static const size_t OF_G     = 4202624;   // 3*256*64*64 = 3,145,728

__device__ __forceinline__ ushortT f2bf(float x) {
  unsigned u = __float_as_uint(x);
  unsigned r = (u + 0x7fffu + ((u >> 16) & 1u)) >> 16;
  return (ushortT)r;
}
__device__ __forceinline__ float dot4(const float4& a, const float4& b) {
  return a.x * b.x + a.y * b.y + a.z * b.z + a.w * b.w;
}
__device__ __forceinline__ float wreduce64(float v) {
  #pragma unroll
  for (int o = 32; o > 0; o >>= 1) v += __shfl_xor(v, o);
  return v;
}

// ---------------- unified prep: embed + all transposes/converts + fnorm partials ----------------
__global__ __launch_bounds__(256) void prep_k(
    const int* __restrict__ story, const int* __restrict__ query,
    const float* __restrict__ WE, const float* __restrict__ PE,
    const float* __restrict__ ueW1, const float* __restrict__ urW1,
    const float* __restrict__ ieW1, const float* __restrict__ irW1,
    const float* __restrict__ ueW2, const float* __restrict__ urW2,
    const float* __restrict__ ieW2, const float* __restrict__ irW2,
    const float* __restrict__ fwm,
    ushortT* __restrict__ sentb, ushortT* __restrict__ qembb,
    ushortT* __restrict__ W1A, ushortT* __restrict__ W2TE,
    ushortT* __restrict__ W2TR, ushortT* __restrict__ fwmBT,
    float* __restrict__ fn2) {
  __shared__ float tl[64 * 65];
  __shared__ float red[4];
  int bx = blockIdx.x, tid = threadIdx.x;
  if (bx < 3968) {
    int row = bx * 2 + (tid >> 7);
    int e = tid & 127;
    const int* idx; ushortT* dst;
    if (row < 7680) { idx = story + (size_t)row * NW; dst = sentb + (size_t)row * SYM; }
    else            { idx = query + (size_t)(row - 7680) * NW; dst = qembb + (size_t)(row - 7680) * SYM; }
    float acc = 0.f;
    #pragma unroll
    for (int w = 0; w < NW; ++w) acc += WE[idx[w] * SYM + e] * PE[w * SYM + e];
    dst[e] = f2bf(acc);
    return;
  }
  bx -= 3968;
  const float* src; ushortT* dst; int R, C, tr0, tc0;
  if (bx < 144) {
    int h = bx >> 4, t = bx & 15;
    src = (h < 2) ? ueW1 + (size_t)h * 65536 : (h < 5) ? urW1 + (size_t)(h - 2) * 65536
        : (h == 5) ? ieW1 : irW1 + (size_t)(h - 6) * 65536;
    dst = W1A + (size_t)h * 65536;
    R = 128; C = 512; tr0 = (t >> 3) * 64; tc0 = (t & 7) * 64;
  } else if (bx < 168) {
    int h = (bx - 144) >> 3, t = (bx - 144) & 7;
    src = (h < 2) ? ueW2 + (size_t)h * 32768 : ieW2;
    dst = W2TE + (size_t)h * 32768;
    R = 512; C = 64; tr0 = t * 64; tc0 = 0;
  } else if (bx < 216) {
    int h = (bx - 168) >> 3, t = (bx - 168) & 7;
    src = (h < 3) ? urW2 + (size_t)h * 16384 : irW2 + (size_t)(h - 3) * 16384;
    dst = W2TR + (size_t)h * 16384;
    R = 512; C = 32; tr0 = t * 64; tc0 = 0;
  } else if (bx < 248) {
    int t = bx - 216;
    src = fwm; dst = fwmBT; R = 2048; C = 64; tr0 = t * 64; tc0 = 0;
  } else {
    int blk = bx - 248;
    const float4* f4 = reinterpret_cast<const float4*>(fwm) + blk * 4096;
    float a = 0.f;
    for (int i = tid; i < 4096; i += 256) {
      float4 v = f4[i];
      a += v.x*v.x + v.y*v.y + v.z*v.z + v.w*v.w;
    }
    a = wreduce64(a);
    if ((tid & 63) == 0) red[tid >> 6] = a;
    __syncthreads();
    if (tid == 0) fn2[blk] = red[0] + red[1] + red[2] + red[3];
    return;
  }
  int TC = (C < 64) ? C : 64;
  int n = 64 * TC;
  for (int i = tid; i < n; i += 256) {
    int r = i / TC, c = i % TC;
    tl[r * 65 + c] = src[(size_t)(tr0 + r) * C + tc0 + c];
  }
  __syncthreads();
  for (int i = tid; i < n; i += 256) {
    int c = i >> 6, r = i & 63;
    dst[(size_t)(tc0 + c) * R + tr0 + r] = f2bf(tl[r * 65 + c]);
  }
}

// ---------------- MFMA fused 2-layer MLP (story y=0..4; query y=5..8 on x<8) ----------------
__global__ __launch_bounds__(256) void mlpm_k(
    const ushortT* __restrict__ sentB, const ushortT* __restrict__ qembB,
    const ushortT* __restrict__ W1A,
    const float* __restrict__ ueb1, const float* __restrict__ urb1,
    const float* __restrict__ ieb1, const float* __restrict__ irb1,
    const ushortT* __restrict__ W2TE, const ushortT* __restrict__ W2TR,
    const float* __restrict__ ueb2, const float* __restrict__ urb2,
    const float* __restrict__ ieb2, const float* __restrict__ irb2,
    float* __restrict__ E1, float* __restrict__ R1,
    float* __restrict__ QE1, float* __restrict__ QR1) {
  __shared__ __align__(16) ushortT Hl[32 * 520];
  int y = blockIdx.y;
  bool isQ = y >= 5;
  if (isQ && blockIdx.x >= 8) return;
  int r0 = blockIdx.x * 32, tid = threadIdx.x;
  int wave = tid >> 6, lane = tid & 63;
  int lrow = lane & 15;
  int kgrp = lane >> 4;
  const ushortT* Xb = isQ ? qembB : sentB;
  const ushortT* W1h = W1A + (size_t)y * 65536;
  const float* b1 = (y < 2) ? ueb1 + y * 512 : (y < 5) ? urb1 + (y - 2) * 512
                  : (y == 5) ? ieb1 : irb1 + (y - 6) * 512;
  bool isE = (y < 2) || (y == 5);

  int lrw = (wave & 1) * 16;
  int cw  = (wave >> 1) * 256;

  short8v afr[4];
  const ushortT* arow = Xb + (size_t)(r0 + lrw + lrow) * 128 + kgrp * 8;
  #pragma unroll
  for (int kt = 0; kt < 4; ++kt)
    afr[kt] = *reinterpret_cast<const short8v*>(arow + kt * 32);

  for (int ct = 0; ct < 16; ++ct) {
    int c0 = cw + ct * 16;
    f32x4 acc = {0.f, 0.f, 0.f, 0.f};
    const ushortT* bcol = W1h + (size_t)(c0 + lrow) * 128 + kgrp * 8;
    #pragma unroll
    for (int kt = 0; kt < 4; ++kt) {
      short8v bfr = *reinterpret_cast<const short8v*>(bcol + kt * 32);
      acc = __builtin_amdgcn_mfma_f32_16x16x32_bf16(afr[kt], bfr, acc, 0, 0, 0);
    }
    int lcol = c0 + lrow;
    float bb = b1[lcol];
    #pragma unroll
    for (int i = 0; i < 4; ++i) {
      float hv = tanhf(acc[i] + bb);
      Hl[(lrw + kgrp * 4 + i) * 520 + lcol] = f2bf(hv);
    }
  }
  __syncthreads();

  if (isE) {
    int slot = (y == 5) ? 2 : y;
    const ushortT* W2h = W2TE + (size_t)slot * 32768;
    const float* b2 = (y == 5) ? ieb2 : ueb2 + y * 64;
    float* Out = (y == 5) ? QE1 : E1 + (size_t)y * 491520;
    int c0w = (wave >> 1) * 32;
    f32x4 acc[2] = {{0.f,0.f,0.f,0.f},{0.f,0.f,0.f,0.f}};
    for (int kt = 0; kt < 16; ++kt) {
      int kb = kt * 32 + kgrp * 8;
      short8v afr2 = *reinterpret_cast<const short8v*>(&Hl[(lrw + lrow) * 520 + kb]);
      #pragma unroll
      for (int t = 0; t < 2; ++t) {
        short8v bfr = *reinterpret_cast<const short8v*>(W2h + (size_t)(c0w + t * 16 + lrow) * 512 + kb);
        acc[t] = __builtin_amdgcn_mfma_f32_16x16x32_bf16(afr2, bfr, acc[t], 0, 0, 0);
      }
    }
    #pragma unroll
    for (int t = 0; t < 2; ++t) {
      int col = c0w + t * 16 + lrow;
      float bb = b2[col];
      #pragma unroll
      for (int i = 0; i < 4; ++i) {
        int grow = r0 + lrw + kgrp * 4 + i;
        Out[(size_t)grow * 64 + col] = tanhf(acc[t][i] + bb);
      }
    }
  } else {
    int slot = (y < 5) ? (y - 2) : (3 + y - 6);
    const ushortT* W2h = W2TR + (size_t)slot * 16384;
    const float* b2 = (y < 5) ? urb2 + (y - 2) * 32 : irb2 + (y - 6) * 32;
    float* Out = (y < 5) ? R1 + (size_t)(y - 2) * 245760 : QR1 + (size_t)(y - 6) * 8192;
    int c0w = (wave >> 1) * 16;
    f32x4 acc = {0.f, 0.f, 0.f, 0.f};
    for (int kt = 0; kt < 16; ++kt) {
      int kb = kt * 32 + kgrp * 8;
      short8v afr2 = *reinterpret_cast<const short8v*>(&Hl[(lrw + lrow) * 520 + kb]);
      short8v bfr = *reinterpret_cast<const short8v*>(W2h + (size_t)(c0w + lrow) * 512 + kb);
      acc = __builtin_amdgcn_mfma_f32_16x16x32_bf16(afr2, bfr, acc, 0, 0, 0);
    }
    int col = c0w + lrow;
    float bb = b2[col];
    #pragma unroll
    for (int i = 0; i < 4; ++i) {
      int grow = r0 + lrw + kgrp * 4 + i;
      Out[(size_t)grow * 32 + col] = tanhf(acc[i] + bb);
    }
  }
}

// ---------------- MFMA P-stage (bx<480) + G-stage (bx>=480: G_k[b][e][f] = sum_r qr_k[r] fwm[e,r,f]) ----------------
__global__ __launch_bounds__(256) void pstage_k(const ushortT* __restrict__ fwmBT,
    const float* __restrict__ e1g, const float* __restrict__ e2g,
    const float* __restrict__ r1g, const float* __restrict__ r2g, const float* __restrict__ r3g,
    const float* __restrict__ qr1g, const float* __restrict__ qr2g, const float* __restrict__ qr3g,
    float* __restrict__ Pp, float* __restrict__ Gg) {
  __shared__ __align__(16) float e1t[16 * 68], e2t[16 * 68];
  int bx = blockIdx.x, tid = threadIdx.x;
  int wave = tid >> 6, lane = tid & 63;
  int c = lane & 15, kg = lane >> 4;
  int f0 = wave * 16;
  const f32x4 zero = {0,0,0,0};

  if (bx >= 480) {   // ---- G blocks: one per batch ----
    int b = bx - 480;
    short8v qa = {0,0,0,0,0,0,0,0};
    if (c < 3) {
      const float* qr = ((c == 0) ? qr1g : (c == 1) ? qr2g : qr3g) + (size_t)b * 32 + kg * 8;
      ushortT* p = (ushortT*)&qa;
      #pragma unroll
      for (int j = 0; j < 8; ++j) p[j] = f2bf(qr[j]);
    }
    const ushortT* bbase = fwmBT + (size_t)(f0 + c) * 2048 + kg * 8;
    float* g0 = Gg + (size_t)b * 4096 + f0 + c;
    for (int e = 0; e < 64; ++e) {
      short8v B = *reinterpret_cast<const short8v*>(bbase + (size_t)e * 32);
      f32x4 T = __builtin_amdgcn_mfma_f32_16x16x32_bf16(qa, B, zero, 0, 0, 0);
      if (kg == 0) {
        g0[e * 64]           = T[0];
        g0[1048576 + e * 64] = T[1];
        g0[2097152 + e * 64] = T[2];
      }
    }
    return;
  }

  int rb = bx;
  {
    int row = tid >> 4, c4 = tid & 15;
    float4 v1 = *reinterpret_cast<const float4*>(e1g + ((size_t)rb * 16 + row) * 64 + c4 * 4);
    float4 v2 = *reinterpret_cast<const float4*>(e2g + ((size_t)rb * 16 + row) * 64 + c4 * 4);
    *reinterpret_cast<float4*>(&e1t[row * 68 + c4 * 4]) = v1;
    *reinterpret_cast<float4*>(&e2t[row * 68 + c4 * 4]) = v2;
  }
  size_t rbase = ((size_t)rb * 16 + c) * 32 + kg * 8;
  short8v rA, rB, rC;
  {
    float4 x0 = *reinterpret_cast<const float4*>(r1g + rbase);
    float4 x1 = *reinterpret_cast<const float4*>(r1g + rbase + 4);
    ushortT* p = (ushortT*)&rA;
    p[0]=f2bf(x0.x); p[1]=f2bf(x0.y); p[2]=f2bf(x0.z); p[3]=f2bf(x0.w);
    p[4]=f2bf(x1.x); p[5]=f2bf(x1.y); p[6]=f2bf(x1.z); p[7]=f2bf(x1.w);
    x0 = *reinterpret_cast<const float4*>(r2g + rbase);
    x1 = *reinterpret_cast<const float4*>(r2g + rbase + 4);
    p = (ushortT*)&rB;
    p[0]=f2bf(x0.x); p[1]=f2bf(x0.y); p[2]=f2bf(x0.z); p[3]=f2bf(x0.w);
    p[4]=f2bf(x1.x); p[5]=f2bf(x1.y); p[6]=f2bf(x1.z); p[7]=f2bf(x1.w);
    x0 = *reinterpret_cast<const float4*>(r3g + rbase);
    x1 = *reinterpret_cast<const float4*>(r3g + rbase + 4);
    p = (ushortT*)&rC;
    p[0]=f2bf(x0.x); p[1]=f2bf(x0.y); p[2]=f2bf(x0.z); p[3]=f2bf(x0.w);
    p[4]=f2bf(x1.x); p[5]=f2bf(x1.y); p[6]=f2bf(x1.z); p[7]=f2bf(x1.w);
  }
  __syncthreads();
  const ushortT* bbase = fwmBT + (size_t)(f0 + c) * 2048 + kg * 8;
  f32x4 P1 = {0,0,0,0}, P2 = {0,0,0,0}, P3 = {0,0,0,0};
  int r0 = kg * 4;
  for (int e4 = 0; e4 < 16; ++e4) {
    float4 ea[4], eb[4];
    #pragma unroll
    for (int i = 0; i < 4; ++i) {
      ea[i] = *reinterpret_cast<const float4*>(&e1t[(r0 + i) * 68 + e4 * 4]);
      eb[i] = *reinterpret_cast<const float4*>(&e2t[(r0 + i) * 68 + e4 * 4]);
    }
    #pragma unroll
    for (int sub = 0; sub < 4; ++sub) {
      int e = e4 * 4 + sub;
      short8v B = *reinterpret_cast<const short8v*>(bbase + (size_t)e * 32);
      f32x4 T1 = __builtin_amdgcn_mfma_f32_16x16x32_bf16(rA, B, zero, 0, 0, 0);
      f32x4 T2 = __builtin_amdgcn_mfma_f32_16x16x32_bf16(rB, B, zero, 0, 0, 0);
      f32x4 T3 = __builtin_amdgcn_mfma_f32_16x16x32_bf16(rC, B, zero, 0, 0, 0);
      #pragma unroll
      for (int i = 0; i < 4; ++i) {
        float e1v = reinterpret_cast<const float*>(&ea[i])[sub];
        float e2v = reinterpret_cast<const float*>(&eb[i])[sub];
        P1[i] += e1v * T1[i];
        P2[i] += e1v * T2[i];
        P3[i] += e2v * T3[i];
      }
    }
  }
  #pragma unroll
  for (int i = 0; i < 4; ++i) {
    size_t row = (size_t)rb * 16 + kg * 4 + i;
    Pp[row * 64 + f0 + c]               = P1[i];
    Pp[491520 + row * 64 + f0 + c]      = P2[i];
    Pp[2 * 491520 + row * 64 + f0 + c]  = P3[i];
  }
}

// ---------------- scan: gram + RQ + layers + inference (F from precomputed G) ----------------
__global__ __launch_bounds__(1024) void scan_k(
    const float* __restrict__ Pp, const float* __restrict__ Gg,
    const float* __restrict__ e1g, const float* __restrict__ e2g,
    const float* __restrict__ r1g, const float* __restrict__ r2g, const float* __restrict__ r3g,
    const float* __restrict__ qe1g, const float* __restrict__ qr1g, const float* __restrict__ qr2g,
    const float* __restrict__ qr3g, const float* __restrict__ fn2p,
    const float* __restrict__ lng, const float* __restrict__ lnb, const float* __restrict__ Zg,
    float* __restrict__ out) {
  __shared__ __align__(16) float MPL[10800];            // gram M; partL overlays +4096
  __shared__ __align__(16) float e1L[2040], e2L[2040];  // [30][68]
  __shared__ __align__(16) float v1L[2040], v2L[2040], v3L[2040];
  __shared__ __align__(16) float r1L[1080], r2L[1080], r3L[1080];  // [30][36]
  __shared__ float uv[64], qv[96], alf[96], siL[64], rqL[272];
  __shared__ float redL[16];
  int b = blockIdx.x, tid = threadIdx.x;
  int s = tid >> 5, g = (tid >> 4) & 1, fo = tid & 15;
  int fq = fo * 4;
  bool act = s < 30;

  float H1[4], H2[4], H3[4], a1[4], a2[4], a3[4];
  #pragma unroll
  for (int j = 0; j < 4; ++j) { a1[j] = 0; a2[j] = 0; a3[j] = 0; }
  if (act) {
    size_t base = (size_t)b * 1920 + s * 64 + fq;
    float4 h1 = *reinterpret_cast<const float4*>(Pp + base);
    float4 h2 = *reinterpret_cast<const float4*>(Pp + 491520 + base);
    float4 h3 = *reinterpret_cast<const float4*>(Pp + 983040 + base);
    H1[0]=h1.x; H1[1]=h1.y; H1[2]=h1.z; H1[3]=h1.w;
    H2[0]=h2.x; H2[1]=h2.y; H2[2]=h2.z; H2[3]=h2.w;
    H3[0]=h3.x; H3[1]=h3.y; H3[2]=h3.z; H3[3]=h3.w;
  } else {
    #pragma unroll
    for (int j = 0; j < 4; ++j) { H1[j]=0; H2[j]=0; H3[j]=0; }
  }
  for (int i = tid; i < 1680; i += 1024) {
    if (i < 480) {
      int ss = i >> 4, c4 = i & 15;
      *reinterpret_cast<float4*>(&e1L[ss * 68 + c4 * 4]) =
          *reinterpret_cast<const float4*>(e1g + (size_t)b * 1920 + i * 4);
    } else if (i < 960) {
      int j = i - 480;
      int ss = j >> 4, c4 = j & 15;
      *reinterpret_cast<float4*>(&e2L[ss * 68 + c4 * 4]) =
          *reinterpret_cast<const float4*>(e2g + (size_t)b * 1920 + j * 4);
    } else {
      int j = i - 960;
      int which = j / 240, jj = j - which * 240;
      int ss = jj >> 3, c4 = jj & 7;
      float* dstL = (which == 0) ? r1L : (which == 1) ? r2L : r3L;
      const float* srcG = (which == 0) ? r1g : (which == 1) ? r2g : r3g;
      *reinterpret_cast<float4*>(&dstL[ss * 36 + c4 * 4]) =
          *reinterpret_cast<const float4*>(srcG + (size_t)b * 960 + jj * 4);
    }
  }
  if (tid >= 128 && tid < 224) {
    int t = tid - 128, st = t >> 5, k = t & 31;
    const float* qrg = (st == 0) ? qr1g : ((st == 1) ? qr2g : qr3g);
    qv[t] = qrg[(size_t)b * 32 + k];
  }
  __syncthreads();

  // ---- fused gram -> packed MP; threads >=900 compute RQ[st][k][s] ----
  if (tid < 900) {
    int si = tid / 30, sj = tid - si * 30;
    float g11 = 0, g12 = 0, g21 = 0, g22 = 0;
    {
      const float4* A1 = reinterpret_cast<const float4*>(&e1L[si * 68]);
      const float4* A2 = reinterpret_cast<const float4*>(&e2L[si * 68]);
      const float4* C1 = reinterpret_cast<const float4*>(&e1L[sj * 68]);
      const float4* C2 = reinterpret_cast<const float4*>(&e2L[sj * 68]);
      #pragma unroll 4
      for (int i = 0; i < 16; ++i) {
        float4 a1v = A1[i], a2v = A2[i], c1v = C1[i], c2v = C2[i];
        g11 += dot4(a1v, c1v); g12 += dot4(a1v, c2v);
        g21 += dot4(a2v, c1v); g22 += dot4(a2v, c2v);
      }
    }
    float R11=0,R12=0,R13=0,R21=0,R22=0,R23=0,R31=0,R32=0,R33=0;
    {
      const float4* X1 = reinterpret_cast<const float4*>(&r1L[si * 36]);
      const float4* X2 = reinterpret_cast<const float4*>(&r2L[si * 36]);
      const float4* X3 = reinterpret_cast<const float4*>(&r3L[si * 36]);
      const float4* Y1 = reinterpret_cast<const float4*>(&r1L[sj * 36]);
      const float4* Y2 = reinterpret_cast<const float4*>(&r2L[sj * 36]);
      const float4* Y3 = reinterpret_cast<const float4*>(&r3L[sj * 36]);
      #pragma unroll 4
      for (int i = 0; i < 8; ++i) {
        float4 x1 = X1[i], x2 = X2[i], x3 = X3[i];
        float4 y1 = Y1[i], y2 = Y2[i], y3 = Y3[i];
        R11 += dot4(x1, y1); R12 += dot4(x1, y2); R13 += dot4(x1, y3);
        R21 += dot4(x2, y1); R22 += dot4(x2, y2); R23 += dot4(x2, y3);
        R31 += dot4(x3, y1); R32 += dot4(x3, y2); R33 += dot4(x3, y3);
      }
    }
    float4* MPv = reinterpret_cast<float4*>(MPL);
    float4 p1; p1.x = g11 * R11; p1.y = g11 * R21; p1.z = g21 * R31; p1.w = 0.f;
    float4 p2; p2.x = g11 * R12; p2.y = g11 * R22; p2.z = g21 * R32; p2.w = 0.f;
    float4 p3; p3.x = g12 * R13; p3.y = g12 * R23; p3.z = g22 * R33; p3.w = 0.f;
    MPv[tid] = p1;
    MPv[900 + tid] = p2;
    MPv[1800 + tid] = p3;
  } else {
    #pragma unroll
    for (int ch = 0; ch < 3; ++ch) {
      int t = (tid - 900) + ch * 124;
      if (t < 270) {
        int st = t / 90, rem = t - st * 90;
        int k = rem / 30, s2 = rem - k * 30;
        const float* rL = (k == 0) ? r1L : (k == 1) ? r2L : r3L;
        const float* qp = qv + st * 32;
        float a = 0.f;
        #pragma unroll 8
        for (int r = 0; r < 32; ++r) a += rL[s2 * 36 + r] * qp[r];
        rqL[st * 90 + k * 30 + s2] = a;
      }
    }
  }
  __syncthreads();

  float n2 = 0.f;
  #pragma unroll
  for (int i = 0; i < 8; ++i) n2 += fn2p[i];
  float c0v = 1.f;

  auto prop = [&](const float* vsrc, int mbase) {
    float d1[4] = {0,0,0,0}, d2[4] = {0,0,0,0}, d3[4] = {0,0,0,0};
    if (act) {
      const float4* mrow = reinterpret_cast<const float4*>(MPL) + mbase + s * 30 + g * 15;
      const float* vb = vsrc + g * 15 * 68 + fq;
      #pragma unroll 5
      for (int i = 0; i < 15; ++i) {
        float4 m = mrow[i];
        float4 vv = *reinterpret_cast<const float4*>(vb + i * 68);
        d1[0]+=m.x*vv.x; d1[1]+=m.x*vv.y; d1[2]+=m.x*vv.z; d1[3]+=m.x*vv.w;
        d2[0]+=m.y*vv.x; d2[1]+=m.y*vv.y; d2[2]+=m.y*vv.z; d2[3]+=m.y*vv.w;
        d3[0]+=m.z*vv.x; d3[1]+=m.z*vv.y; d3[2]+=m.z*vv.z; d3[3]+=m.z*vv.w;
      }
    }
    #pragma unroll
    for (int j = 0; j < 4; ++j) {
      H1[j] += d1[j] + __shfl_xor(d1[j], 16);
      H2[j] += d2[j] + __shfl_xor(d2[j], 16);
      H3[j] += d3[j] + __shfl_xor(d3[j], 16);
    }
  };

  for (int layer = 0; layer < 3; ++layer) {
    float w[4], H2s[4], H3s[4], v1r[4], v2r[4], v3r[4];
    if (act) {
      float4 e2v = *reinterpret_cast<const float4*>(&e2L[s * 68 + fq]);
      w[0]=H1[0]; w[1]=H1[1]; w[2]=H1[2]; w[3]=H1[3];
      #pragma unroll
      for (int j = 0; j < 4; ++j) { H2s[j] = H2[j]; H3s[j] = H3[j]; }
      v1r[0] = e2v.x - H1[0]; v1r[1] = e2v.y - H1[1]; v1r[2] = e2v.z - H1[2]; v1r[3] = e2v.w - H1[3];
      if (g == 0) {
        float4 t; t.x=v1r[0]; t.y=v1r[1]; t.z=v1r[2]; t.w=v1r[3];
        *reinterpret_cast<float4*>(&v1L[s * 68 + fq]) = t;
      }
    }
    __syncthreads();
    prop(v1L, 0);
    if (act) {
      #pragma unroll
      for (int j = 0; j < 4; ++j) v2r[j] = w[j] - H2[j];
      if (g == 0) {
        float4 t; t.x=v2r[0]; t.y=v2r[1]; t.z=v2r[2]; t.w=v2r[3];
        *reinterpret_cast<float4*>(&v2L[s * 68 + fq]) = t;
      }
    }
    __syncthreads();
    prop(v2L, 900);
    if (act) {
      float4 e1v = *reinterpret_cast<const float4*>(&e1L[s * 68 + fq]);
      v3r[0] = e1v.x - H3[0]; v3r[1] = e1v.y - H3[1]; v3r[2] = e1v.z - H3[2]; v3r[3] = e1v.w - H3[3];
      if (g == 0) {
        float4 t; t.x=v3r[0]; t.y=v3r[1]; t.z=v3r[2]; t.w=v3r[3];
        *reinterpret_cast<float4*>(&v3L[s * 68 + fq]) = t;
      }
    }
    __syncthreads();
    prop(v3L, 1800);
    float local = 0.f;
    if (act) {
      #pragma unroll
      for (int j = 0; j < 4; ++j) { a1[j] += v1r[j]; a2[j] += v2r[j]; a3[j] += v3r[j]; }
      if (g == 0) {
        #pragma unroll
        for (int j = 0; j < 4; ++j)
          local += v1r[j] * (w[j] + H1[j]) + v2r[j] * (H2s[j] + H2[j]) + v3r[j] * (H3s[j] + H3[j]);
      }
    }
    local = wreduce64(local);
    if ((tid & 63) == 0) redL[tid >> 6] = local;
    __syncthreads();
    // all threads compute identical inv (same summation order -> deterministic)
    float tot = n2;
    #pragma unroll
    for (int i = 0; i < 16; ++i) tot += redL[i];
    float fn = fmaxf(sqrtf(tot), 1.f);
    float inv = 1.f / fn;
    n2 = tot * inv * inv;
    c0v *= inv;
    if (act) {
      #pragma unroll
      for (int j = 0; j < 4; ++j) { H1[j]*=inv; H2[j]*=inv; H3[j]*=inv; a1[j]*=inv; a2[j]*=inv; a3[j]*=inv; }
    }
  }

  // ---- inference ----
  if (act && g == 0) {
    float4 t1; t1.x=a1[0]; t1.y=a1[1]; t1.z=a1[2]; t1.w=a1[3];
    float4 t2; t2.x=a2[0]; t2.y=a2[1]; t2.z=a2[2]; t2.w=a2[3];
    float4 t3; t3.x=a3[0]; t3.y=a3[1]; t3.z=a3[2]; t3.w=a3[3];
    *reinterpret_cast<float4*>(&v1L[s * 68 + fq]) = t1;
    *reinterpret_cast<float4*>(&v2L[s * 68 + fq]) = t2;
    *reinterpret_cast<float4*>(&v3L[s * 68 + fq]) = t3;
  }
  if (tid < 64) { uv[tid] = qe1g[(size_t)b * 64 + tid]; siL[tid] = 0.f; }
  __syncthreads();
  float* partL = MPL + 4096;     // [16][64]
  int k32 = tid & 31;
  for (int st = 0; st < 3; ++st) {
    if (act) {
      float u0 = uv[k32], u1 = uv[k32 + 32];
      float eu1 = e1L[s * 68 + k32] * u0 + e1L[s * 68 + k32 + 32] * u1;
      float eu2 = e2L[s * 68 + k32] * u0 + e2L[s * 68 + k32 + 32] * u1;
      #pragma unroll
      for (int d = 16; d > 0; d >>= 1) {
        eu1 += __shfl_down(eu1, d, 32); eu2 += __shfl_down(eu2, d, 32);
      }
      if (k32 == 0) {
        alf[s]      = eu1 * rqL[st * 90 + s];
        alf[32 + s] = eu1 * rqL[st * 90 + 30 + s];
        alf[64 + s] = eu2 * rqL[st * 90 + 60 + s];
      }
    }
    __syncthreads();
    {
      int p = tid >> 6, f = tid & 63;
      float part = 0.f;
      if (p < 12) {
        int start = (p < 6) ? p * 3 : 18 + (p - 6) * 2;
        int cnt = (p < 6) ? 3 : 2;
        for (int q = 0; q < cnt; ++q) {
          int sp = start + q;
          part += alf[sp] * v1L[sp * 68 + f] + alf[32 + sp] * v2L[sp * 68 + f]
                + alf[64 + sp] * v3L[sp * 68 + f];
        }
      } else {
        int e0 = (p - 12) * 16;
        const float* Gp = Gg + (size_t)st * 1048576 + (size_t)b * 4096 + (size_t)e0 * 64 + f;
        float F = 0.f;
        #pragma unroll 4
        for (int e = 0; e < 16; ++e) F += uv[e0 + e] * Gp[e * 64];
        part = c0v * F;
      }
      partL[p * 64 + f] = part;
    }
    __syncthreads();
    if (tid < 64) {
      float raw = 0.f;
      #pragma unroll
      for (int p = 0; p < 16; ++p) raw += partL[p * 64 + tid];
      float mean = wreduce64(raw) * (1.f / 64.f);
      float d = raw - mean;
      float var = wreduce64(d * d) * (1.f / 63.f);
      float y = lng[st * 64 + tid] * d / (sqrtf(var) + 1e-6f) + lnb[st * 64 + tid];
      siL[tid] += y;
      uv[tid] = y;
    }
    __syncthreads();
  }
  if (tid < 9) {
    float o = 0.f;
    for (int ff = 0; ff < 64; ++ff) o += siL[ff] * Zg[ff * 9 + tid];
    out[(size_t)b * 9 + tid] = o;
  }
}

extern "C" void kernel_launch(void* const* d_in, const int* in_sizes, int n_in,
                              void* d_out, int out_size, void* d_ws, size_t ws_size,
                              hipStream_t stream) {
  const int*   story = (const int*)d_in[0];
  const int*   query = (const int*)d_in[1];
  const float* WE    = (const float*)d_in[2];
  const float* PE    = (const float*)d_in[3];
  const float* ueW1  = (const float*)d_in[4];
  const float* ueb1  = (const float*)d_in[5];
  const float* ueW2  = (const float*)d_in[6];
  const float* ueb2  = (const float*)d_in[7];
  const float* urW1  = (const float*)d_in[8];
  const float* urb1  = (const float*)d_in[9];
  const float* urW2  = (const float*)d_in[10];
  const float* urb2  = (const float*)d_in[11];
  const float* fwm   = (const float*)d_in[12];
  const float* ieW1  = (const float*)d_in[13];
  const float* ieb1  = (const float*)d_in[14];
  const float* ieW2  = (const float*)d_in[15];
  const float* ieb2  = (const float*)d_in[16];
  const float* irW1  = (const float*)d_in[17];
  const float* irb1  = (const float*)d_in[18];
  const float* irW2  = (const float*)d_in[19];
  const float* irb2  = (const float*)d_in[20];
  const float* lng   = (const float*)d_in[21];
  const float* lnb   = (const float*)d_in[22];
  const float* Z     = (const float*)d_in[23];
  float* W = (float*)d_ws;
  float* out = (float*)d_out;

  ushortT* sentB = (ushortT*)(W + OF_SENTB);
  ushortT* qembB = (ushortT*)(W + OF_QEMBB);
  ushortT* W1A   = (ushortT*)(W + OF_W1A);
  ushortT* W2TE  = (ushortT*)(W + OF_W2TE);
  ushortT* W2TR  = (ushortT*)(W + OF_W2TR);
  ushortT* fwmBT = (ushortT*)(W + OF_FWMB);

  prep_k<<<4232, 256, 0, stream>>>(story, query, WE, PE,
      ueW1, urW1, ieW1, irW1, ueW2, urW2, ieW2, irW2, fwm,
      sentB, qembB, W1A, W2TE, W2TR, fwmBT, W + OF_FN2);

  mlpm_k<<<dim3(240, 9), 256, 0, stream>>>(sentB, qembB, W1A,
      ueb1, urb1, ieb1, irb1, W2TE, W2TR, ueb2, urb2, ieb2, irb2,
      W + OF_E1, W + OF_R1, W + OF_QE1, W + OF_QR1);

  pstage_k<<<736, 256, 0, stream>>>(fwmBT, W + OF_E1, W + OF_E1 + 491520,
      W + OF_R1, W + OF_R1 + 245760, W + OF_R1 + 2 * 245760,
      W + OF_QR1, W + OF_QR1 + 8192, W + OF_QR1 + 16384,
      W + OF_PP, W + OF_G);

  scan_k<<<NB, 1024, 0, stream>>>(W + OF_PP, W + OF_G,
      W + OF_E1, W + OF_E1 + 491520,
      W + OF_R1, W + OF_R1 + 245760, W + OF_R1 + 2 * 245760,
      W + OF_QE1, W + OF_QR1, W + OF_QR1 + 8192, W + OF_QR1 + 16384,
      W + OF_FN2, lng, lnb, Z, out);
}

// Round 12
// 149.551 us; speedup vs baseline: 4.9829x; 1.1223x over previous
//
#include <hip/hip_runtime.h>
#include <hip/hip_bf16.h>

// Sizes
#define NB 256
#define NS 30
#define NW 10
#define SYM 128
#define HID 512
#define ENT 64
#define ROLE 32

typedef unsigned short ushortT;
typedef __attribute__((ext_vector_type(8))) short short8v;   // 8 bf16
typedef __attribute__((ext_vector_type(4))) float f32x4;

// Workspace offsets (floats; bf16 arrays use 2 elems per float slot)
static const size_t OF_SENTB = 0;         // 7680*128 bf16 -> 491520 fl
static const size_t OF_QEMBB = 491520;    // 256*128 bf16 -> 16384 fl
static const size_t OF_W1A   = 507904;    // 9*512*128 bf16 -> 294912 fl
static const size_t OF_W2TE  = 802816;    // 3*64*512 bf16 -> 49152 fl
static const size_t OF_W2TR  = 851968;    // 6*32*512 bf16 -> 49152 fl
static const size_t OF_FWMB  = 901120;    // 64*2048 bf16 -> 65536 fl  (fwm^T [f][e*32+r])
static const size_t OF_E1    = 966656;    // 7680*64 x2 (stride 491520)
static const size_t OF_R1    = 1949696;   // 7680*32 x3 (stride 245760)
static const size_t OF_QE1   = 2686976;   // 256*64
static const size_t OF_QR1   = 2703360;   // 256*32 x3 (stride 8192)
static const size_t OF_PP    = 2727936;   // 3 * 7680*64 = 1,474,560
static const size_t OF_FN2   = 4202496;   // 8 partials
static const size_t OF_G     = 4202624;   // 3*256*64*64 = 3,145,728

__device__ __forceinline__ ushortT f2bf(float x) {
  unsigned u = __float_as_uint(x);
  unsigned r = (u + 0x7fffu + ((u >> 16) & 1u)) >> 16;
  return (ushortT)r;
}
__device__ __forceinline__ float ftanh(float x) {
  // tanh(x) = 1 - 2/(exp(2x)+1); saturates correctly at +/-inf, no NaN.
  float t = __expf(2.f * x);
  return 1.f - 2.f * __builtin_amdgcn_rcpf(t + 1.f);
}
__device__ __forceinline__ float dot4(const float4& a, const float4& b) {
  return a.x * b.x + a.y * b.y + a.z * b.z + a.w * b.w;
}
__device__ __forceinline__ float wreduce64(float v) {
  #pragma unroll
  for (int o = 32; o > 0; o >>= 1) v += __shfl_xor(v, o);
  return v;
}

// ---------------- unified prep: embed + all transposes/converts + fnorm partials ----------------
__global__ __launch_bounds__(256) void prep_k(
    const int* __restrict__ story, const int* __restrict__ query,
    const float* __restrict__ WE, const float* __restrict__ PE,
    const float* __restrict__ ueW1, const float* __restrict__ urW1,
    const float* __restrict__ ieW1, const float* __restrict__ irW1,
    const float* __restrict__ ueW2, const float* __restrict__ urW2,
    const float* __restrict__ ieW2, const float* __restrict__ irW2,
    const float* __restrict__ fwm,
    ushortT* __restrict__ sentb, ushortT* __restrict__ qembb,
    ushortT* __restrict__ W1A, ushortT* __restrict__ W2TE,
    ushortT* __restrict__ W2TR, ushortT* __restrict__ fwmBT,
    float* __restrict__ fn2) {
  __shared__ float tl[64 * 65];
  __shared__ float red[4];
  int bx = blockIdx.x, tid = threadIdx.x;
  if (bx < 3968) {
    int row = bx * 2 + (tid >> 7);
    int e = tid & 127;
    const int* idx; ushortT* dst;
    if (row < 7680) { idx = story + (size_t)row * NW; dst = sentb + (size_t)row * SYM; }
    else            { idx = query + (size_t)(row - 7680) * NW; dst = qembb + (size_t)(row - 7680) * SYM; }
    float acc = 0.f;
    #pragma unroll
    for (int w = 0; w < NW; ++w) acc += WE[idx[w] * SYM + e] * PE[w * SYM + e];
    dst[e] = f2bf(acc);
    return;
  }
  bx -= 3968;
  const float* src; ushortT* dst; int R, C, tr0, tc0;
  if (bx < 144) {
    int h = bx >> 4, t = bx & 15;
    src = (h < 2) ? ueW1 + (size_t)h * 65536 : (h < 5) ? urW1 + (size_t)(h - 2) * 65536
        : (h == 5) ? ieW1 : irW1 + (size_t)(h - 6) * 65536;
    dst = W1A + (size_t)h * 65536;
    R = 128; C = 512; tr0 = (t >> 3) * 64; tc0 = (t & 7) * 64;
  } else if (bx < 168) {
    int h = (bx - 144) >> 3, t = (bx - 144) & 7;
    src = (h < 2) ? ueW2 + (size_t)h * 32768 : ieW2;
    dst = W2TE + (size_t)h * 32768;
    R = 512; C = 64; tr0 = t * 64; tc0 = 0;
  } else if (bx < 216) {
    int h = (bx - 168) >> 3, t = (bx - 168) & 7;
    src = (h < 3) ? urW2 + (size_t)h * 16384 : irW2 + (size_t)(h - 3) * 16384;
    dst = W2TR + (size_t)h * 16384;
    R = 512; C = 32; tr0 = t * 64; tc0 = 0;
  } else if (bx < 248) {
    int t = bx - 216;
    src = fwm; dst = fwmBT; R = 2048; C = 64; tr0 = t * 64; tc0 = 0;
  } else {
    int blk = bx - 248;
    const float4* f4 = reinterpret_cast<const float4*>(fwm) + blk * 4096;
    float a = 0.f;
    for (int i = tid; i < 4096; i += 256) {
      float4 v = f4[i];
      a += v.x*v.x + v.y*v.y + v.z*v.z + v.w*v.w;
    }
    a = wreduce64(a);
    if ((tid & 63) == 0) red[tid >> 6] = a;
    __syncthreads();
    if (tid == 0) fn2[blk] = red[0] + red[1] + red[2] + red[3];
    return;
  }
  int TC = (C < 64) ? C : 64;
  int n = 64 * TC;
  for (int i = tid; i < n; i += 256) {
    int r = i / TC, c = i % TC;
    tl[r * 65 + c] = src[(size_t)(tr0 + r) * C + tc0 + c];
  }
  __syncthreads();
  for (int i = tid; i < n; i += 256) {
    int c = i >> 6, r = i & 63;
    dst[(size_t)(tc0 + c) * R + tr0 + r] = f2bf(tl[r * 65 + c]);
  }
}

// ---------------- MFMA fused 2-layer MLP (story y=0..4; query y=5..8 on x<8) ----------------
__global__ __launch_bounds__(256, 4) void mlpm_k(
    const ushortT* __restrict__ sentB, const ushortT* __restrict__ qembB,
    const ushortT* __restrict__ W1A,
    const float* __restrict__ ueb1, const float* __restrict__ urb1,
    const float* __restrict__ ieb1, const float* __restrict__ irb1,
    const ushortT* __restrict__ W2TE, const ushortT* __restrict__ W2TR,
    const float* __restrict__ ueb2, const float* __restrict__ urb2,
    const float* __restrict__ ieb2, const float* __restrict__ irb2,
    float* __restrict__ E1, float* __restrict__ R1,
    float* __restrict__ QE1, float* __restrict__ QR1) {
  __shared__ __align__(16) ushortT Hl[32 * 520];
  int y = blockIdx.y;
  bool isQ = y >= 5;
  if (isQ && blockIdx.x >= 8) return;
  int r0 = blockIdx.x * 32, tid = threadIdx.x;
  int wave = tid >> 6, lane = tid & 63;
  int lrow = lane & 15;
  int kgrp = lane >> 4;
  const ushortT* Xb = isQ ? qembB : sentB;
  const ushortT* W1h = W1A + (size_t)y * 65536;
  const float* b1 = (y < 2) ? ueb1 + y * 512 : (y < 5) ? urb1 + (y - 2) * 512
                  : (y == 5) ? ieb1 : irb1 + (y - 6) * 512;
  bool isE = (y < 2) || (y == 5);

  int lrw = (wave & 1) * 16;
  int cw  = (wave >> 1) * 256;

  short8v afr[4];
  const ushortT* arow = Xb + (size_t)(r0 + lrw + lrow) * 128 + kgrp * 8;
  #pragma unroll
  for (int kt = 0; kt < 4; ++kt)
    afr[kt] = *reinterpret_cast<const short8v*>(arow + kt * 32);

  // GEMM1: fully unrolled, split-K accumulators for ILP
  #pragma unroll
  for (int ct = 0; ct < 16; ++ct) {
    int c0 = cw + ct * 16;
    const ushortT* bcol = W1h + (size_t)(c0 + lrow) * 128 + kgrp * 8;
    short8v bfr0 = *reinterpret_cast<const short8v*>(bcol);
    short8v bfr1 = *reinterpret_cast<const short8v*>(bcol + 32);
    short8v bfr2 = *reinterpret_cast<const short8v*>(bcol + 64);
    short8v bfr3 = *reinterpret_cast<const short8v*>(bcol + 96);
    f32x4 accA = {0.f, 0.f, 0.f, 0.f}, accB = {0.f, 0.f, 0.f, 0.f};
    accA = __builtin_amdgcn_mfma_f32_16x16x32_bf16(afr[0], bfr0, accA, 0, 0, 0);
    accB = __builtin_amdgcn_mfma_f32_16x16x32_bf16(afr[1], bfr1, accB, 0, 0, 0);
    accA = __builtin_amdgcn_mfma_f32_16x16x32_bf16(afr[2], bfr2, accA, 0, 0, 0);
    accB = __builtin_amdgcn_mfma_f32_16x16x32_bf16(afr[3], bfr3, accB, 0, 0, 0);
    int lcol = c0 + lrow;
    float bb = b1[lcol];
    #pragma unroll
    for (int i = 0; i < 4; ++i) {
      float hv = ftanh(accA[i] + accB[i] + bb);
      Hl[(lrw + kgrp * 4 + i) * 520 + lcol] = f2bf(hv);
    }
  }
  __syncthreads();

  if (isE) {
    int slot = (y == 5) ? 2 : y;
    const ushortT* W2h = W2TE + (size_t)slot * 32768;
    const float* b2 = (y == 5) ? ieb2 : ueb2 + y * 64;
    float* Out = (y == 5) ? QE1 : E1 + (size_t)y * 491520;
    int c0w = (wave >> 1) * 32;
    f32x4 accA[2] = {{0.f,0.f,0.f,0.f},{0.f,0.f,0.f,0.f}};
    f32x4 accB[2] = {{0.f,0.f,0.f,0.f},{0.f,0.f,0.f,0.f}};
    #pragma unroll
    for (int kt = 0; kt < 16; kt += 2) {
      int kb0 = kt * 32 + kgrp * 8;
      int kb1 = kb0 + 32;
      short8v a0 = *reinterpret_cast<const short8v*>(&Hl[(lrw + lrow) * 520 + kb0]);
      short8v a1 = *reinterpret_cast<const short8v*>(&Hl[(lrw + lrow) * 520 + kb1]);
      #pragma unroll
      for (int t = 0; t < 2; ++t) {
        const ushortT* wc = W2h + (size_t)(c0w + t * 16 + lrow) * 512;
        short8v b0 = *reinterpret_cast<const short8v*>(wc + kb0);
        short8v b1v = *reinterpret_cast<const short8v*>(wc + kb1);
        accA[t] = __builtin_amdgcn_mfma_f32_16x16x32_bf16(a0, b0, accA[t], 0, 0, 0);
        accB[t] = __builtin_amdgcn_mfma_f32_16x16x32_bf16(a1, b1v, accB[t], 0, 0, 0);
      }
    }
    #pragma unroll
    for (int t = 0; t < 2; ++t) {
      int col = c0w + t * 16 + lrow;
      float bb = b2[col];
      #pragma unroll
      for (int i = 0; i < 4; ++i) {
        int grow = r0 + lrw + kgrp * 4 + i;
        Out[(size_t)grow * 64 + col] = ftanh(accA[t][i] + accB[t][i] + bb);
      }
    }
  } else {
    int slot = (y < 5) ? (y - 2) : (3 + y - 6);
    const ushortT* W2h = W2TR + (size_t)slot * 16384;
    const float* b2 = (y < 5) ? urb2 + (y - 2) * 32 : irb2 + (y - 6) * 32;
    float* Out = (y < 5) ? R1 + (size_t)(y - 2) * 245760 : QR1 + (size_t)(y - 6) * 8192;
    int c0w = (wave >> 1) * 16;
    f32x4 accA = {0.f, 0.f, 0.f, 0.f}, accB = {0.f, 0.f, 0.f, 0.f};
    const ushortT* wc = W2h + (size_t)(c0w + lrow) * 512;
    #pragma unroll
    for (int kt = 0; kt < 16; kt += 2) {
      int kb0 = kt * 32 + kgrp * 8;
      int kb1 = kb0 + 32;
      short8v a0 = *reinterpret_cast<const short8v*>(&Hl[(lrw + lrow) * 520 + kb0]);
      short8v a1 = *reinterpret_cast<const short8v*>(&Hl[(lrw + lrow) * 520 + kb1]);
      short8v b0 = *reinterpret_cast<const short8v*>(wc + kb0);
      short8v b1v = *reinterpret_cast<const short8v*>(wc + kb1);
      accA = __builtin_amdgcn_mfma_f32_16x16x32_bf16(a0, b0, accA, 0, 0, 0);
      accB = __builtin_amdgcn_mfma_f32_16x16x32_bf16(a1, b1v, accB, 0, 0, 0);
    }
    int col = c0w + lrow;
    float bb = b2[col];
    #pragma unroll
    for (int i = 0; i < 4; ++i) {
      int grow = r0 + lrw + kgrp * 4 + i;
      Out[(size_t)grow * 32 + col] = ftanh(accA[i] + accB[i] + bb);
    }
  }
}

// ---------------- MFMA P-stage (bx<480) + G-stage (bx>=480) ----------------
__global__ __launch_bounds__(256) void pstage_k(const ushortT* __restrict__ fwmBT,
    const float* __restrict__ e1g, const float* __restrict__ e2g,
    const float* __restrict__ r1g, const float* __restrict__ r2g, const float* __restrict__ r3g,
    const float* __restrict__ qr1g, const float* __restrict__ qr2g, const float* __restrict__ qr3g,
    float* __restrict__ Pp, float* __restrict__ Gg) {
  __shared__ __align__(16) float e1t[16 * 68], e2t[16 * 68];
  int bx = blockIdx.x, tid = threadIdx.x;
  int wave = tid >> 6, lane = tid & 63;
  int c = lane & 15, kg = lane >> 4;
  int f0 = wave * 16;
  const f32x4 zero = {0,0,0,0};

  if (bx >= 480) {   // ---- G blocks: one per batch ----
    int b = bx - 480;
    short8v qa = {0,0,0,0,0,0,0,0};
    if (c < 3) {
      const float* qr = ((c == 0) ? qr1g : (c == 1) ? qr2g : qr3g) + (size_t)b * 32 + kg * 8;
      ushortT* p = (ushortT*)&qa;
      #pragma unroll
      for (int j = 0; j < 8; ++j) p[j] = f2bf(qr[j]);
    }
    const ushortT* bbase = fwmBT + (size_t)(f0 + c) * 2048 + kg * 8;
    float* g0 = Gg + (size_t)b * 4096 + f0 + c;
    for (int e = 0; e < 64; ++e) {
      short8v B = *reinterpret_cast<const short8v*>(bbase + (size_t)e * 32);
      f32x4 T = __builtin_amdgcn_mfma_f32_16x16x32_bf16(qa, B, zero, 0, 0, 0);
      if (kg == 0) {
        g0[e * 64]           = T[0];
        g0[1048576 + e * 64] = T[1];
        g0[2097152 + e * 64] = T[2];
      }
    }
    return;
  }

  int rb = bx;
  {
    int row = tid >> 4, c4 = tid & 15;
    float4 v1 = *reinterpret_cast<const float4*>(e1g + ((size_t)rb * 16 + row) * 64 + c4 * 4);
    float4 v2 = *reinterpret_cast<const float4*>(e2g + ((size_t)rb * 16 + row) * 64 + c4 * 4);
    *reinterpret_cast<float4*>(&e1t[row * 68 + c4 * 4]) = v1;
    *reinterpret_cast<float4*>(&e2t[row * 68 + c4 * 4]) = v2;
  }
  size_t rbase = ((size_t)rb * 16 + c) * 32 + kg * 8;
  short8v rA, rB, rC;
  {
    float4 x0 = *reinterpret_cast<const float4*>(r1g + rbase);
    float4 x1 = *reinterpret_cast<const float4*>(r1g + rbase + 4);
    ushortT* p = (ushortT*)&rA;
    p[0]=f2bf(x0.x); p[1]=f2bf(x0.y); p[2]=f2bf(x0.z); p[3]=f2bf(x0.w);
    p[4]=f2bf(x1.x); p[5]=f2bf(x1.y); p[6]=f2bf(x1.z); p[7]=f2bf(x1.w);
    x0 = *reinterpret_cast<const float4*>(r2g + rbase);
    x1 = *reinterpret_cast<const float4*>(r2g + rbase + 4);
    p = (ushortT*)&rB;
    p[0]=f2bf(x0.x); p[1]=f2bf(x0.y); p[2]=f2bf(x0.z); p[3]=f2bf(x0.w);
    p[4]=f2bf(x1.x); p[5]=f2bf(x1.y); p[6]=f2bf(x1.z); p[7]=f2bf(x1.w);
    x0 = *reinterpret_cast<const float4*>(r3g + rbase);
    x1 = *reinterpret_cast<const float4*>(r3g + rbase + 4);
    p = (ushortT*)&rC;
    p[0]=f2bf(x0.x); p[1]=f2bf(x0.y); p[2]=f2bf(x0.z); p[3]=f2bf(x0.w);
    p[4]=f2bf(x1.x); p[5]=f2bf(x1.y); p[6]=f2bf(x1.z); p[7]=f2bf(x1.w);
  }
  __syncthreads();
  const ushortT* bbase = fwmBT + (size_t)(f0 + c) * 2048 + kg * 8;
  f32x4 P1 = {0,0,0,0}, P2 = {0,0,0,0}, P3 = {0,0,0,0};
  int r0 = kg * 4;
  for (int e4 = 0; e4 < 16; ++e4) {
    float4 ea[4], eb[4];
    #pragma unroll
    for (int i = 0; i < 4; ++i) {
      ea[i] = *reinterpret_cast<const float4*>(&e1t[(r0 + i) * 68 + e4 * 4]);
      eb[i] = *reinterpret_cast<const float4*>(&e2t[(r0 + i) * 68 + e4 * 4]);
    }
    #pragma unroll
    for (int sub = 0; sub < 4; ++sub) {
      int e = e4 * 4 + sub;
      short8v B = *reinterpret_cast<const short8v*>(bbase + (size_t)e * 32);
      f32x4 T1 = __builtin_amdgcn_mfma_f32_16x16x32_bf16(rA, B, zero, 0, 0, 0);
      f32x4 T2 = __builtin_amdgcn_mfma_f32_16x16x32_bf16(rB, B, zero, 0, 0, 0);
      f32x4 T3 = __builtin_amdgcn_mfma_f32_16x16x32_bf16(rC, B, zero, 0, 0, 0);
      #pragma unroll
      for (int i = 0; i < 4; ++i) {
        float e1v = reinterpret_cast<const float*>(&ea[i])[sub];
        float e2v = reinterpret_cast<const float*>(&eb[i])[sub];
        P1[i] += e1v * T1[i];
        P2[i] += e1v * T2[i];
        P3[i] += e2v * T3[i];
      }
    }
  }
  #pragma unroll
  for (int i = 0; i < 4; ++i) {
    size_t row = (size_t)rb * 16 + kg * 4 + i;
    Pp[row * 64 + f0 + c]               = P1[i];
    Pp[491520 + row * 64 + f0 + c]      = P2[i];
    Pp[2 * 491520 + row * 64 + f0 + c]  = P3[i];
  }
}

// ---------------- scan: gram + RQ + layers + inference (F from precomputed G) ----------------
__global__ __launch_bounds__(1024) void scan_k(
    const float* __restrict__ Pp, const float* __restrict__ Gg,
    const float* __restrict__ e1g, const float* __restrict__ e2g,
    const float* __restrict__ r1g, const float* __restrict__ r2g, const float* __restrict__ r3g,
    const float* __restrict__ qe1g, const float* __restrict__ qr1g, const float* __restrict__ qr2g,
    const float* __restrict__ qr3g, const float* __restrict__ fn2p,
    const float* __restrict__ lng, const float* __restrict__ lnb, const float* __restrict__ Zg,
    float* __restrict__ out) {
  __shared__ __align__(16) float MPL[10800];            // gram M; partL overlays +4096
  __shared__ __align__(16) float e1L[2040], e2L[2040];  // [30][68]
  __shared__ __align__(16) float v1L[2040], v2L[2040], v3L[2040];
  __shared__ __align__(16) float r1L[1080], r2L[1080], r3L[1080];  // [30][36]
  __shared__ float uv[64], qv[96], alf[96], siL[64], rqL[272];
  __shared__ float redL[16];
  int b = blockIdx.x, tid = threadIdx.x;
  int s = tid >> 5, g = (tid >> 4) & 1, fo = tid & 15;
  int fq = fo * 4;
  bool act = s < 30;

  float H1[4], H2[4], H3[4], a1[4], a2[4], a3[4];
  #pragma unroll
  for (int j = 0; j < 4; ++j) { a1[j] = 0; a2[j] = 0; a3[j] = 0; }
  if (act) {
    size_t base = (size_t)b * 1920 + s * 64 + fq;
    float4 h1 = *reinterpret_cast<const float4*>(Pp + base);
    float4 h2 = *reinterpret_cast<const float4*>(Pp + 491520 + base);
    float4 h3 = *reinterpret_cast<const float4*>(Pp + 983040 + base);
    H1[0]=h1.x; H1[1]=h1.y; H1[2]=h1.z; H1[3]=h1.w;
    H2[0]=h2.x; H2[1]=h2.y; H2[2]=h2.z; H2[3]=h2.w;
    H3[0]=h3.x; H3[1]=h3.y; H3[2]=h3.z; H3[3]=h3.w;
  } else {
    #pragma unroll
    for (int j = 0; j < 4; ++j) { H1[j]=0; H2[j]=0; H3[j]=0; }
  }
  for (int i = tid; i < 1680; i += 1024) {
    if (i < 480) {
      int ss = i >> 4, c4 = i & 15;
      *reinterpret_cast<float4*>(&e1L[ss * 68 + c4 * 4]) =
          *reinterpret_cast<const float4*>(e1g + (size_t)b * 1920 + i * 4);
    } else if (i < 960) {
      int j = i - 480;
      int ss = j >> 4, c4 = j & 15;
      *reinterpret_cast<float4*>(&e2L[ss * 68 + c4 * 4]) =
          *reinterpret_cast<const float4*>(e2g + (size_t)b * 1920 + j * 4);
    } else {
      int j = i - 960;
      int which = j / 240, jj = j - which * 240;
      int ss = jj >> 3, c4 = jj & 7;
      float* dstL = (which == 0) ? r1L : (which == 1) ? r2L : r3L;
      const float* srcG = (which == 0) ? r1g : (which == 1) ? r2g : r3g;
      *reinterpret_cast<float4*>(&dstL[ss * 36 + c4 * 4]) =
          *reinterpret_cast<const float4*>(srcG + (size_t)b * 960 + jj * 4);
    }
  }
  if (tid >= 128 && tid < 224) {
    int t = tid - 128, st = t >> 5, k = t & 31;
    const float* qrg = (st == 0) ? qr1g : ((st == 1) ? qr2g : qr3g);
    qv[t] = qrg[(size_t)b * 32 + k];
  }
  __syncthreads();

  // ---- fused gram -> packed MP; threads >=900 compute RQ[st][k][s] ----
  if (tid < 900) {
    int si = tid / 30, sj = tid - si * 30;
    float g11 = 0, g12 = 0, g21 = 0, g22 = 0;
    {
      const float4* A1 = reinterpret_cast<const float4*>(&e1L[si * 68]);
      const float4* A2 = reinterpret_cast<const float4*>(&e2L[si * 68]);
      const float4* C1 = reinterpret_cast<const float4*>(&e1L[sj * 68]);
      const float4* C2 = reinterpret_cast<const float4*>(&e2L[sj * 68]);
      #pragma unroll 4
      for (int i = 0; i < 16; ++i) {
        float4 a1v = A1[i], a2v = A2[i], c1v = C1[i], c2v = C2[i];
        g11 += dot4(a1v, c1v); g12 += dot4(a1v, c2v);
        g21 += dot4(a2v, c1v); g22 += dot4(a2v, c2v);
      }
    }
    float R11=0,R12=0,R13=0,R21=0,R22=0,R23=0,R31=0,R32=0,R33=0;
    {
      const float4* X1 = reinterpret_cast<const float4*>(&r1L[si * 36]);
      const float4* X2 = reinterpret_cast<const float4*>(&r2L[si * 36]);
      const float4* X3 = reinterpret_cast<const float4*>(&r3L[si * 36]);
      const float4* Y1 = reinterpret_cast<const float4*>(&r1L[sj * 36]);
      const float4* Y2 = reinterpret_cast<const float4*>(&r2L[sj * 36]);
      const float4* Y3 = reinterpret_cast<const float4*>(&r3L[sj * 36]);
      #pragma unroll 4
      for (int i = 0; i < 8; ++i) {
        float4 x1 = X1[i], x2 = X2[i], x3 = X3[i];
        float4 y1 = Y1[i], y2 = Y2[i], y3 = Y3[i];
        R11 += dot4(x1, y1); R12 += dot4(x1, y2); R13 += dot4(x1, y3);
        R21 += dot4(x2, y1); R22 += dot4(x2, y2); R23 += dot4(x2, y3);
        R31 += dot4(x3, y1); R32 += dot4(x3, y2); R33 += dot4(x3, y3);
      }
    }
    float4* MPv = reinterpret_cast<float4*>(MPL);
    float4 p1; p1.x = g11 * R11; p1.y = g11 * R21; p1.z = g21 * R31; p1.w = 0.f;
    float4 p2; p2.x = g11 * R12; p2.y = g11 * R22; p2.z = g21 * R32; p2.w = 0.f;
    float4 p3; p3.x = g12 * R13; p3.y = g12 * R23; p3.z = g22 * R33; p3.w = 0.f;
    MPv[tid] = p1;
    MPv[900 + tid] = p2;
    MPv[1800 + tid] = p3;
  } else {
    #pragma unroll
    for (int ch = 0; ch < 3; ++ch) {
      int t = (tid - 900) + ch * 124;
      if (t < 270) {
        int st = t / 90, rem = t - st * 90;
        int k = rem / 30, s2 = rem - k * 30;
        const float* rL = (k == 0) ? r1L : (k == 1) ? r2L : r3L;
        const float* qp = qv + st * 32;
        float a = 0.f;
        #pragma unroll 8
        for (int r = 0; r < 32; ++r) a += rL[s2 * 36 + r] * qp[r];
        rqL[st * 90 + k * 30 + s2] = a;
      }
    }
  }
  __syncthreads();

  float n2 = 0.f;
  #pragma unroll
  for (int i = 0; i < 8; ++i) n2 += fn2p[i];
  float c0v = 1.f;

  auto prop = [&](const float* vsrc, int mbase) {
    float d1[4] = {0,0,0,0}, d2[4] = {0,0,0,0}, d3[4] = {0,0,0,0};
    if (act) {
      const float4* mrow = reinterpret_cast<const float4*>(MPL) + mbase + s * 30 + g * 15;
      const float* vb = vsrc + g * 15 * 68 + fq;
      #pragma unroll 5
      for (int i = 0; i < 15; ++i) {
        float4 m = mrow[i];
        float4 vv = *reinterpret_cast<const float4*>(vb + i * 68);
        d1[0]+=m.x*vv.x; d1[1]+=m.x*vv.y; d1[2]+=m.x*vv.z; d1[3]+=m.x*vv.w;
        d2[0]+=m.y*vv.x; d2[1]+=m.y*vv.y; d2[2]+=m.y*vv.z; d2[3]+=m.y*vv.w;
        d3[0]+=m.z*vv.x; d3[1]+=m.z*vv.y; d3[2]+=m.z*vv.z; d3[3]+=m.z*vv.w;
      }
    }
    #pragma unroll
    for (int j = 0; j < 4; ++j) {
      H1[j] += d1[j] + __shfl_xor(d1[j], 16);
      H2[j] += d2[j] + __shfl_xor(d2[j], 16);
      H3[j] += d3[j] + __shfl_xor(d3[j], 16);
    }
  };

  for (int layer = 0; layer < 3; ++layer) {
    float w[4], H2s[4], H3s[4], v1r[4], v2r[4], v3r[4];
    if (act) {
      float4 e2v = *reinterpret_cast<const float4*>(&e2L[s * 68 + fq]);
      w[0]=H1[0]; w[1]=H1[1]; w[2]=H1[2]; w[3]=H1[3];
      #pragma unroll
      for (int j = 0; j < 4; ++j) { H2s[j] = H2[j]; H3s[j] = H3[j]; }
      v1r[0] = e2v.x - H1[0]; v1r[1] = e2v.y - H1[1]; v1r[2] = e2v.z - H1[2]; v1r[3] = e2v.w - H1[3];
      if (g == 0) {
        float4 t; t.x=v1r[0]; t.y=v1r[1]; t.z=v1r[2]; t.w=v1r[3];
        *reinterpret_cast<float4*>(&v1L[s * 68 + fq]) = t;
      }
    }
    __syncthreads();
    prop(v1L, 0);
    if (act) {
      #pragma unroll
      for (int j = 0; j < 4; ++j) v2r[j] = w[j] - H2[j];
      if (g == 0) {
        float4 t; t.x=v2r[0]; t.y=v2r[1]; t.z=v2r[2]; t.w=v2r[3];
        *reinterpret_cast<float4*>(&v2L[s * 68 + fq]) = t;
      }
    }
    __syncthreads();
    prop(v2L, 900);
    if (act) {
      float4 e1v = *reinterpret_cast<const float4*>(&e1L[s * 68 + fq]);
      v3r[0] = e1v.x - H3[0]; v3r[1] = e1v.y - H3[1]; v3r[2] = e1v.z - H3[2]; v3r[3] = e1v.w - H3[3];
      if (g == 0) {
        float4 t; t.x=v3r[0]; t.y=v3r[1]; t.z=v3r[2]; t.w=v3r[3];
        *reinterpret_cast<float4*>(&v3L[s * 68 + fq]) = t;
      }
    }
    __syncthreads();
    prop(v3L, 1800);
    float local = 0.f;
    if (act) {
      #pragma unroll
      for (int j = 0; j < 4; ++j) { a1[j] += v1r[j]; a2[j] += v2r[j]; a3[j] += v3r[j]; }
      if (g == 0) {
        #pragma unroll
        for (int j = 0; j < 4; ++j)
          local += v1r[j] * (w[j] + H1[j]) + v2r[j] * (H2s[j] + H2[j]) + v3r[j] * (H3s[j] + H3[j]);
      }
    }
    local = wreduce64(local);
    if ((tid & 63) == 0) redL[tid >> 6] = local;
    __syncthreads();
    float tot = n2;
    #pragma unroll
    for (int i = 0; i < 16; ++i) tot += redL[i];
    float fn = fmaxf(sqrtf(tot), 1.f);
    float inv = 1.f / fn;
    n2 = tot * inv * inv;
    c0v *= inv;
    if (act) {
      #pragma unroll
      for (int j = 0; j < 4; ++j) { H1[j]*=inv; H2[j]*=inv; H3[j]*=inv; a1[j]*=inv; a2[j]*=inv; a3[j]*=inv; }
    }
  }

  // ---- inference ----
  if (act && g == 0) {
    float4 t1; t1.x=a1[0]; t1.y=a1[1]; t1.z=a1[2]; t1.w=a1[3];
    float4 t2; t2.x=a2[0]; t2.y=a2[1]; t2.z=a2[2]; t2.w=a2[3];
    float4 t3; t3.x=a3[0]; t3.y=a3[1]; t3.z=a3[2]; t3.w=a3[3];
    *reinterpret_cast<float4*>(&v1L[s * 68 + fq]) = t1;
    *reinterpret_cast<float4*>(&v2L[s * 68 + fq]) = t2;
    *reinterpret_cast<float4*>(&v3L[s * 68 + fq]) = t3;
  }
  if (tid < 64) { uv[tid] = qe1g[(size_t)b * 64 + tid]; siL[tid] = 0.f; }
  __syncthreads();
  float* partL = MPL + 4096;     // [16][64]
  int k32 = tid & 31;
  for (int st = 0; st < 3; ++st) {
    if (act) {
      float u0 = uv[k32], u1 = uv[k32 + 32];
      float eu1 = e1L[s * 68 + k32] * u0 + e1L[s * 68 + k32 + 32] * u1;
      float eu2 = e2L[s * 68 + k32] * u0 + e2L[s * 68 + k32 + 32] * u1;
      #pragma unroll
      for (int d = 16; d > 0; d >>= 1) {
        eu1 += __shfl_down(eu1, d, 32); eu2 += __shfl_down(eu2, d, 32);
      }
      if (k32 == 0) {
        alf[s]      = eu1 * rqL[st * 90 + s];
        alf[32 + s] = eu1 * rqL[st * 90 + 30 + s];
        alf[64 + s] = eu2 * rqL[st * 90 + 60 + s];
      }
    }
    __syncthreads();
    {
      int p = tid >> 6, f = tid & 63;
      float part = 0.f;
      if (p < 12) {
        int start = (p < 6) ? p * 3 : 18 + (p - 6) * 2;
        int cnt = (p < 6) ? 3 : 2;
        for (int q = 0; q < cnt; ++q) {
          int sp = start + q;
          part += alf[sp] * v1L[sp * 68 + f] + alf[32 + sp] * v2L[sp * 68 + f]
                + alf[64 + sp] * v3L[sp * 68 + f];
        }
      } else {
        int e0 = (p - 12) * 16;
        const float* Gp = Gg + (size_t)st * 1048576 + (size_t)b * 4096 + (size_t)e0 * 64 + f;
        float F = 0.f;
        #pragma unroll 4
        for (int e = 0; e < 16; ++e) F += uv[e0 + e] * Gp[e * 64];
        part = c0v * F;
      }
      partL[p * 64 + f] = part;
    }
    __syncthreads();
    if (tid < 64) {
      float raw = 0.f;
      #pragma unroll
      for (int p = 0; p < 16; ++p) raw += partL[p * 64 + tid];
      float mean = wreduce64(raw) * (1.f / 64.f);
      float d = raw - mean;
      float var = wreduce64(d * d) * (1.f / 63.f);
      float y = lng[st * 64 + tid] * d / (sqrtf(var) + 1e-6f) + lnb[st * 64 + tid];
      siL[tid] += y;
      uv[tid] = y;
    }
    __syncthreads();
  }
  if (tid < 9) {
    float o = 0.f;
    for (int ff = 0; ff < 64; ++ff) o += siL[ff] * Zg[ff * 9 + tid];
    out[(size_t)b * 9 + tid] = o;
  }
}

extern "C" void kernel_launch(void* const* d_in, const int* in_sizes, int n_in,
                              void* d_out, int out_size, void* d_ws, size_t ws_size,
                              hipStream_t stream) {
  const int*   story = (const int*)d_in[0];
  const int*   query = (const int*)d_in[1];
  const float* WE    = (const float*)d_in[2];
  const float* PE    = (const float*)d_in[3];
  const float* ueW1  = (const float*)d_in[4];
  const float* ueb1  = (const float*)d_in[5];
  const float* ueW2  = (const float*)d_in[6];
  const float* ueb2  = (const float*)d_in[7];
  const float* urW1  = (const float*)d_in[8];
  const float* urb1  = (const float*)d_in[9];
  const float* urW2  = (const float*)d_in[10];
  const float* urb2  = (const float*)d_in[11];
  const float* fwm   = (const float*)d_in[12];
  const float* ieW1  = (const float*)d_in[13];
  const float* ieb1  = (const float*)d_in[14];
  const float* ieW2  = (const float*)d_in[15];
  const float* ieb2  = (const float*)d_in[16];
  const float* irW1  = (const float*)d_in[17];
  const float* irb1  = (const float*)d_in[18];
  const float* irW2  = (const float*)d_in[19];
  const float* irb2  = (const float*)d_in[20];
  const float* lng   = (const float*)d_in[21];
  const float* lnb   = (const float*)d_in[22];
  const float* Z     = (const float*)d_in[23];
  float* W = (float*)d_ws;
  float* out = (float*)d_out;

  ushortT* sentB = (ushortT*)(W + OF_SENTB);
  ushortT* qembB = (ushortT*)(W + OF_QEMBB);
  ushortT* W1A   = (ushortT*)(W + OF_W1A);
  ushortT* W2TE  = (ushortT*)(W + OF_W2TE);
  ushortT* W2TR  = (ushortT*)(W + OF_W2TR);
  ushortT* fwmBT = (ushortT*)(W + OF_FWMB);

  prep_k<<<4232, 256, 0, stream>>>(story, query, WE, PE,
      ueW1, urW1, ieW1, irW1, ueW2, urW2, ieW2, irW2, fwm,
      sentB, qembB, W1A, W2TE, W2TR, fwmBT, W + OF_FN2);

  mlpm_k<<<dim3(240, 9), 256, 0, stream>>>(sentB, qembB, W1A,
      ueb1, urb1, ieb1, irb1, W2TE, W2TR, ueb2, urb2, ieb2, irb2,
      W + OF_E1, W + OF_R1, W + OF_QE1, W + OF_QR1);

  pstage_k<<<736, 256, 0, stream>>>(fwmBT, W + OF_E1, W + OF_E1 + 491520,
      W + OF_R1, W + OF_R1 + 245760, W + OF_R1 + 2 * 245760,
      W + OF_QR1, W + OF_QR1 + 8192, W + OF_QR1 + 16384,
      W + OF_PP, W + OF_G);

  scan_k<<<NB, 1024, 0, stream>>>(W + OF_PP, W + OF_G,
      W + OF_E1, W + OF_E1 + 491520,
      W + OF_R1, W + OF_R1 + 245760, W + OF_R1 + 2 * 245760,
      W + OF_QE1, W + OF_QR1, W + OF_QR1 + 8192, W + OF_QR1 + 16384,
      W + OF_FN2, lng, lnb, Z, out);
}

// Round 13
// 131.405 us; speedup vs baseline: 5.6710x; 1.1381x over previous
//
#include <hip/hip_runtime.h>
#include <hip/hip_bf16.h>

// Sizes
#define NB 256
#define NS 30
#define NW 10
#define SYM 128
#define HID 512
#define ENT 64
#define ROLE 32

typedef unsigned short ushortT;
typedef __attribute__((ext_vector_type(8))) short short8v;   // 8 bf16
typedef __attribute__((ext_vector_type(4))) float f32x4;

// Workspace offsets (floats; bf16 arrays use 2 elems per float slot)
static const size_t OF_SENTB = 0;         // 7680*128 bf16 -> 491520 fl
static const size_t OF_QEMBB = 491520;    // 256*128 bf16 -> 16384 fl
static const size_t OF_W1A   = 507904;    // 9*512*128 bf16 -> 294912 fl
static const size_t OF_W2TE  = 802816;    // 3*64*512 bf16 -> 49152 fl
static const size_t OF_W2TR  = 851968;    // 6*32*512 bf16 -> 49152 fl
static const size_t OF_FWMB  = 901120;    // 64*2048 bf16 -> 65536 fl  (fwm^T [f][e*32+r])
static const size_t OF_E1    = 966656;    // 7680*64 x2 (stride 491520)
static const size_t OF_R1    = 1949696;   // 7680*32 x3 (stride 245760)
static const size_t OF_QE1   = 2686976;   // 256*64
static const size_t OF_QR1   = 2703360;   // 256*32 x3 (stride 8192)
static const size_t OF_PP    = 2727936;   // 3 * 7680*64 = 1,474,560
static const size_t OF_FN2   = 4202496;   // 8 partials
static const size_t OF_G     = 4202624;   // 3*256*64*64 = 3,145,728

__device__ __forceinline__ ushortT f2bf(float x) {
  unsigned u = __float_as_uint(x);
  unsigned r = (u + 0x7fffu + ((u >> 16) & 1u)) >> 16;
  return (ushortT)r;
}
__device__ __forceinline__ float ftanh(float x) {
  float t = __expf(2.f * x);
  return 1.f - 2.f * __builtin_amdgcn_rcpf(t + 1.f);
}
__device__ __forceinline__ float dot4(const float4& a, const float4& b) {
  return a.x * b.x + a.y * b.y + a.z * b.z + a.w * b.w;
}
__device__ __forceinline__ float wreduce64(float v) {
  #pragma unroll
  for (int o = 32; o > 0; o >>= 1) v += __shfl_xor(v, o);
  return v;
}

// ---------------- unified prep: embed + all transposes/converts + fnorm partials ----------------
__global__ __launch_bounds__(256) void prep_k(
    const int* __restrict__ story, const int* __restrict__ query,
    const float* __restrict__ WE, const float* __restrict__ PE,
    const float* __restrict__ ueW1, const float* __restrict__ urW1,
    const float* __restrict__ ieW1, const float* __restrict__ irW1,
    const float* __restrict__ ueW2, const float* __restrict__ urW2,
    const float* __restrict__ ieW2, const float* __restrict__ irW2,
    const float* __restrict__ fwm,
    ushortT* __restrict__ sentb, ushortT* __restrict__ qembb,
    ushortT* __restrict__ W1A, ushortT* __restrict__ W2TE,
    ushortT* __restrict__ W2TR, ushortT* __restrict__ fwmBT,
    float* __restrict__ fn2) {
  __shared__ float tl[64 * 65];
  __shared__ float red[4];
  int bx = blockIdx.x, tid = threadIdx.x;
  if (bx < 3968) {
    int row = bx * 2 + (tid >> 7);
    int e = tid & 127;
    const int* idx; ushortT* dst;
    if (row < 7680) { idx = story + (size_t)row * NW; dst = sentb + (size_t)row * SYM; }
    else            { idx = query + (size_t)(row - 7680) * NW; dst = qembb + (size_t)(row - 7680) * SYM; }
    float acc = 0.f;
    #pragma unroll
    for (int w = 0; w < NW; ++w) acc += WE[idx[w] * SYM + e] * PE[w * SYM + e];
    dst[e] = f2bf(acc);
    return;
  }
  bx -= 3968;
  const float* src; ushortT* dst; int R, C, tr0, tc0;
  if (bx < 144) {
    int h = bx >> 4, t = bx & 15;
    src = (h < 2) ? ueW1 + (size_t)h * 65536 : (h < 5) ? urW1 + (size_t)(h - 2) * 65536
        : (h == 5) ? ieW1 : irW1 + (size_t)(h - 6) * 65536;
    dst = W1A + (size_t)h * 65536;
    R = 128; C = 512; tr0 = (t >> 3) * 64; tc0 = (t & 7) * 64;
  } else if (bx < 168) {
    int h = (bx - 144) >> 3, t = (bx - 144) & 7;
    src = (h < 2) ? ueW2 + (size_t)h * 32768 : ieW2;
    dst = W2TE + (size_t)h * 32768;
    R = 512; C = 64; tr0 = t * 64; tc0 = 0;
  } else if (bx < 216) {
    int h = (bx - 168) >> 3, t = (bx - 168) & 7;
    src = (h < 3) ? urW2 + (size_t)h * 16384 : irW2 + (size_t)(h - 3) * 16384;
    dst = W2TR + (size_t)h * 16384;
    R = 512; C = 32; tr0 = t * 64; tc0 = 0;
  } else if (bx < 248) {
    int t = bx - 216;
    src = fwm; dst = fwmBT; R = 2048; C = 64; tr0 = t * 64; tc0 = 0;
  } else {
    int blk = bx - 248;
    const float4* f4 = reinterpret_cast<const float4*>(fwm) + blk * 4096;
    float a = 0.f;
    for (int i = tid; i < 4096; i += 256) {
      float4 v = f4[i];
      a += v.x*v.x + v.y*v.y + v.z*v.z + v.w*v.w;
    }
    a = wreduce64(a);
    if ((tid & 63) == 0) red[tid >> 6] = a;
    __syncthreads();
    if (tid == 0) fn2[blk] = red[0] + red[1] + red[2] + red[3];
    return;
  }
  int TC = (C < 64) ? C : 64;
  int n = 64 * TC;
  for (int i = tid; i < n; i += 256) {
    int r = i / TC, c = i % TC;
    tl[r * 65 + c] = src[(size_t)(tr0 + r) * C + tc0 + c];
  }
  __syncthreads();
  for (int i = tid; i < n; i += 256) {
    int c = i >> 6, r = i & 63;
    dst[(size_t)(tc0 + c) * R + tr0 + r] = f2bf(tl[r * 65 + c]);
  }
}

// ---------------- MFMA fused 2-layer MLP ----------------
// Wave owns BOTH 16-row tiles x 128 GEMM1 cols: every B-frag feeds 2 MFMAs, 8 serial tiles.
__global__ __launch_bounds__(256, 4) void mlpm_k(
    const ushortT* __restrict__ sentB, const ushortT* __restrict__ qembB,
    const ushortT* __restrict__ W1A,
    const float* __restrict__ ueb1, const float* __restrict__ urb1,
    const float* __restrict__ ieb1, const float* __restrict__ irb1,
    const ushortT* __restrict__ W2TE, const ushortT* __restrict__ W2TR,
    const float* __restrict__ ueb2, const float* __restrict__ urb2,
    const float* __restrict__ ieb2, const float* __restrict__ irb2,
    float* __restrict__ E1, float* __restrict__ R1,
    float* __restrict__ QE1, float* __restrict__ QR1) {
  __shared__ __align__(16) ushortT Hl[32 * 520];
  int y = blockIdx.y;
  bool isQ = y >= 5;
  if (isQ && blockIdx.x >= 8) return;
  int r0 = blockIdx.x * 32, tid = threadIdx.x;
  int wave = tid >> 6, lane = tid & 63;
  int lrow = lane & 15;
  int kgrp = lane >> 4;
  const ushortT* Xb = isQ ? qembB : sentB;
  const ushortT* W1h = W1A + (size_t)y * 65536;
  const float* b1 = (y < 2) ? ueb1 + y * 512 : (y < 5) ? urb1 + (y - 2) * 512
                  : (y == 5) ? ieb1 : irb1 + (y - 6) * 512;
  bool isE = (y < 2) || (y == 5);

  int cw = wave * 128;                      // GEMM1 col range for this wave

  // A fragments: both row-tiles, full K=128
  short8v afr[2][4];
  #pragma unroll
  for (int rt = 0; rt < 2; ++rt) {
    const ushortT* arow = Xb + (size_t)(r0 + rt * 16 + lrow) * 128 + kgrp * 8;
    #pragma unroll
    for (int kt = 0; kt < 4; ++kt)
      afr[rt][kt] = *reinterpret_cast<const short8v*>(arow + kt * 32);
  }

  // GEMM1: 8 col-tiles; each B-frag feeds 2 MFMAs (row-tiles); 4 indep acc chains
  #pragma unroll
  for (int ct = 0; ct < 8; ++ct) {
    int c0 = cw + ct * 16;
    const ushortT* bcol = W1h + (size_t)(c0 + lrow) * 128 + kgrp * 8;
    short8v bf0 = *reinterpret_cast<const short8v*>(bcol);
    short8v bf1 = *reinterpret_cast<const short8v*>(bcol + 32);
    short8v bf2 = *reinterpret_cast<const short8v*>(bcol + 64);
    short8v bf3 = *reinterpret_cast<const short8v*>(bcol + 96);
    f32x4 aA[2] = {{0.f,0.f,0.f,0.f},{0.f,0.f,0.f,0.f}};
    f32x4 aB[2] = {{0.f,0.f,0.f,0.f},{0.f,0.f,0.f,0.f}};
    #pragma unroll
    for (int rt = 0; rt < 2; ++rt) {
      aA[rt] = __builtin_amdgcn_mfma_f32_16x16x32_bf16(afr[rt][0], bf0, aA[rt], 0, 0, 0);
      aB[rt] = __builtin_amdgcn_mfma_f32_16x16x32_bf16(afr[rt][1], bf1, aB[rt], 0, 0, 0);
      aA[rt] = __builtin_amdgcn_mfma_f32_16x16x32_bf16(afr[rt][2], bf2, aA[rt], 0, 0, 0);
      aB[rt] = __builtin_amdgcn_mfma_f32_16x16x32_bf16(afr[rt][3], bf3, aB[rt], 0, 0, 0);
    }
    int lcol = c0 + lrow;
    float bb = b1[lcol];
    #pragma unroll
    for (int rt = 0; rt < 2; ++rt)
      #pragma unroll
      for (int i = 0; i < 4; ++i) {
        float hv = ftanh(aA[rt][i] + aB[rt][i] + bb);
        Hl[(rt * 16 + kgrp * 4 + i) * 520 + lcol] = f2bf(hv);
      }
  }
  __syncthreads();

  if (isE) {
    int slot = (y == 5) ? 2 : y;
    const ushortT* W2h = W2TE + (size_t)slot * 32768;
    const float* b2 = (y == 5) ? ieb2 : ueb2 + y * 64;
    float* Out = (y == 5) ? QE1 : E1 + (size_t)y * 491520;
    int rt = wave >> 1, cb = (wave & 1) * 32;     // wave = (row-tile, col-half)
    f32x4 accA[2] = {{0.f,0.f,0.f,0.f},{0.f,0.f,0.f,0.f}};
    f32x4 accB[2] = {{0.f,0.f,0.f,0.f},{0.f,0.f,0.f,0.f}};
    #pragma unroll
    for (int kt = 0; kt < 16; kt += 2) {
      int kb0 = kt * 32 + kgrp * 8;
      int kb1 = kb0 + 32;
      short8v a0 = *reinterpret_cast<const short8v*>(&Hl[(rt * 16 + lrow) * 520 + kb0]);
      short8v a1 = *reinterpret_cast<const short8v*>(&Hl[(rt * 16 + lrow) * 520 + kb1]);
      #pragma unroll
      for (int t = 0; t < 2; ++t) {
        const ushortT* wc = W2h + (size_t)(cb + t * 16 + lrow) * 512;
        short8v b0 = *reinterpret_cast<const short8v*>(wc + kb0);
        short8v b1v = *reinterpret_cast<const short8v*>(wc + kb1);
        accA[t] = __builtin_amdgcn_mfma_f32_16x16x32_bf16(a0, b0, accA[t], 0, 0, 0);
        accB[t] = __builtin_amdgcn_mfma_f32_16x16x32_bf16(a1, b1v, accB[t], 0, 0, 0);
      }
    }
    #pragma unroll
    for (int t = 0; t < 2; ++t) {
      int col = cb + t * 16 + lrow;
      float bb = b2[col];
      #pragma unroll
      for (int i = 0; i < 4; ++i) {
        int grow = r0 + rt * 16 + kgrp * 4 + i;
        Out[(size_t)grow * 64 + col] = ftanh(accA[t][i] + accB[t][i] + bb);
      }
    }
  } else {
    int slot = (y < 5) ? (y - 2) : (3 + y - 6);
    const ushortT* W2h = W2TR + (size_t)slot * 16384;
    const float* b2 = (y < 5) ? urb2 + (y - 2) * 32 : irb2 + (y - 6) * 32;
    float* Out = (y < 5) ? R1 + (size_t)(y - 2) * 245760 : QR1 + (size_t)(y - 6) * 8192;
    int rt = wave >> 1, cb = (wave & 1) * 16;     // 2 row-tiles x 2 col-tiles = 4 waves
    f32x4 accA = {0.f, 0.f, 0.f, 0.f}, accB = {0.f, 0.f, 0.f, 0.f};
    const ushortT* wc = W2h + (size_t)(cb + lrow) * 512;
    #pragma unroll
    for (int kt = 0; kt < 16; kt += 2) {
      int kb0 = kt * 32 + kgrp * 8;
      int kb1 = kb0 + 32;
      short8v a0 = *reinterpret_cast<const short8v*>(&Hl[(rt * 16 + lrow) * 520 + kb0]);
      short8v a1 = *reinterpret_cast<const short8v*>(&Hl[(rt * 16 + lrow) * 520 + kb1]);
      short8v b0 = *reinterpret_cast<const short8v*>(wc + kb0);
      short8v b1v = *reinterpret_cast<const short8v*>(wc + kb1);
      accA = __builtin_amdgcn_mfma_f32_16x16x32_bf16(a0, b0, accA, 0, 0, 0);
      accB = __builtin_amdgcn_mfma_f32_16x16x32_bf16(a1, b1v, accB, 0, 0, 0);
    }
    int col = cb + lrow;
    float bb = b2[col];
    #pragma unroll
    for (int i = 0; i < 4; ++i) {
      int grow = r0 + rt * 16 + kgrp * 4 + i;
      Out[(size_t)grow * 32 + col] = ftanh(accA[i] + accB[i] + bb);
    }
  }
}

// ---------------- MFMA P-stage (bx<480) + G-stage (bx>=480) ----------------
__global__ __launch_bounds__(256) void pstage_k(const ushortT* __restrict__ fwmBT,
    const float* __restrict__ e1g, const float* __restrict__ e2g,
    const float* __restrict__ r1g, const float* __restrict__ r2g, const float* __restrict__ r3g,
    const float* __restrict__ qr1g, const float* __restrict__ qr2g, const float* __restrict__ qr3g,
    float* __restrict__ Pp, float* __restrict__ Gg) {
  __shared__ __align__(16) float e1t[16 * 68], e2t[16 * 68];
  int bx = blockIdx.x, tid = threadIdx.x;
  int wave = tid >> 6, lane = tid & 63;
  int c = lane & 15, kg = lane >> 4;
  int f0 = wave * 16;
  const f32x4 zero = {0,0,0,0};

  if (bx >= 480) {   // ---- G blocks: one per batch ----
    int b = bx - 480;
    short8v qa = {0,0,0,0,0,0,0,0};
    if (c < 3) {
      const float* qr = ((c == 0) ? qr1g : (c == 1) ? qr2g : qr3g) + (size_t)b * 32 + kg * 8;
      ushortT* p = (ushortT*)&qa;
      #pragma unroll
      for (int j = 0; j < 8; ++j) p[j] = f2bf(qr[j]);
    }
    const ushortT* bbase = fwmBT + (size_t)(f0 + c) * 2048 + kg * 8;
    float* g0 = Gg + (size_t)b * 4096 + f0 + c;
    for (int e = 0; e < 64; ++e) {
      short8v B = *reinterpret_cast<const short8v*>(bbase + (size_t)e * 32);
      f32x4 T = __builtin_amdgcn_mfma_f32_16x16x32_bf16(qa, B, zero, 0, 0, 0);
      if (kg == 0) {
        g0[e * 64]           = T[0];
        g0[1048576 + e * 64] = T[1];
        g0[2097152 + e * 64] = T[2];
      }
    }
    return;
  }

  int rb = bx;
  {
    int row = tid >> 4, c4 = tid & 15;
    float4 v1 = *reinterpret_cast<const float4*>(e1g + ((size_t)rb * 16 + row) * 64 + c4 * 4);
    float4 v2 = *reinterpret_cast<const float4*>(e2g + ((size_t)rb * 16 + row) * 64 + c4 * 4);
    *reinterpret_cast<float4*>(&e1t[row * 68 + c4 * 4]) = v1;
    *reinterpret_cast<float4*>(&e2t[row * 68 + c4 * 4]) = v2;
  }
  size_t rbase = ((size_t)rb * 16 + c) * 32 + kg * 8;
  short8v rA, rB, rC;
  {
    float4 x0 = *reinterpret_cast<const float4*>(r1g + rbase);
    float4 x1 = *reinterpret_cast<const float4*>(r1g + rbase + 4);
    ushortT* p = (ushortT*)&rA;
    p[0]=f2bf(x0.x); p[1]=f2bf(x0.y); p[2]=f2bf(x0.z); p[3]=f2bf(x0.w);
    p[4]=f2bf(x1.x); p[5]=f2bf(x1.y); p[6]=f2bf(x1.z); p[7]=f2bf(x1.w);
    x0 = *reinterpret_cast<const float4*>(r2g + rbase);
    x1 = *reinterpret_cast<const float4*>(r2g + rbase + 4);
    p = (ushortT*)&rB;
    p[0]=f2bf(x0.x); p[1]=f2bf(x0.y); p[2]=f2bf(x0.z); p[3]=f2bf(x0.w);
    p[4]=f2bf(x1.x); p[5]=f2bf(x1.y); p[6]=f2bf(x1.z); p[7]=f2bf(x1.w);
    x0 = *reinterpret_cast<const float4*>(r3g + rbase);
    x1 = *reinterpret_cast<const float4*>(r3g + rbase + 4);
    p = (ushortT*)&rC;
    p[0]=f2bf(x0.x); p[1]=f2bf(x0.y); p[2]=f2bf(x0.z); p[3]=f2bf(x0.w);
    p[4]=f2bf(x1.x); p[5]=f2bf(x1.y); p[6]=f2bf(x1.z); p[7]=f2bf(x1.w);
  }
  __syncthreads();
  const ushortT* bbase = fwmBT + (size_t)(f0 + c) * 2048 + kg * 8;
  f32x4 P1 = {0,0,0,0}, P2 = {0,0,0,0}, P3 = {0,0,0,0};
  int r0 = kg * 4;
  for (int e4 = 0; e4 < 16; ++e4) {
    float4 ea[4], eb[4];
    #pragma unroll
    for (int i = 0; i < 4; ++i) {
      ea[i] = *reinterpret_cast<const float4*>(&e1t[(r0 + i) * 68 + e4 * 4]);
      eb[i] = *reinterpret_cast<const float4*>(&e2t[(r0 + i) * 68 + e4 * 4]);
    }
    #pragma unroll
    for (int sub = 0; sub < 4; ++sub) {
      int e = e4 * 4 + sub;
      short8v B = *reinterpret_cast<const short8v*>(bbase + (size_t)e * 32);
      f32x4 T1 = __builtin_amdgcn_mfma_f32_16x16x32_bf16(rA, B, zero, 0, 0, 0);
      f32x4 T2 = __builtin_amdgcn_mfma_f32_16x16x32_bf16(rB, B, zero, 0, 0, 0);
      f32x4 T3 = __builtin_amdgcn_mfma_f32_16x16x32_bf16(rC, B, zero, 0, 0, 0);
      #pragma unroll
      for (int i = 0; i < 4; ++i) {
        float e1v = reinterpret_cast<const float*>(&ea[i])[sub];
        float e2v = reinterpret_cast<const float*>(&eb[i])[sub];
        P1[i] += e1v * T1[i];
        P2[i] += e1v * T2[i];
        P3[i] += e2v * T3[i];
      }
    }
  }
  #pragma unroll
  for (int i = 0; i < 4; ++i) {
    size_t row = (size_t)rb * 16 + kg * 4 + i;
    Pp[row * 64 + f0 + c]               = P1[i];
    Pp[491520 + row * 64 + f0 + c]      = P2[i];
    Pp[2 * 491520 + row * 64 + f0 + c]  = P3[i];
  }
}

// ---------------- scan: gram + RQ + layers + inference (F from precomputed G) ----------------
__global__ __launch_bounds__(1024) void scan_k(
    const float* __restrict__ Pp, const float* __restrict__ Gg,
    const float* __restrict__ e1g, const float* __restrict__ e2g,
    const float* __restrict__ r1g, const float* __restrict__ r2g, const float* __restrict__ r3g,
    const float* __restrict__ qe1g, const float* __restrict__ qr1g, const float* __restrict__ qr2g,
    const float* __restrict__ qr3g, const float* __restrict__ fn2p,
    const float* __restrict__ lng, const float* __restrict__ lnb, const float* __restrict__ Zg,
    float* __restrict__ out) {
  __shared__ __align__(16) float MPL[10800];            // gram M; partL overlays +4096
  __shared__ __align__(16) float e1L[2040], e2L[2040];  // [30][68]
  __shared__ __align__(16) float v1L[2040], v2L[2040], v3L[2040];
  __shared__ __align__(16) float r1L[1080], r2L[1080], r3L[1080];  // [30][36]
  __shared__ float uv[64], qv[96], alf[96], siL[64], rqL[272];
  __shared__ float redL[16];
  int b = blockIdx.x, tid = threadIdx.x;
  int s = tid >> 5, g = (tid >> 4) & 1, fo = tid & 15;
  int fq = fo * 4;
  bool act = s < 30;

  float H1[4], H2[4], H3[4], a1[4], a2[4], a3[4];
  #pragma unroll
  for (int j = 0; j < 4; ++j) { a1[j] = 0; a2[j] = 0; a3[j] = 0; }
  if (act) {
    size_t base = (size_t)b * 1920 + s * 64 + fq;
    float4 h1 = *reinterpret_cast<const float4*>(Pp + base);
    float4 h2 = *reinterpret_cast<const float4*>(Pp + 491520 + base);
    float4 h3 = *reinterpret_cast<const float4*>(Pp + 983040 + base);
    H1[0]=h1.x; H1[1]=h1.y; H1[2]=h1.z; H1[3]=h1.w;
    H2[0]=h2.x; H2[1]=h2.y; H2[2]=h2.z; H2[3]=h2.w;
    H3[0]=h3.x; H3[1]=h3.y; H3[2]=h3.z; H3[3]=h3.w;
  } else {
    #pragma unroll
    for (int j = 0; j < 4; ++j) { H1[j]=0; H2[j]=0; H3[j]=0; }
  }
  for (int i = tid; i < 1680; i += 1024) {
    if (i < 480) {
      int ss = i >> 4, c4 = i & 15;
      *reinterpret_cast<float4*>(&e1L[ss * 68 + c4 * 4]) =
          *reinterpret_cast<const float4*>(e1g + (size_t)b * 1920 + i * 4);
    } else if (i < 960) {
      int j = i - 480;
      int ss = j >> 4, c4 = j & 15;
      *reinterpret_cast<float4*>(&e2L[ss * 68 + c4 * 4]) =
          *reinterpret_cast<const float4*>(e2g + (size_t)b * 1920 + j * 4);
    } else {
      int j = i - 960;
      int which = j / 240, jj = j - which * 240;
      int ss = jj >> 3, c4 = jj & 7;
      float* dstL = (which == 0) ? r1L : (which == 1) ? r2L : r3L;
      const float* srcG = (which == 0) ? r1g : (which == 1) ? r2g : r3g;
      *reinterpret_cast<float4*>(&dstL[ss * 36 + c4 * 4]) =
          *reinterpret_cast<const float4*>(srcG + (size_t)b * 960 + jj * 4);
    }
  }
  if (tid >= 128 && tid < 224) {
    int t = tid - 128, st = t >> 5, k = t & 31;
    const float* qrg = (st == 0) ? qr1g : ((st == 1) ? qr2g : qr3g);
    qv[t] = qrg[(size_t)b * 32 + k];
  }
  __syncthreads();

  // ---- fused gram -> packed MP; threads >=900 compute RQ[st][k][s] ----
  if (tid < 900) {
    int si = tid / 30, sj = tid - si * 30;
    float g11 = 0, g12 = 0, g21 = 0, g22 = 0;
    {
      const float4* A1 = reinterpret_cast<const float4*>(&e1L[si * 68]);
      const float4* A2 = reinterpret_cast<const float4*>(&e2L[si * 68]);
      const float4* C1 = reinterpret_cast<const float4*>(&e1L[sj * 68]);
      const float4* C2 = reinterpret_cast<const float4*>(&e2L[sj * 68]);
      #pragma unroll 4
      for (int i = 0; i < 16; ++i) {
        float4 a1v = A1[i], a2v = A2[i], c1v = C1[i], c2v = C2[i];
        g11 += dot4(a1v, c1v); g12 += dot4(a1v, c2v);
        g21 += dot4(a2v, c1v); g22 += dot4(a2v, c2v);
      }
    }
    float R11=0,R12=0,R13=0,R21=0,R22=0,R23=0,R31=0,R32=0,R33=0;
    {
      const float4* X1 = reinterpret_cast<const float4*>(&r1L[si * 36]);
      const float4* X2 = reinterpret_cast<const float4*>(&r2L[si * 36]);
      const float4* X3 = reinterpret_cast<const float4*>(&r3L[si * 36]);
      const float4* Y1 = reinterpret_cast<const float4*>(&r1L[sj * 36]);
      const float4* Y2 = reinterpret_cast<const float4*>(&r2L[sj * 36]);
      const float4* Y3 = reinterpret_cast<const float4*>(&r3L[sj * 36]);
      #pragma unroll 4
      for (int i = 0; i < 8; ++i) {
        float4 x1 = X1[i], x2 = X2[i], x3 = X3[i];
        float4 y1 = Y1[i], y2 = Y2[i], y3 = Y3[i];
        R11 += dot4(x1, y1); R12 += dot4(x1, y2); R13 += dot4(x1, y3);
        R21 += dot4(x2, y1); R22 += dot4(x2, y2); R23 += dot4(x2, y3);
        R31 += dot4(x3, y1); R32 += dot4(x3, y2); R33 += dot4(x3, y3);
      }
    }
    float4* MPv = reinterpret_cast<float4*>(MPL);
    float4 p1; p1.x = g11 * R11; p1.y = g11 * R21; p1.z = g21 * R31; p1.w = 0.f;
    float4 p2; p2.x = g11 * R12; p2.y = g11 * R22; p2.z = g21 * R32; p2.w = 0.f;
    float4 p3; p3.x = g12 * R13; p3.y = g12 * R23; p3.z = g22 * R33; p3.w = 0.f;
    MPv[tid] = p1;
    MPv[900 + tid] = p2;
    MPv[1800 + tid] = p3;
  } else {
    #pragma unroll
    for (int ch = 0; ch < 3; ++ch) {
      int t = (tid - 900) + ch * 124;
      if (t < 270) {
        int st = t / 90, rem = t - st * 90;
        int k = rem / 30, s2 = rem - k * 30;
        const float* rL = (k == 0) ? r1L : (k == 1) ? r2L : r3L;
        const float* qp = qv + st * 32;
        float a = 0.f;
        #pragma unroll 8
        for (int r = 0; r < 32; ++r) a += rL[s2 * 36 + r] * qp[r];
        rqL[st * 90 + k * 30 + s2] = a;
      }
    }
  }
  __syncthreads();

  float n2 = 0.f;
  #pragma unroll
  for (int i = 0; i < 8; ++i) n2 += fn2p[i];
  float c0v = 1.f;

  auto prop = [&](const float* vsrc, int mbase) {
    float d1[4] = {0,0,0,0}, d2[4] = {0,0,0,0}, d3[4] = {0,0,0,0};
    if (act) {
      const float4* mrow = reinterpret_cast<const float4*>(MPL) + mbase + s * 30 + g * 15;
      const float* vb = vsrc + g * 15 * 68 + fq;
      #pragma unroll 5
      for (int i = 0; i < 15; ++i) {
        float4 m = mrow[i];
        float4 vv = *reinterpret_cast<const float4*>(vb + i * 68);
        d1[0]+=m.x*vv.x; d1[1]+=m.x*vv.y; d1[2]+=m.x*vv.z; d1[3]+=m.x*vv.w;
        d2[0]+=m.y*vv.x; d2[1]+=m.y*vv.y; d2[2]+=m.y*vv.z; d2[3]+=m.y*vv.w;
        d3[0]+=m.z*vv.x; d3[1]+=m.z*vv.y; d3[2]+=m.z*vv.z; d3[3]+=m.z*vv.w;
      }
    }
    #pragma unroll
    for (int j = 0; j < 4; ++j) {
      H1[j] += d1[j] + __shfl_xor(d1[j], 16);
      H2[j] += d2[j] + __shfl_xor(d2[j], 16);
      H3[j] += d3[j] + __shfl_xor(d3[j], 16);
    }
  };

  for (int layer = 0; layer < 3; ++layer) {
    float w[4], H2s[4], H3s[4], v1r[4], v2r[4], v3r[4];
    if (act) {
      float4 e2v = *reinterpret_cast<const float4*>(&e2L[s * 68 + fq]);
      w[0]=H1[0]; w[1]=H1[1]; w[2]=H1[2]; w[3]=H1[3];
      #pragma unroll
      for (int j = 0; j < 4; ++j) { H2s[j] = H2[j]; H3s[j] = H3[j]; }
      v1r[0] = e2v.x - H1[0]; v1r[1] = e2v.y - H1[1]; v1r[2] = e2v.z - H1[2]; v1r[3] = e2v.w - H1[3];
      if (g == 0) {
        float4 t; t.x=v1r[0]; t.y=v1r[1]; t.z=v1r[2]; t.w=v1r[3];
        *reinterpret_cast<float4*>(&v1L[s * 68 + fq]) = t;
      }
    }
    __syncthreads();
    prop(v1L, 0);
    if (act) {
      #pragma unroll
      for (int j = 0; j < 4; ++j) v2r[j] = w[j] - H2[j];
      if (g == 0) {
        float4 t; t.x=v2r[0]; t.y=v2r[1]; t.z=v2r[2]; t.w=v2r[3];
        *reinterpret_cast<float4*>(&v2L[s * 68 + fq]) = t;
      }
    }
    __syncthreads();
    prop(v2L, 900);
    if (act) {
      float4 e1v = *reinterpret_cast<const float4*>(&e1L[s * 68 + fq]);
      v3r[0] = e1v.x - H3[0]; v3r[1] = e1v.y - H3[1]; v3r[2] = e1v.z - H3[2]; v3r[3] = e1v.w - H3[3];
      if (g == 0) {
        float4 t; t.x=v3r[0]; t.y=v3r[1]; t.z=v3r[2]; t.w=v3r[3];
        *reinterpret_cast<float4*>(&v3L[s * 68 + fq]) = t;
      }
    }
    __syncthreads();
    prop(v3L, 1800);
    float local = 0.f;
    if (act) {
      #pragma unroll
      for (int j = 0; j < 4; ++j) { a1[j] += v1r[j]; a2[j] += v2r[j]; a3[j] += v3r[j]; }
      if (g == 0) {
        #pragma unroll
        for (int j = 0; j < 4; ++j)
          local += v1r[j] * (w[j] + H1[j]) + v2r[j] * (H2s[j] + H2[j]) + v3r[j] * (H3s[j] + H3[j]);
      }
    }
    local = wreduce64(local);
    if ((tid & 63) == 0) redL[tid >> 6] = local;
    __syncthreads();
    float tot = n2;
    #pragma unroll
    for (int i = 0; i < 16; ++i) tot += redL[i];
    float fn = fmaxf(sqrtf(tot), 1.f);
    float inv = 1.f / fn;
    n2 = tot * inv * inv;
    c0v *= inv;
    if (act) {
      #pragma unroll
      for (int j = 0; j < 4; ++j) { H1[j]*=inv; H2[j]*=inv; H3[j]*=inv; a1[j]*=inv; a2[j]*=inv; a3[j]*=inv; }
    }
  }

  // ---- inference ----
  if (act && g == 0) {
    float4 t1; t1.x=a1[0]; t1.y=a1[1]; t1.z=a1[2]; t1.w=a1[3];
    float4 t2; t2.x=a2[0]; t2.y=a2[1]; t2.z=a2[2]; t2.w=a2[3];
    float4 t3; t3.x=a3[0]; t3.y=a3[1]; t3.z=a3[2]; t3.w=a3[3];
    *reinterpret_cast<float4*>(&v1L[s * 68 + fq]) = t1;
    *reinterpret_cast<float4*>(&v2L[s * 68 + fq]) = t2;
    *reinterpret_cast<float4*>(&v3L[s * 68 + fq]) = t3;
  }
  if (tid < 64) { uv[tid] = qe1g[(size_t)b * 64 + tid]; siL[tid] = 0.f; }
  __syncthreads();
  float* partL = MPL + 4096;     // [16][64]
  int k32 = tid & 31;
  for (int st = 0; st < 3; ++st) {
    if (act) {
      float u0 = uv[k32], u1 = uv[k32 + 32];
      float eu1 = e1L[s * 68 + k32] * u0 + e1L[s * 68 + k32 + 32] * u1;
      float eu2 = e2L[s * 68 + k32] * u0 + e2L[s * 68 + k32 + 32] * u1;
      #pragma unroll
      for (int d = 16; d > 0; d >>= 1) {
        eu1 += __shfl_down(eu1, d, 32); eu2 += __shfl_down(eu2, d, 32);
      }
      if (k32 == 0) {
        alf[s]      = eu1 * rqL[st * 90 + s];
        alf[32 + s] = eu1 * rqL[st * 90 + 30 + s];
        alf[64 + s] = eu2 * rqL[st * 90 + 60 + s];
      }
    }
    __syncthreads();
    {
      int p = tid >> 6, f = tid & 63;
      float part = 0.f;
      if (p < 12) {
        int start = (p < 6) ? p * 3 : 18 + (p - 6) * 2;
        int cnt = (p < 6) ? 3 : 2;
        for (int q = 0; q < cnt; ++q) {
          int sp = start + q;
          part += alf[sp] * v1L[sp * 68 + f] + alf[32 + sp] * v2L[sp * 68 + f]
                + alf[64 + sp] * v3L[sp * 68 + f];
        }
      } else {
        int e0 = (p - 12) * 16;
        const float* Gp = Gg + (size_t)st * 1048576 + (size_t)b * 4096 + (size_t)e0 * 64 + f;
        float F = 0.f;
        #pragma unroll 4
        for (int e = 0; e < 16; ++e) F += uv[e0 + e] * Gp[e * 64];
        part = c0v * F;
      }
      partL[p * 64 + f] = part;
    }
    __syncthreads();
    if (tid < 64) {
      float raw = 0.f;
      #pragma unroll
      for (int p = 0; p < 16; ++p) raw += partL[p * 64 + tid];
      float mean = wreduce64(raw) * (1.f / 64.f);
      float d = raw - mean;
      float var = wreduce64(d * d) * (1.f / 63.f);
      float y = lng[st * 64 + tid] * d / (sqrtf(var) + 1e-6f) + lnb[st * 64 + tid];
      siL[tid] += y;
      uv[tid] = y;
    }
    __syncthreads();
  }
  if (tid < 9) {
    float o = 0.f;
    for (int ff = 0; ff < 64; ++ff) o += siL[ff] * Zg[ff * 9 + tid];
    out[(size_t)b * 9 + tid] = o;
  }
}

extern "C" void kernel_launch(void* const* d_in, const int* in_sizes, int n_in,
                              void* d_out, int out_size, void* d_ws, size_t ws_size,
                              hipStream_t stream) {
  const int*   story = (const int*)d_in[0];
  const int*   query = (const int*)d_in[1];
  const float* WE    = (const float*)d_in[2];
  const float* PE    = (const float*)d_in[3];
  const float* ueW1  = (const float*)d_in[4];
  const float* ueb1  = (const float*)d_in[5];
  const float* ueW2  = (const float*)d_in[6];
  const float* ueb2  = (const float*)d_in[7];
  const float* urW1  = (const float*)d_in[8];
  const float* urb1  = (const float*)d_in[9];
  const float* urW2  = (const float*)d_in[10];
  const float* urb2  = (const float*)d_in[11];
  const float* fwm   = (const float*)d_in[12];
  const float* ieW1  = (const float*)d_in[13];
  const float* ieb1  = (const float*)d_in[14];
  const float* ieW2  = (const float*)d_in[15];
  const float* ieb2  = (const float*)d_in[16];
  const float* irW1  = (const float*)d_in[17];
  const float* irb1  = (const float*)d_in[18];
  const float* irW2  = (const float*)d_in[19];
  const float* irb2  = (const float*)d_in[20];
  const float* lng   = (const float*)d_in[21];
  const float* lnb   = (const float*)d_in[22];
  const float* Z     = (const float*)d_in[23];
  float* W = (float*)d_ws;
  float* out = (float*)d_out;

  ushortT* sentB = (ushortT*)(W + OF_SENTB);
  ushortT* qembB = (ushortT*)(W + OF_QEMBB);
  ushortT* W1A   = (ushortT*)(W + OF_W1A);
  ushortT* W2TE  = (ushortT*)(W + OF_W2TE);
  ushortT* W2TR  = (ushortT*)(W + OF_W2TR);
  ushortT* fwmBT = (ushortT*)(W + OF_FWMB);

  prep_k<<<4232, 256, 0, stream>>>(story, query, WE, PE,
      ueW1, urW1, ieW1, irW1, ueW2, urW2, ieW2, irW2, fwm,
      sentB, qembB, W1A, W2TE, W2TR, fwmBT, W + OF_FN2);

  mlpm_k<<<dim3(240, 9), 256, 0, stream>>>(sentB, qembB, W1A,
      ueb1, urb1, ieb1, irb1, W2TE, W2TR, ueb2, urb2, ieb2, irb2,
      W + OF_E1, W + OF_R1, W + OF_QE1, W + OF_QR1);

  pstage_k<<<736, 256, 0, stream>>>(fwmBT, W + OF_E1, W + OF_E1 + 491520,
      W + OF_R1, W + OF_R1 + 245760, W + OF_R1 + 2 * 245760,
      W + OF_QR1, W + OF_QR1 + 8192, W + OF_QR1 + 16384,
      W + OF_PP, W + OF_G);

  scan_k<<<NB, 1024, 0, stream>>>(W + OF_PP, W + OF_G,
      W + OF_E1, W + OF_E1 + 491520,
      W + OF_R1, W + OF_R1 + 245760, W + OF_R1 + 2 * 245760,
      W + OF_QE1, W + OF_QR1, W + OF_QR1 + 8192, W + OF_QR1 + 16384,
      W + OF_FN2, lng, lnb, Z, out);
}

// Round 14
// 115.086 us; speedup vs baseline: 6.4751x; 1.1418x over previous
//
#include <hip/hip_runtime.h>
#include <hip/hip_bf16.h>

// Sizes
#define NB 256
#define NS 30
#define NW 10
#define SYM 128
#define HID 512
#define ENT 64
#define ROLE 32

typedef unsigned short ushortT;
typedef __attribute__((ext_vector_type(8))) short short8v;   // 8 bf16
typedef __attribute__((ext_vector_type(4))) float f32x4;

// Workspace offsets (floats; bf16 arrays use 2 elems per float slot)
static const size_t OF_SENTB = 0;         // 7680*128 bf16 -> 491520 fl
static const size_t OF_QEMBB = 491520;    // 256*128 bf16 -> 16384 fl
static const size_t OF_W1A   = 507904;    // 9*512*128 bf16 -> 294912 fl
static const size_t OF_W2TE  = 802816;    // 3*64*512 bf16 -> 49152 fl
static const size_t OF_W2TR  = 851968;    // 6*32*512 bf16 -> 49152 fl
static const size_t OF_FWMB  = 901120;    // 64*2048 bf16 -> 65536 fl  (fwm^T [f][e*32+r])
static const size_t OF_E1    = 966656;    // 7680*64 x2 (stride 491520)
static const size_t OF_R1    = 1949696;   // 7680*32 x3 (stride 245760)
static const size_t OF_QE1   = 2686976;   // 256*64
static const size_t OF_QR1   = 2703360;   // 256*32 x3 (stride 8192)
static const size_t OF_PP    = 2727936;   // 3 * 7680*64 = 1,474,560
static const size_t OF_FN2   = 4202496;   // 8 partials
static const size_t OF_G     = 4202624;   // 3*256*64*64 = 3,145,728

__device__ __forceinline__ ushortT f2bf(float x) {
  unsigned u = __float_as_uint(x);
  unsigned r = (u + 0x7fffu + ((u >> 16) & 1u)) >> 16;
  return (ushortT)r;
}
__device__ __forceinline__ float bf2f(ushortT h) {
  return __uint_as_float((unsigned)h << 16);
}
__device__ __forceinline__ float ftanh(float x) {
  float t = __expf(2.f * x);
  return 1.f - 2.f * __builtin_amdgcn_rcpf(t + 1.f);
}
__device__ __forceinline__ float dot4(const float4& a, const float4& b) {
  return a.x * b.x + a.y * b.y + a.z * b.z + a.w * b.w;
}
__device__ __forceinline__ float wreduce64(float v) {
  #pragma unroll
  for (int o = 32; o > 0; o >>= 1) v += __shfl_xor(v, o);
  return v;
}

// ---------------- unified prep: embed + all transposes/converts + fnorm partials ----------------
__global__ __launch_bounds__(256) void prep_k(
    const int* __restrict__ story, const int* __restrict__ query,
    const float* __restrict__ WE, const float* __restrict__ PE,
    const float* __restrict__ ueW1, const float* __restrict__ urW1,
    const float* __restrict__ ieW1, const float* __restrict__ irW1,
    const float* __restrict__ ueW2, const float* __restrict__ urW2,
    const float* __restrict__ ieW2, const float* __restrict__ irW2,
    const float* __restrict__ fwm,
    ushortT* __restrict__ sentb, ushortT* __restrict__ qembb,
    ushortT* __restrict__ W1A, ushortT* __restrict__ W2TE,
    ushortT* __restrict__ W2TR, ushortT* __restrict__ fwmBT,
    float* __restrict__ fn2) {
  __shared__ float tl[64 * 65];
  __shared__ float red[4];
  int bx = blockIdx.x, tid = threadIdx.x;
  if (bx < 3968) {
    int row = bx * 2 + (tid >> 7);
    int e = tid & 127;
    const int* idx; ushortT* dst;
    if (row < 7680) { idx = story + (size_t)row * NW; dst = sentb + (size_t)row * SYM; }
    else            { idx = query + (size_t)(row - 7680) * NW; dst = qembb + (size_t)(row - 7680) * SYM; }
    float acc = 0.f;
    #pragma unroll
    for (int w = 0; w < NW; ++w) acc += WE[idx[w] * SYM + e] * PE[w * SYM + e];
    dst[e] = f2bf(acc);
    return;
  }
  bx -= 3968;
  const float* src; ushortT* dst; int R, C, tr0, tc0;
  if (bx < 144) {
    int h = bx >> 4, t = bx & 15;
    src = (h < 2) ? ueW1 + (size_t)h * 65536 : (h < 5) ? urW1 + (size_t)(h - 2) * 65536
        : (h == 5) ? ieW1 : irW1 + (size_t)(h - 6) * 65536;
    dst = W1A + (size_t)h * 65536;
    R = 128; C = 512; tr0 = (t >> 3) * 64; tc0 = (t & 7) * 64;
  } else if (bx < 168) {
    int h = (bx - 144) >> 3, t = (bx - 144) & 7;
    src = (h < 2) ? ueW2 + (size_t)h * 32768 : ieW2;
    dst = W2TE + (size_t)h * 32768;
    R = 512; C = 64; tr0 = t * 64; tc0 = 0;
  } else if (bx < 216) {
    int h = (bx - 168) >> 3, t = (bx - 168) & 7;
    src = (h < 3) ? urW2 + (size_t)h * 16384 : irW2 + (size_t)(h - 3) * 16384;
    dst = W2TR + (size_t)h * 16384;
    R = 512; C = 32; tr0 = t * 64; tc0 = 0;
  } else if (bx < 248) {
    int t = bx - 216;
    src = fwm; dst = fwmBT; R = 2048; C = 64; tr0 = t * 64; tc0 = 0;
  } else {
    int blk = bx - 248;
    const float4* f4 = reinterpret_cast<const float4*>(fwm) + blk * 4096;
    float a = 0.f;
    for (int i = tid; i < 4096; i += 256) {
      float4 v = f4[i];
      a += v.x*v.x + v.y*v.y + v.z*v.z + v.w*v.w;
    }
    a = wreduce64(a);
    if ((tid & 63) == 0) red[tid >> 6] = a;
    __syncthreads();
    if (tid == 0) fn2[blk] = red[0] + red[1] + red[2] + red[3];
    return;
  }
  int TC = (C < 64) ? C : 64;
  int n = 64 * TC;
  for (int i = tid; i < n; i += 256) {
    int r = i / TC, c = i % TC;
    tl[r * 65 + c] = src[(size_t)(tr0 + r) * C + tc0 + c];
  }
  __syncthreads();
  for (int i = tid; i < n; i += 256) {
    int c = i >> 6, r = i & 63;
    dst[(size_t)(tc0 + c) * R + tr0 + r] = f2bf(tl[r * 65 + c]);
  }
}

// ---------------- MFMA fused 2-layer MLP ----------------
__global__ __launch_bounds__(256, 4) void mlpm_k(
    const ushortT* __restrict__ sentB, const ushortT* __restrict__ qembB,
    const ushortT* __restrict__ W1A,
    const float* __restrict__ ueb1, const float* __restrict__ urb1,
    const float* __restrict__ ieb1, const float* __restrict__ irb1,
    const ushortT* __restrict__ W2TE, const ushortT* __restrict__ W2TR,
    const float* __restrict__ ueb2, const float* __restrict__ urb2,
    const float* __restrict__ ieb2, const float* __restrict__ irb2,
    float* __restrict__ E1, float* __restrict__ R1,
    float* __restrict__ QE1, float* __restrict__ QR1) {
  __shared__ __align__(16) ushortT Hl[32 * 520];
  int y = blockIdx.y;
  bool isQ = y >= 5;
  if (isQ && blockIdx.x >= 8) return;
  int r0 = blockIdx.x * 32, tid = threadIdx.x;
  int wave = tid >> 6, lane = tid & 63;
  int lrow = lane & 15;
  int kgrp = lane >> 4;
  const ushortT* Xb = isQ ? qembB : sentB;
  const ushortT* W1h = W1A + (size_t)y * 65536;
  const float* b1 = (y < 2) ? ueb1 + y * 512 : (y < 5) ? urb1 + (y - 2) * 512
                  : (y == 5) ? ieb1 : irb1 + (y - 6) * 512;
  bool isE = (y < 2) || (y == 5);

  int cw = wave * 128;

  short8v afr[2][4];
  #pragma unroll
  for (int rt = 0; rt < 2; ++rt) {
    const ushortT* arow = Xb + (size_t)(r0 + rt * 16 + lrow) * 128 + kgrp * 8;
    #pragma unroll
    for (int kt = 0; kt < 4; ++kt)
      afr[rt][kt] = *reinterpret_cast<const short8v*>(arow + kt * 32);
  }

  #pragma unroll
  for (int ct = 0; ct < 8; ++ct) {
    int c0 = cw + ct * 16;
    const ushortT* bcol = W1h + (size_t)(c0 + lrow) * 128 + kgrp * 8;
    short8v bf0 = *reinterpret_cast<const short8v*>(bcol);
    short8v bf1 = *reinterpret_cast<const short8v*>(bcol + 32);
    short8v bf2 = *reinterpret_cast<const short8v*>(bcol + 64);
    short8v bf3 = *reinterpret_cast<const short8v*>(bcol + 96);
    f32x4 aA[2] = {{0.f,0.f,0.f,0.f},{0.f,0.f,0.f,0.f}};
    f32x4 aB[2] = {{0.f,0.f,0.f,0.f},{0.f,0.f,0.f,0.f}};
    #pragma unroll
    for (int rt = 0; rt < 2; ++rt) {
      aA[rt] = __builtin_amdgcn_mfma_f32_16x16x32_bf16(afr[rt][0], bf0, aA[rt], 0, 0, 0);
      aB[rt] = __builtin_amdgcn_mfma_f32_16x16x32_bf16(afr[rt][1], bf1, aB[rt], 0, 0, 0);
      aA[rt] = __builtin_amdgcn_mfma_f32_16x16x32_bf16(afr[rt][2], bf2, aA[rt], 0, 0, 0);
      aB[rt] = __builtin_amdgcn_mfma_f32_16x16x32_bf16(afr[rt][3], bf3, aB[rt], 0, 0, 0);
    }
    int lcol = c0 + lrow;
    float bb = b1[lcol];
    #pragma unroll
    for (int rt = 0; rt < 2; ++rt)
      #pragma unroll
      for (int i = 0; i < 4; ++i) {
        float hv = ftanh(aA[rt][i] + aB[rt][i] + bb);
        Hl[(rt * 16 + kgrp * 4 + i) * 520 + lcol] = f2bf(hv);
      }
  }
  __syncthreads();

  if (isE) {
    int slot = (y == 5) ? 2 : y;
    const ushortT* W2h = W2TE + (size_t)slot * 32768;
    const float* b2 = (y == 5) ? ieb2 : ueb2 + y * 64;
    float* Out = (y == 5) ? QE1 : E1 + (size_t)y * 491520;
    int rt = wave >> 1, cb = (wave & 1) * 32;
    f32x4 accA[2] = {{0.f,0.f,0.f,0.f},{0.f,0.f,0.f,0.f}};
    f32x4 accB[2] = {{0.f,0.f,0.f,0.f},{0.f,0.f,0.f,0.f}};
    #pragma unroll
    for (int kt = 0; kt < 16; kt += 2) {
      int kb0 = kt * 32 + kgrp * 8;
      int kb1 = kb0 + 32;
      short8v a0 = *reinterpret_cast<const short8v*>(&Hl[(rt * 16 + lrow) * 520 + kb0]);
      short8v a1 = *reinterpret_cast<const short8v*>(&Hl[(rt * 16 + lrow) * 520 + kb1]);
      #pragma unroll
      for (int t = 0; t < 2; ++t) {
        const ushortT* wc = W2h + (size_t)(cb + t * 16 + lrow) * 512;
        short8v b0 = *reinterpret_cast<const short8v*>(wc + kb0);
        short8v b1v = *reinterpret_cast<const short8v*>(wc + kb1);
        accA[t] = __builtin_amdgcn_mfma_f32_16x16x32_bf16(a0, b0, accA[t], 0, 0, 0);
        accB[t] = __builtin_amdgcn_mfma_f32_16x16x32_bf16(a1, b1v, accB[t], 0, 0, 0);
      }
    }
    #pragma unroll
    for (int t = 0; t < 2; ++t) {
      int col = cb + t * 16 + lrow;
      float bb = b2[col];
      #pragma unroll
      for (int i = 0; i < 4; ++i) {
        int grow = r0 + rt * 16 + kgrp * 4 + i;
        Out[(size_t)grow * 64 + col] = ftanh(accA[t][i] + accB[t][i] + bb);
      }
    }
  } else {
    int slot = (y < 5) ? (y - 2) : (3 + y - 6);
    const ushortT* W2h = W2TR + (size_t)slot * 16384;
    const float* b2 = (y < 5) ? urb2 + (y - 2) * 32 : irb2 + (y - 6) * 32;
    float* Out = (y < 5) ? R1 + (size_t)(y - 2) * 245760 : QR1 + (size_t)(y - 6) * 8192;
    int rt = wave >> 1, cb = (wave & 1) * 16;
    f32x4 accA = {0.f, 0.f, 0.f, 0.f}, accB = {0.f, 0.f, 0.f, 0.f};
    const ushortT* wc = W2h + (size_t)(cb + lrow) * 512;
    #pragma unroll
    for (int kt = 0; kt < 16; kt += 2) {
      int kb0 = kt * 32 + kgrp * 8;
      int kb1 = kb0 + 32;
      short8v a0 = *reinterpret_cast<const short8v*>(&Hl[(rt * 16 + lrow) * 520 + kb0]);
      short8v a1 = *reinterpret_cast<const short8v*>(&Hl[(rt * 16 + lrow) * 520 + kb1]);
      short8v b0 = *reinterpret_cast<const short8v*>(wc + kb0);
      short8v b1v = *reinterpret_cast<const short8v*>(wc + kb1);
      accA = __builtin_amdgcn_mfma_f32_16x16x32_bf16(a0, b0, accA, 0, 0, 0);
      accB = __builtin_amdgcn_mfma_f32_16x16x32_bf16(a1, b1v, accB, 0, 0, 0);
    }
    int col = cb + lrow;
    float bb = b2[col];
    #pragma unroll
    for (int i = 0; i < 4; ++i) {
      int grow = r0 + rt * 16 + kgrp * 4 + i;
      Out[(size_t)grow * 32 + col] = ftanh(accA[i] + accB[i] + bb);
    }
  }
}

// ---------------- MFMA P-stage (bx<480) + G-stage (bx>=480) ----------------
__global__ __launch_bounds__(256) void pstage_k(const ushortT* __restrict__ fwmBT,
    const float* __restrict__ e1g, const float* __restrict__ e2g,
    const float* __restrict__ r1g, const float* __restrict__ r2g, const float* __restrict__ r3g,
    const float* __restrict__ qr1g, const float* __restrict__ qr2g, const float* __restrict__ qr3g,
    float* __restrict__ Pp, float* __restrict__ Gg) {
  __shared__ __align__(16) float e1t[16 * 68], e2t[16 * 68];
  int bx = blockIdx.x, tid = threadIdx.x;
  int wave = tid >> 6, lane = tid & 63;
  int c = lane & 15, kg = lane >> 4;
  int f0 = wave * 16;
  const f32x4 zero = {0,0,0,0};

  if (bx >= 480) {
    int b = bx - 480;
    short8v qa = {0,0,0,0,0,0,0,0};
    if (c < 3) {
      const float* qr = ((c == 0) ? qr1g : (c == 1) ? qr2g : qr3g) + (size_t)b * 32 + kg * 8;
      ushortT* p = (ushortT*)&qa;
      #pragma unroll
      for (int j = 0; j < 8; ++j) p[j] = f2bf(qr[j]);
    }
    const ushortT* bbase = fwmBT + (size_t)(f0 + c) * 2048 + kg * 8;
    float* g0 = Gg + (size_t)b * 4096 + f0 + c;
    for (int e = 0; e < 64; ++e) {
      short8v B = *reinterpret_cast<const short8v*>(bbase + (size_t)e * 32);
      f32x4 T = __builtin_amdgcn_mfma_f32_16x16x32_bf16(qa, B, zero, 0, 0, 0);
      if (kg == 0) {
        g0[e * 64]           = T[0];
        g0[1048576 + e * 64] = T[1];
        g0[2097152 + e * 64] = T[2];
      }
    }
    return;
  }

  int rb = bx;
  {
    int row = tid >> 4, c4 = tid & 15;
    float4 v1 = *reinterpret_cast<const float4*>(e1g + ((size_t)rb * 16 + row) * 64 + c4 * 4);
    float4 v2 = *reinterpret_cast<const float4*>(e2g + ((size_t)rb * 16 + row) * 64 + c4 * 4);
    *reinterpret_cast<float4*>(&e1t[row * 68 + c4 * 4]) = v1;
    *reinterpret_cast<float4*>(&e2t[row * 68 + c4 * 4]) = v2;
  }
  size_t rbase = ((size_t)rb * 16 + c) * 32 + kg * 8;
  short8v rA, rB, rC;
  {
    float4 x0 = *reinterpret_cast<const float4*>(r1g + rbase);
    float4 x1 = *reinterpret_cast<const float4*>(r1g + rbase + 4);
    ushortT* p = (ushortT*)&rA;
    p[0]=f2bf(x0.x); p[1]=f2bf(x0.y); p[2]=f2bf(x0.z); p[3]=f2bf(x0.w);
    p[4]=f2bf(x1.x); p[5]=f2bf(x1.y); p[6]=f2bf(x1.z); p[7]=f2bf(x1.w);
    x0 = *reinterpret_cast<const float4*>(r2g + rbase);
    x1 = *reinterpret_cast<const float4*>(r2g + rbase + 4);
    p = (ushortT*)&rB;
    p[0]=f2bf(x0.x); p[1]=f2bf(x0.y); p[2]=f2bf(x0.z); p[3]=f2bf(x0.w);
    p[4]=f2bf(x1.x); p[5]=f2bf(x1.y); p[6]=f2bf(x1.z); p[7]=f2bf(x1.w);
    x0 = *reinterpret_cast<const float4*>(r3g + rbase);
    x1 = *reinterpret_cast<const float4*>(r3g + rbase + 4);
    p = (ushortT*)&rC;
    p[0]=f2bf(x0.x); p[1]=f2bf(x0.y); p[2]=f2bf(x0.z); p[3]=f2bf(x0.w);
    p[4]=f2bf(x1.x); p[5]=f2bf(x1.y); p[6]=f2bf(x1.z); p[7]=f2bf(x1.w);
  }
  __syncthreads();
  const ushortT* bbase = fwmBT + (size_t)(f0 + c) * 2048 + kg * 8;
  f32x4 P1 = {0,0,0,0}, P2 = {0,0,0,0}, P3 = {0,0,0,0};
  int r0 = kg * 4;
  for (int e4 = 0; e4 < 16; ++e4) {
    float4 ea[4], eb[4];
    #pragma unroll
    for (int i = 0; i < 4; ++i) {
      ea[i] = *reinterpret_cast<const float4*>(&e1t[(r0 + i) * 68 + e4 * 4]);
      eb[i] = *reinterpret_cast<const float4*>(&e2t[(r0 + i) * 68 + e4 * 4]);
    }
    #pragma unroll
    for (int sub = 0; sub < 4; ++sub) {
      int e = e4 * 4 + sub;
      short8v B = *reinterpret_cast<const short8v*>(bbase + (size_t)e * 32);
      f32x4 T1 = __builtin_amdgcn_mfma_f32_16x16x32_bf16(rA, B, zero, 0, 0, 0);
      f32x4 T2 = __builtin_amdgcn_mfma_f32_16x16x32_bf16(rB, B, zero, 0, 0, 0);
      f32x4 T3 = __builtin_amdgcn_mfma_f32_16x16x32_bf16(rC, B, zero, 0, 0, 0);
      #pragma unroll
      for (int i = 0; i < 4; ++i) {
        float e1v = reinterpret_cast<const float*>(&ea[i])[sub];
        float e2v = reinterpret_cast<const float*>(&eb[i])[sub];
        P1[i] += e1v * T1[i];
        P2[i] += e1v * T2[i];
        P3[i] += e2v * T3[i];
      }
    }
  }
  #pragma unroll
  for (int i = 0; i < 4; ++i) {
    size_t row = (size_t)rb * 16 + kg * 4 + i;
    Pp[row * 64 + f0 + c]               = P1[i];
    Pp[491520 + row * 64 + f0 + c]      = P2[i];
    Pp[2 * 491520 + row * 64 + f0 + c]  = P3[i];
  }
}

// ---------------- scan: gram(bf16 hi/lo M) + MFMA propagation + inference ----------------
__global__ __launch_bounds__(1024) void scan_k(
    const float* __restrict__ Pp, const float* __restrict__ Gg,
    const float* __restrict__ e1g, const float* __restrict__ e2g,
    const float* __restrict__ r1g, const float* __restrict__ r2g, const float* __restrict__ r3g,
    const float* __restrict__ qe1g, const float* __restrict__ qr1g, const float* __restrict__ qr2g,
    const float* __restrict__ qr3g, const float* __restrict__ fn2p,
    const float* __restrict__ lng, const float* __restrict__ lnb, const float* __restrict__ Zg,
    float* __restrict__ out) {
  __shared__ __align__(16) ushortT MBs[2][9][1280];     // [hi/lo][ph*3+kk][row*40+col] bf16 M
  __shared__ __align__(16) ushortT vTb[2][2][2560];     // [buf][hi/lo][f*40+sp]
  __shared__ float wLx[2048];                            // w relay [slot][lane*8+..]
  __shared__ float partBuf[1024];
  __shared__ __align__(16) float e1L[2040], e2L[2040];  // [30][68]
  __shared__ __align__(16) float v1L[2040], v2L[2040], v3L[2040];
  __shared__ __align__(16) float r1L[1080], r2L[1080], r3L[1080];  // [30][36]
  __shared__ float uv[64], qv[96], alf[96], siL[64], rqL[272];
  __shared__ float redL[16];
  int b = blockIdx.x, tid = threadIdx.x;
  int wave = tid >> 6, lane = tid & 63;
  int col = lane & 15, kgrp = lane >> 4;
  bool wact = wave < 12;
  int kk = wave >> 2, idx = wave & 3, st = idx >> 1, fp = idx & 1;

  // ---- staging ----
  for (int i = tid; i < 1680; i += 1024) {
    if (i < 480) {
      int ss = i >> 4, c4 = i & 15;
      *reinterpret_cast<float4*>(&e1L[ss * 68 + c4 * 4]) =
          *reinterpret_cast<const float4*>(e1g + (size_t)b * 1920 + i * 4);
    } else if (i < 960) {
      int j = i - 480;
      int ss = j >> 4, c4 = j & 15;
      *reinterpret_cast<float4*>(&e2L[ss * 68 + c4 * 4]) =
          *reinterpret_cast<const float4*>(e2g + (size_t)b * 1920 + j * 4);
    } else {
      int j = i - 960;
      int which = j / 240, jj = j - which * 240;
      int ss = jj >> 3, c4 = jj & 7;
      float* dstL = (which == 0) ? r1L : (which == 1) ? r2L : r3L;
      const float* srcG = (which == 0) ? r1g : (which == 1) ? r2g : r3g;
      *reinterpret_cast<float4*>(&dstL[ss * 36 + c4 * 4]) =
          *reinterpret_cast<const float4*>(srcG + (size_t)b * 960 + jj * 4);
    }
  }
  if (tid >= 128 && tid < 224) {
    int t = tid - 128, sst = t >> 5, k = t & 31;
    const float* qrg = (sst == 0) ? qr1g : ((sst == 1) ? qr2g : qr3g);
    qv[t] = qrg[(size_t)b * 32 + k];
  }
  // MB pad zero: rows 0..31 cols 30..39 (320) + rows 30..31 cols 0..39 (80) per matrix-half
  for (int i = tid; i < 7200; i += 1024) {
    int m = i / 400, rr = i - m * 400;
    int hl = m / 9, mat = m - hl * 9;
    int r, c;
    if (rr < 320) { r = rr / 10; c = 30 + rr % 10; }
    else { int q = rr - 320; r = 30 + q / 40; c = q % 40; }
    MBs[hl][mat][r * 40 + c] = 0;
  }
  // H-frag init from Pp (global loads)
  f32x4 Ht[2] = {{0.f,0.f,0.f,0.f},{0.f,0.f,0.f,0.f}};
  float aT[2][4] = {{0,0,0,0},{0,0,0,0}};
  if (wact) {
    #pragma unroll
    for (int t = 0; t < 2; ++t)
      #pragma unroll
      for (int i = 0; i < 4; ++i) {
        int srow = st * 16 + kgrp * 4 + i;
        int f = (fp * 2 + t) * 16 + col;
        Ht[t][i] = (srow < 30) ? Pp[(size_t)kk * 491520 + (size_t)b * 1920 + srow * 64 + f] : 0.f;
      }
  }
  __syncthreads();

  // ---- gram -> bf16 hi/lo M ; rqL ----
  if (tid < 900) {
    int si = tid / 30, sj = tid - si * 30;
    float g11 = 0, g12 = 0, g21 = 0, g22 = 0;
    {
      const float4* A1 = reinterpret_cast<const float4*>(&e1L[si * 68]);
      const float4* A2 = reinterpret_cast<const float4*>(&e2L[si * 68]);
      const float4* C1 = reinterpret_cast<const float4*>(&e1L[sj * 68]);
      const float4* C2 = reinterpret_cast<const float4*>(&e2L[sj * 68]);
      #pragma unroll 4
      for (int i = 0; i < 16; ++i) {
        float4 a1v = A1[i], a2v = A2[i], c1v = C1[i], c2v = C2[i];
        g11 += dot4(a1v, c1v); g12 += dot4(a1v, c2v);
        g21 += dot4(a2v, c1v); g22 += dot4(a2v, c2v);
      }
    }
    float R11=0,R12=0,R13=0,R21=0,R22=0,R23=0,R31=0,R32=0,R33=0;
    {
      const float4* X1 = reinterpret_cast<const float4*>(&r1L[si * 36]);
      const float4* X2 = reinterpret_cast<const float4*>(&r2L[si * 36]);
      const float4* X3 = reinterpret_cast<const float4*>(&r3L[si * 36]);
      const float4* Y1 = reinterpret_cast<const float4*>(&r1L[sj * 36]);
      const float4* Y2 = reinterpret_cast<const float4*>(&r2L[sj * 36]);
      const float4* Y3 = reinterpret_cast<const float4*>(&r3L[sj * 36]);
      #pragma unroll 4
      for (int i = 0; i < 8; ++i) {
        float4 x1 = X1[i], x2 = X2[i], x3 = X3[i];
        float4 y1 = Y1[i], y2 = Y2[i], y3 = Y3[i];
        R11 += dot4(x1, y1); R12 += dot4(x1, y2); R13 += dot4(x1, y3);
        R21 += dot4(x2, y1); R22 += dot4(x2, y2); R23 += dot4(x2, y3);
        R31 += dot4(x3, y1); R32 += dot4(x3, y2); R33 += dot4(x3, y3);
      }
    }
    float vals[9];
    vals[0] = g11 * R11; vals[1] = g11 * R21; vals[2] = g21 * R31;   // ph0 -> H1,H2,H3
    vals[3] = g11 * R12; vals[4] = g11 * R22; vals[5] = g21 * R32;   // ph1
    vals[6] = g12 * R13; vals[7] = g12 * R23; vals[8] = g22 * R33;   // ph2
    int o = si * 40 + sj;
    #pragma unroll
    for (int m = 0; m < 9; ++m) {
      ushortT hi = f2bf(vals[m]);
      float res = vals[m] - bf2f(hi);
      MBs[0][m][o] = hi;
      MBs[1][m][o] = f2bf(res);
    }
  } else {
    #pragma unroll
    for (int ch = 0; ch < 3; ++ch) {
      int t = (tid - 900) + ch * 124;
      if (t < 270) {
        int sst = t / 90, rem = t - sst * 90;
        int k = rem / 30, s2 = rem - k * 30;
        const float* rL = (k == 0) ? r1L : (k == 1) ? r2L : r3L;
        const float* qp = qv + sst * 32;
        float a = 0.f;
        #pragma unroll 8
        for (int r = 0; r < 32; ++r) a += rL[s2 * 36 + r] * qp[r];
        rqL[sst * 90 + k * 30 + s2] = a;
      }
    }
  }
  // eP preload (e-arrays ready since BAR1)
  float eP[2][4] = {{0,0,0,0},{0,0,0,0}};
  if (wact && kk != 1) {
    const float* eSrc = (kk == 0) ? e2L : e1L;
    #pragma unroll
    for (int t = 0; t < 2; ++t)
      #pragma unroll
      for (int i = 0; i < 4; ++i) {
        int srow = st * 16 + kgrp * 4 + i;
        if (srow < 30) eP[t][i] = eSrc[srow * 68 + (fp * 2 + t) * 16 + col];
      }
  }
  __syncthreads();

  // ---- A-fragment preload (M constant across layers) ----
  short8v Ah0, Al0, Ah1, Al1, Ah2, Al2;
  if (wact) {
    int ao = (st * 16 + col) * 40 + kgrp * 8;
    Ah0 = *reinterpret_cast<const short8v*>(&MBs[0][kk][ao]);
    Al0 = *reinterpret_cast<const short8v*>(&MBs[1][kk][ao]);
    Ah1 = *reinterpret_cast<const short8v*>(&MBs[0][3 + kk][ao]);
    Al1 = *reinterpret_cast<const short8v*>(&MBs[1][3 + kk][ao]);
    Ah2 = *reinterpret_cast<const short8v*>(&MBs[0][6 + kk][ao]);
    Al2 = *reinterpret_cast<const short8v*>(&MBs[1][6 + kk][ao]);
  }

  float n2 = 0.f;
  #pragma unroll
  for (int i = 0; i < 8; ++i) n2 += fn2p[i];
  float c0v = 1.f;

  float sav[2][4], vr[2][4];
  auto vWrite = [&](int bsel) {
    #pragma unroll
    for (int t = 0; t < 2; ++t) {
      ushortT h0 = f2bf(vr[t][0]), h1 = f2bf(vr[t][1]), h2 = f2bf(vr[t][2]), h3 = f2bf(vr[t][3]);
      float r0 = vr[t][0] - bf2f(h0), r1 = vr[t][1] - bf2f(h1);
      float r2 = vr[t][2] - bf2f(h2), r3 = vr[t][3] - bf2f(h3);
      uint2 hw, lw;
      hw.x = (unsigned)h0 | ((unsigned)h1 << 16);
      hw.y = (unsigned)h2 | ((unsigned)h3 << 16);
      lw.x = (unsigned)f2bf(r0) | ((unsigned)f2bf(r1) << 16);
      lw.y = (unsigned)f2bf(r2) | ((unsigned)f2bf(r3) << 16);
      int off = ((fp * 2 + t) * 16 + col) * 40 + st * 16 + kgrp * 4;
      *reinterpret_cast<uint2*>(&vTb[bsel][0][off]) = hw;
      *reinterpret_cast<uint2*>(&vTb[bsel][1][off]) = lw;
    }
  };
  auto mfmaPh = [&](int bsel, short8v AH, short8v AL) {
    if (wact) {
      #pragma unroll
      for (int t = 0; t < 2; ++t) {
        int off = ((fp * 2 + t) * 16 + col) * 40 + kgrp * 8;
        short8v Bh = *reinterpret_cast<const short8v*>(&vTb[bsel][0][off]);
        short8v Bl = *reinterpret_cast<const short8v*>(&vTb[bsel][1][off]);
        Ht[t] = __builtin_amdgcn_mfma_f32_16x16x32_bf16(AH, Bh, Ht[t], 0, 0, 0);
        Ht[t] = __builtin_amdgcn_mfma_f32_16x16x32_bf16(AH, Bl, Ht[t], 0, 0, 0);
        Ht[t] = __builtin_amdgcn_mfma_f32_16x16x32_bf16(AL, Bh, Ht[t], 0, 0, 0);
      }
    }
  };

  int buf = 0;
  for (int layer = 0; layer < 3; ++layer) {
    if (wact) {
      #pragma unroll
      for (int t = 0; t < 2; ++t)
        #pragma unroll
        for (int i = 0; i < 4; ++i) { sav[t][i] = Ht[t][i]; vr[t][i] = 0.f; }
      if (kk == 0) {
        int base = idx * 512 + lane * 8;
        #pragma unroll
        for (int t = 0; t < 2; ++t)
          #pragma unroll
          for (int i = 0; i < 4; ++i) wLx[base + t * 4 + i] = Ht[t][i];
      }
    }
    // phase 0: v1 = e2 - H1 (k=0)
    if (wact && kk == 0) {
      #pragma unroll
      for (int t = 0; t < 2; ++t)
        #pragma unroll
        for (int i = 0; i < 4; ++i) {
          int srow = st * 16 + kgrp * 4 + i;
          vr[t][i] = (srow < 30) ? (eP[t][i] - Ht[t][i]) : 0.f;
        }
      vWrite(buf);
    }
    __syncthreads();
    mfmaPh(buf, Ah0, Al0);
    buf ^= 1;
    if (wact && kk == 0) {
      #pragma unroll
      for (int t = 0; t < 2; ++t)
        #pragma unroll
        for (int i = 0; i < 4; ++i) aT[t][i] += vr[t][i];
    }
    // phase 1: v2 = w - H2 (k=1)
    if (wact && kk == 1) {
      int base = idx * 512 + lane * 8;
      #pragma unroll
      for (int t = 0; t < 2; ++t)
        #pragma unroll
        for (int i = 0; i < 4; ++i) {
          int srow = st * 16 + kgrp * 4 + i;
          vr[t][i] = (srow < 30) ? (wLx[base + t * 4 + i] - Ht[t][i]) : 0.f;
        }
      vWrite(buf);
    }
    __syncthreads();
    mfmaPh(buf, Ah1, Al1);
    buf ^= 1;
    if (wact && kk == 1) {
      #pragma unroll
      for (int t = 0; t < 2; ++t)
        #pragma unroll
        for (int i = 0; i < 4; ++i) aT[t][i] += vr[t][i];
    }
    // phase 2: v3 = e1 - H3 (k=2)
    if (wact && kk == 2) {
      #pragma unroll
      for (int t = 0; t < 2; ++t)
        #pragma unroll
        for (int i = 0; i < 4; ++i) {
          int srow = st * 16 + kgrp * 4 + i;
          vr[t][i] = (srow < 30) ? (eP[t][i] - Ht[t][i]) : 0.f;
        }
      vWrite(buf);
    }
    __syncthreads();
    mfmaPh(buf, Ah2, Al2);
    buf ^= 1;
    if (wact && kk == 2) {
      #pragma unroll
      for (int t = 0; t < 2; ++t)
        #pragma unroll
        for (int i = 0; i < 4; ++i) aT[t][i] += vr[t][i];
    }
    // norm: local = vr . (sav + H_end), uniform across k
    float local = 0.f;
    if (wact) {
      #pragma unroll
      for (int t = 0; t < 2; ++t)
        #pragma unroll
        for (int i = 0; i < 4; ++i) {
          int srow = st * 16 + kgrp * 4 + i;
          if (srow < 30) local += vr[t][i] * (sav[t][i] + Ht[t][i]);
        }
    }
    local = wreduce64(local);
    if ((tid & 63) == 0) redL[tid >> 6] = local;
    __syncthreads();
    float tot = n2;
    #pragma unroll
    for (int i = 0; i < 16; ++i) tot += redL[i];
    float fn = fmaxf(sqrtf(tot), 1.f);
    float inv = 1.f / fn;
    n2 = tot * inv * inv;
    c0v *= inv;
    if (wact) {
      #pragma unroll
      for (int t = 0; t < 2; ++t)
        #pragma unroll
        for (int i = 0; i < 4; ++i) { Ht[t][i] *= inv; aT[t][i] *= inv; }
    }
  }

  // ---- publish a's for inference ----
  if (wact) {
    float* dstA = (kk == 0) ? v1L : (kk == 1) ? v2L : v3L;
    #pragma unroll
    for (int t = 0; t < 2; ++t)
      #pragma unroll
      for (int i = 0; i < 4; ++i) {
        int srow = st * 16 + kgrp * 4 + i;
        if (srow < 30) dstA[srow * 68 + (fp * 2 + t) * 16 + col] = aT[t][i];
      }
  }
  if (tid < 64) { uv[tid] = qe1g[(size_t)b * 64 + tid]; siL[tid] = 0.f; }
  __syncthreads();

  // ---- inference (unchanged) ----
  int s = tid >> 5;
  bool act = s < 30;
  float* partL = partBuf;
  int k32 = tid & 31;
  for (int stg = 0; stg < 3; ++stg) {
    if (act) {
      float u0 = uv[k32], u1 = uv[k32 + 32];
      float eu1 = e1L[s * 68 + k32] * u0 + e1L[s * 68 + k32 + 32] * u1;
      float eu2 = e2L[s * 68 + k32] * u0 + e2L[s * 68 + k32 + 32] * u1;
      #pragma unroll
      for (int d = 16; d > 0; d >>= 1) {
        eu1 += __shfl_down(eu1, d, 32); eu2 += __shfl_down(eu2, d, 32);
      }
      if (k32 == 0) {
        alf[s]      = eu1 * rqL[stg * 90 + s];
        alf[32 + s] = eu1 * rqL[stg * 90 + 30 + s];
        alf[64 + s] = eu2 * rqL[stg * 90 + 60 + s];
      }
    }
    __syncthreads();
    {
      int p = tid >> 6, f = tid & 63;
      float part = 0.f;
      if (p < 12) {
        int start = (p < 6) ? p * 3 : 18 + (p - 6) * 2;
        int cnt = (p < 6) ? 3 : 2;
        for (int q = 0; q < cnt; ++q) {
          int sp = start + q;
          part += alf[sp] * v1L[sp * 68 + f] + alf[32 + sp] * v2L[sp * 68 + f]
                + alf[64 + sp] * v3L[sp * 68 + f];
        }
      } else {
        int e0 = (p - 12) * 16;
        const float* Gp = Gg + (size_t)stg * 1048576 + (size_t)b * 4096 + (size_t)e0 * 64 + f;
        float F = 0.f;
        #pragma unroll 4
        for (int e = 0; e < 16; ++e) F += uv[e0 + e] * Gp[e * 64];
        part = c0v * F;
      }
      partL[p * 64 + f] = part;
    }
    __syncthreads();
    if (tid < 64) {
      float raw = 0.f;
      #pragma unroll
      for (int p = 0; p < 16; ++p) raw += partL[p * 64 + tid];
      float mean = wreduce64(raw) * (1.f / 64.f);
      float d = raw - mean;
      float var = wreduce64(d * d) * (1.f / 63.f);
      float y = lng[stg * 64 + tid] * d / (sqrtf(var) + 1e-6f) + lnb[stg * 64 + tid];
      siL[tid] += y;
      uv[tid] = y;
    }
    __syncthreads();
  }
  if (tid < 9) {
    float o = 0.f;
    for (int ff = 0; ff < 64; ++ff) o += siL[ff] * Zg[ff * 9 + tid];
    out[(size_t)b * 9 + tid] = o;
  }
}

extern "C" void kernel_launch(void* const* d_in, const int* in_sizes, int n_in,
                              void* d_out, int out_size, void* d_ws, size_t ws_size,
                              hipStream_t stream) {
  const int*   story = (const int*)d_in[0];
  const int*   query = (const int*)d_in[1];
  const float* WE    = (const float*)d_in[2];
  const float* PE    = (const float*)d_in[3];
  const float* ueW1  = (const float*)d_in[4];
  const float* ueb1  = (const float*)d_in[5];
  const float* ueW2  = (const float*)d_in[6];
  const float* ueb2  = (const float*)d_in[7];
  const float* urW1  = (const float*)d_in[8];
  const float* urb1  = (const float*)d_in[9];
  const float* urW2  = (const float*)d_in[10];
  const float* urb2  = (const float*)d_in[11];
  const float* fwm   = (const float*)d_in[12];
  const float* ieW1  = (const float*)d_in[13];
  const float* ieb1  = (const float*)d_in[14];
  const float* ieW2  = (const float*)d_in[15];
  const float* ieb2  = (const float*)d_in[16];
  const float* irW1  = (const float*)d_in[17];
  const float* irb1  = (const float*)d_in[18];
  const float* irW2  = (const float*)d_in[19];
  const float* irb2  = (const float*)d_in[20];
  const float* lng   = (const float*)d_in[21];
  const float* lnb   = (const float*)d_in[22];
  const float* Z     = (const float*)d_in[23];
  float* W = (float*)d_ws;
  float* out = (float*)d_out;

  ushortT* sentB = (ushortT*)(W + OF_SENTB);
  ushortT* qembB = (ushortT*)(W + OF_QEMBB);
  ushortT* W1A   = (ushortT*)(W + OF_W1A);
  ushortT* W2TE  = (ushortT*)(W + OF_W2TE);
  ushortT* W2TR  = (ushortT*)(W + OF_W2TR);
  ushortT* fwmBT = (ushortT*)(W + OF_FWMB);

  prep_k<<<4232, 256, 0, stream>>>(story, query, WE, PE,
      ueW1, urW1, ieW1, irW1, ueW2, urW2, ieW2, irW2, fwm,
      sentB, qembB, W1A, W2TE, W2TR, fwmBT, W + OF_FN2);

  mlpm_k<<<dim3(240, 9), 256, 0, stream>>>(sentB, qembB, W1A,
      ueb1, urb1, ieb1, irb1, W2TE, W2TR, ueb2, urb2, ieb2, irb2,
      W + OF_E1, W + OF_R1, W + OF_QE1, W + OF_QR1);

  pstage_k<<<736, 256, 0, stream>>>(fwmBT, W + OF_E1, W + OF_E1 + 491520,
      W + OF_R1, W + OF_R1 + 245760, W + OF_R1 + 2 * 245760,
      W + OF_QR1, W + OF_QR1 + 8192, W + OF_QR1 + 16384,
      W + OF_PP, W + OF_G);

  scan_k<<<NB, 1024, 0, stream>>>(W + OF_PP, W + OF_G,
      W + OF_E1, W + OF_E1 + 491520,
      W + OF_R1, W + OF_R1 + 245760, W + OF_R1 + 2 * 245760,
      W + OF_QE1, W + OF_QR1, W + OF_QR1 + 8192, W + OF_QR1 + 16384,
      W + OF_FN2, lng, lnb, Z, out);
}